// Round 7
// baseline (1405.173 us; speedup 1.0000x reference)
//
#include <hip/hip_runtime.h>
#include <math.h>

static constexpr int NODES = 512;
static constexpr int CC    = 256;
static constexpr int KP    = 64;
static constexpr int ZDIM  = 513;
static constexpr int TPNB  = 16;
static constexpr int TPROWS = 33;

typedef unsigned short u16;
typedef short bf16x8 __attribute__((ext_vector_type(8)));
typedef float f32x4 __attribute__((ext_vector_type(4)));

__device__ __forceinline__ u16 f2b(float f){
  unsigned u = __float_as_uint(f);
  unsigned r = (u + 0x7FFF + ((u >> 16) & 1)) >> 16;
  return (u16)r;
}
__device__ __forceinline__ float b2f(u16 h){ return __uint_as_float(((unsigned)h) << 16); }
__device__ __forceinline__ f32x4 mfma16(bf16x8 a, bf16x8 b, f32x4 c){
  return __builtin_amdgcn_mfma_f32_16x16x32_bf16(a, b, c, 0, 0, 0);
}
__device__ __forceinline__ void astore(float* p, float v){
  __hip_atomic_store(p, v, __ATOMIC_RELAXED, __HIP_MEMORY_SCOPE_AGENT);
}
__device__ __forceinline__ float fpoll(const float* p){
  const unsigned* up = (const unsigned*)p;
  unsigned v = __hip_atomic_load(up, __ATOMIC_RELAXED, __HIP_MEMORY_SCOPE_AGENT);
  while (v == 0xFFFFFFFFu)
    v = __hip_atomic_load(up, __ATOMIC_RELAXED, __HIP_MEMORY_SCOPE_AGENT);
  return __uint_as_float(v);
}

// ======================= NN + hist (fused, decision-exact) =======================
__global__ __launch_bounds__(256) void nn_hist_kernel(
    const float* __restrict__ pts_s, int ns, const float* __restrict__ nodes_s,
    int* __restrict__ out_s, int* __restrict__ hist_s,
    const float* __restrict__ pts_t, int ntt, const float* __restrict__ nodes_t,
    int* __restrict__ out_t, int* __restrict__ hist_t, int nbs)
{
#pragma clang fp contract(off)
  __shared__ float nx[NODES], ny[NODES], nz[NODES], nn[NODES];
  __shared__ int h[NODES];
  int blk = blockIdx.x;
  const float* pts; const float* nodes; int* out; int* hist; int n; int bb;
  if (blk < nbs){ pts=pts_s; nodes=nodes_s; out=out_s; hist=hist_s; n=ns; bb=blk; }
  else          { pts=pts_t; nodes=nodes_t; out=out_t; hist=hist_t; n=ntt; bb=blk-nbs; }
  int t = threadIdx.x;
  for (int m = t; m < NODES; m += 256){
    float a = nodes[m*3+0], b = nodes[m*3+1], c = nodes[m*3+2];
    nx[m]=a; ny[m]=b; nz[m]=c;
    nn[m] = a*a + b*b + c*c;
    h[m] = 0;
  }
  __syncthreads();
  int i = bb*256 + t;
  if (i < n){
    float p0 = pts[i*3+0], p1 = pts[i*3+1], p2 = pts[i*3+2];
    float pp = p0*p0 + p1*p1 + p2*p2;
    float best = INFINITY; int bi = 0;
    for (int m = 0; m < NODES; ++m){
      float dot = fmaf(p2, nz[m], fmaf(p1, ny[m], p0*nx[m]));
      float d = (pp - 2.0f*dot) + nn[m];
      if (d < best){ best = d; bi = m; }
    }
    out[i] = bi;
    atomicAdd(&h[bi], 1);
  }
  __syncthreads();
  hist[(long)bb*NODES + t]       = h[t];
  hist[(long)bb*NODES + t + 256] = h[t+256];
}

__global__ __launch_bounds__(512) void scan_kernel(
    int* __restrict__ hist_s, int nbs, int* __restrict__ cnt_s,
    int* __restrict__ hist_t, int nbt, int* __restrict__ cnt_t)
{
  int* hist; int nb; int* counts;
  if (blockIdx.x == 0){ hist=hist_s; nb=nbs; counts=cnt_s; }
  else                { hist=hist_t; nb=nbt; counts=cnt_t; }
  int m = threadIdx.x;
  int run = 0;
  for (int b = 0; b < nb; ++b){
    int t = hist[(long)b*NODES + m];
    hist[(long)b*NODES + m] = run;
    run += t;
  }
  counts[m] = run;
}

__global__ __launch_bounds__(256) void rank_kernel(
    const int* __restrict__ id_s, int ns, const int* __restrict__ hist_s, int* __restrict__ patch_s,
    const int* __restrict__ id_t, int ntt, const int* __restrict__ hist_t, int* __restrict__ patch_t,
    int nbs)
{
  __shared__ int lid[256];
  int blk = blockIdx.x;
  const int* id; const int* hist; int* patch; int n; int bb;
  if (blk < nbs){ id=id_s; hist=hist_s; patch=patch_s; n=ns; bb=blk; }
  else          { id=id_t; hist=hist_t; patch=patch_t; n=ntt; bb=blk-nbs; }
  int t = threadIdx.x;
  int i = bb*256 + t;
  lid[t] = (i < n) ? id[i] : -1;
  __syncthreads();
  if (i >= n) return;
  int m = lid[t];
  int r = hist[(long)bb*NODES + m];
  for (int q = 0; q < t; ++q) r += (lid[q] == m) ? 1 : 0;
  if (r < KP) patch[m*KP + r] = i;
}

// ======================= weight conversion =======================
__global__ __launch_bounds__(256) void conv_weights(
  const float* cwq, const float* cwk, const float* cwv, const float* cwm,
  const float* cw1, const float* cw2, const float* fpw,
  const float* lwq, const float* lwk, const float* lwv, const float* lwm,
  const float* lw1, const float* lw2, const float* lfp,
  u16* __restrict__ dst)
{
  int i = blockIdx.x*256 + threadIdx.x;
  if (i >= 2539520) return;
  const float* s; int off;
  if      (i <  196608){ s=cwq; off=0; }
  else if (i <  393216){ s=cwk; off=196608; }
  else if (i <  589824){ s=cwv; off=393216; }
  else if (i <  786432){ s=cwm; off=589824; }
  else if (i < 1572864){ s=cw1; off=786432; }
  else if (i < 1966080){ s=cw2; off=1572864; }
  else if (i < 2031616){ s=fpw; off=1966080; }
  else if (i < 2080768){ s=lwq; off=2031616; }
  else if (i < 2129920){ s=lwk; off=2080768; }
  else if (i < 2179072){ s=lwv; off=2129920; }
  else if (i < 2228224){ s=lwm; off=2179072; }
  else if (i < 2424832){ s=lw1; off=2228224; }
  else if (i < 2523136){ s=lw2; off=2424832; }
  else                 { s=lfp; off=2523136; }
  dst[i] = f2b(s[i - off]);
}

__global__ __launch_bounds__(256) void tr_in(const float* __restrict__ fs,
                                             const float* __restrict__ ft,
                                             u16* __restrict__ cf,
                                             float* __restrict__ cff)
{
  int i = blockIdx.x*256 + threadIdx.x;
  if (i >= 262144) return;
  int side = i >> 17; int r = i & 131071; int d = r >> 9; int n = r & 511;
  float v = (side ? ft : fs)[r];
  long o = ((long)side*512 + n)*256 + d;
  cf[o] = f2b(v);
  cff[o] = v;
}

// ======================= coarse transformer (bf16 MFMA, [n][d]) =======================
__global__ __launch_bounds__(256) void coarse_qkv(
    const u16* __restrict__ cf, int cross, int side0,
    const u16* __restrict__ Wq, const u16* __restrict__ Wk, const u16* __restrict__ Wv,
    const float* __restrict__ bq, const float* __restrict__ bk, const float* __restrict__ bv,
    u16* __restrict__ qb, u16* __restrict__ kb, u16* __restrict__ vtb)
{
  int z = blockIdx.x;
  int side = side0 + z/24, rem = z%24, proj = rem >> 3, slice = rem & 7;
  const u16* x = cf + (long)side*131072;
  const u16* s = cross ? cf + (long)(1-side)*131072 : x;
  const u16* in = (proj == 0) ? x : s;
  const u16* W  = (proj==0)?Wq:(proj==1)?Wk:Wv;
  const float* bi = (proj==0)?bq:(proj==1)?bk:bv;
  int n0 = slice << 6;
  int wv_ = threadIdx.x >> 6, L = threadIdx.x & 63, lr = L & 15, lk = L >> 4;
  const u16* inb = in + (long)(n0 + lr)*256 + 8*lk;
  for (int oi = 0; oi < 4; ++oi){
    int o0 = (wv_*4 + oi) << 4;
    const u16* wrow = W + (long)(o0 + lr)*256 + 8*lk;
    f32x4 acc[4] = {};
#pragma unroll
    for (int ks = 0; ks < 8; ++ks){
      bf16x8 b = *(const bf16x8*)(wrow + ks*32);
#pragma unroll
      for (int a = 0; a < 4; ++a){
        bf16x8 av = *(const bf16x8*)(inb + a*16*256 + ks*32);
        acc[a] = mfma16(av, b, acc[a]);
      }
    }
    int col = o0 + lr;
    float bvv = bi[col];
    if (proj < 2){
      u16* o = (proj==0 ? qb : kb) + ((long)side*512 + n0)*256 + col;
#pragma unroll
      for (int a = 0; a < 4; ++a)
#pragma unroll
        for (int q_ = 0; q_ < 4; ++q_)
          o[(long)(a*16 + lk*4 + q_)*256] = f2b(acc[a][q_] + bvv);
    } else {
      u16* o = vtb + ((long)side*256 + col)*512 + n0;
#pragma unroll
      for (int a = 0; a < 4; ++a)
#pragma unroll
        for (int q_ = 0; q_ < 4; ++q_)
          o[a*16 + lk*4 + q_] = f2b(acc[a][q_] + bvv);
    }
  }
}

__global__ __launch_bounds__(256) void coarse_attn(
    const u16* __restrict__ qb, const u16* __restrict__ kb,
    const u16* __restrict__ vtb, u16* __restrict__ msgb, int side0)
{
  __shared__ u16 P[64][512];
  __shared__ float rmx[64][4], rsm[64][4];
  int z = blockIdx.x;
  int side = side0 + (z >> 5); int rem = z & 31;
  int head = rem >> 3, qs = rem & 7;
  int wv_ = threadIdx.x >> 6, L = threadIdx.x & 63, lr = L & 15, lk = L >> 4;
  const u16* q = qb + ((long)side*512 + qs*64)*256 + head*64;
  const u16* k = kb + (long)side*512*256 + head*64;
  const u16* vt = vtb + ((long)side*256 + head*64)*512;

  bf16x8 af[4][2];
#pragma unroll
  for (int a = 0; a < 4; ++a)
#pragma unroll
    for (int ks = 0; ks < 2; ++ks)
      af[a][ks] = *(const bf16x8*)(q + (long)(a*16 + lr)*256 + ks*32 + 8*lk);

  f32x4 sc[4][8] = {};
  for (int b = 0; b < 8; ++b){
    const u16* krow = k + (long)(wv_*128 + b*16 + lr)*256 + 8*lk;
#pragma unroll
    for (int ks = 0; ks < 2; ++ks){
      bf16x8 bf = *(const bf16x8*)(krow + ks*32);
#pragma unroll
      for (int a = 0; a < 4; ++a)
        sc[a][b] = mfma16(af[a][ks], bf, sc[a][b]);
    }
  }
  const float SC = 0.125f;
#pragma unroll
  for (int a = 0; a < 4; ++a)
#pragma unroll
    for (int q_ = 0; q_ < 4; ++q_){
      float m = sc[a][0][q_];
#pragma unroll
      for (int b = 1; b < 8; ++b) m = fmaxf(m, sc[a][b][q_]);
      m = fmaxf(m, __shfl_xor(m, 1)); m = fmaxf(m, __shfl_xor(m, 2));
      m = fmaxf(m, __shfl_xor(m, 4)); m = fmaxf(m, __shfl_xor(m, 8));
      if (lr == 0) rmx[a*16 + lk*4 + q_][wv_] = m;
    }
  __syncthreads();
#pragma unroll
  for (int a = 0; a < 4; ++a)
#pragma unroll
    for (int q_ = 0; q_ < 4; ++q_){
      int row = a*16 + lk*4 + q_;
      float m = fmaxf(fmaxf(rmx[row][0], rmx[row][1]), fmaxf(rmx[row][2], rmx[row][3]));
      float s = 0.f;
#pragma unroll
      for (int b = 0; b < 8; ++b){
        float e = __expf((sc[a][b][q_] - m)*SC);
        sc[a][b][q_] = e; s += e;
      }
      s += __shfl_xor(s,1); s += __shfl_xor(s,2); s += __shfl_xor(s,4); s += __shfl_xor(s,8);
      if (lr == 0) rsm[row][wv_] = s;
    }
  __syncthreads();
#pragma unroll
  for (int a = 0; a < 4; ++a)
#pragma unroll
    for (int q_ = 0; q_ < 4; ++q_){
      int row = a*16 + lk*4 + q_;
      float inv = 1.f / (rsm[row][0]+rsm[row][1]+rsm[row][2]+rsm[row][3]);
#pragma unroll
      for (int b = 0; b < 8; ++b)
        P[row][wv_*128 + b*16 + lr] = f2b(sc[a][b][q_] * inv);
    }
  __syncthreads();
  f32x4 mv[4] = {};
  for (int ks = 0; ks < 16; ++ks){
    bf16x8 bf = *(const bf16x8*)(vt + (long)(wv_*16 + lr)*512 + ks*32 + 8*lk);
#pragma unroll
    for (int a = 0; a < 4; ++a){
      bf16x8 av = *(const bf16x8*)(&P[a*16 + lr][ks*32 + 8*lk]);
      mv[a] = mfma16(av, bf, mv[a]);
    }
  }
  u16* o = msgb + ((long)side*512 + qs*64)*256 + head*64 + wv_*16 + lr;
#pragma unroll
  for (int a = 0; a < 4; ++a)
#pragma unroll
    for (int q_ = 0; q_ < 4; ++q_)
      o[(long)(a*16 + lk*4 + q_)*256] = f2b(mv[a][q_]);
}

__global__ __launch_bounds__(512) void coarse_ffn(
    const u16* __restrict__ msgb, u16* __restrict__ cf, float* __restrict__ cff,
    const u16* __restrict__ Wm, const float* __restrict__ bm,
    const u16* __restrict__ W1, const float* __restrict__ b1,
    const u16* __restrict__ W2, const float* __restrict__ b2, int side0)
{
  __shared__ u16 m2[64*256];
  __shared__ u16 h1[64*512];
  int z = blockIdx.x;
  int side = side0 + (z >> 3), slice = z & 7;
  int wv_ = threadIdx.x >> 6, L = threadIdx.x & 63, lr = L & 15, lk = L >> 4;
  const u16* msg = msgb + ((long)side*512 + slice*64)*256;
  u16* x = cf + ((long)side*512 + slice*64)*256;
  float* xf = cff + ((long)side*512 + slice*64)*256;
  for (int oi = 0; oi < 2; ++oi){
    int o0 = (wv_*2 + oi) << 4;
    f32x4 acc[4] = {};
    const u16* wrow = Wm + (long)(o0+lr)*256 + 8*lk;
#pragma unroll
    for (int ks = 0; ks < 8; ++ks){
      bf16x8 b = *(const bf16x8*)(wrow + ks*32);
#pragma unroll
      for (int a = 0; a < 4; ++a){
        bf16x8 av = *(const bf16x8*)(msg + (long)(a*16+lr)*256 + ks*32 + 8*lk);
        acc[a] = mfma16(av, b, acc[a]);
      }
    }
    int col = o0 + lr; float bb = bm[col];
#pragma unroll
    for (int a = 0; a < 4; ++a)
#pragma unroll
      for (int q_ = 0; q_ < 4; ++q_)
        m2[(a*16+lk*4+q_)*256 + col] = f2b(acc[a][q_] + bb);
  }
  __syncthreads();
  for (int oi = 0; oi < 4; ++oi){
    int o0 = (wv_*4 + oi) << 4;
    f32x4 acc[4] = {};
    const u16* wrow = W1 + (long)(o0+lr)*512 + 8*lk;
#pragma unroll
    for (int ks = 0; ks < 16; ++ks){
      int kk = ks*32;
      bf16x8 b = *(const bf16x8*)(wrow + kk);
#pragma unroll
      for (int a = 0; a < 4; ++a){
        bf16x8 av;
        if (kk < 256) av = *(const bf16x8*)(x + (long)(a*16+lr)*256 + kk + 8*lk);
        else          av = *(const bf16x8*)(&m2[(a*16+lr)*256 + kk - 256 + 8*lk]);
        acc[a] = mfma16(av, b, acc[a]);
      }
    }
    int col = o0 + lr; float bb = b1[col];
#pragma unroll
    for (int a = 0; a < 4; ++a)
#pragma unroll
      for (int q_ = 0; q_ < 4; ++q_)
        h1[(a*16+lk*4+q_)*512 + col] = f2b(fmaxf(acc[a][q_] + bb, 0.f));
  }
  __syncthreads();
  for (int oi = 0; oi < 2; ++oi){
    int o0 = (wv_*2 + oi) << 4;
    f32x4 acc[4] = {};
    const u16* wrow = W2 + (long)(o0+lr)*512 + 8*lk;
#pragma unroll
    for (int ks = 0; ks < 16; ++ks){
      bf16x8 b = *(const bf16x8*)(wrow + ks*32);
#pragma unroll
      for (int a = 0; a < 4; ++a){
        bf16x8 av = *(const bf16x8*)(&h1[(a*16+lr)*512 + ks*32 + 8*lk]);
        acc[a] = mfma16(av, b, acc[a]);
      }
    }
    int col = o0 + lr; float bb = b2[col];
#pragma unroll
    for (int a = 0; a < 4; ++a)
#pragma unroll
      for (int q_ = 0; q_ < 4; ++q_){
        long idx = (long)(a*16+lk*4+q_)*256 + col;
        float v = acc[a][q_] + bb + xf[idx];
        xf[idx] = v;
        x[idx] = f2b(v);
      }
  }
}

__global__ __launch_bounds__(256) void coarse_proj(
    const u16* __restrict__ cf, const u16* __restrict__ W,
    const float* __restrict__ bias, u16* __restrict__ out)
{
  int z = blockIdx.x;
  int side = z >> 3, slice = z & 7;
  const u16* in = cf + (long)side*131072;
  u16* o = out + (long)side*131072;
  int n0 = slice << 6;
  int wv_ = threadIdx.x >> 6, L = threadIdx.x & 63, lr = L & 15, lk = L >> 4;
  const u16* inb = in + (long)(n0 + lr)*256 + 8*lk;
  for (int oi = 0; oi < 4; ++oi){
    int o0 = (wv_*4 + oi) << 4;
    const u16* wrow = W + (long)(o0 + lr)*256 + 8*lk;
    f32x4 acc[4] = {};
#pragma unroll
    for (int ks = 0; ks < 8; ++ks){
      bf16x8 b = *(const bf16x8*)(wrow + ks*32);
#pragma unroll
      for (int a = 0; a < 4; ++a){
        bf16x8 av = *(const bf16x8*)(inb + a*16*256 + ks*32);
        acc[a] = mfma16(av, b, acc[a]);
      }
    }
    int col = o0 + lr; float bb = bias[col];
#pragma unroll
    for (int a = 0; a < 4; ++a)
#pragma unroll
      for (int q_ = 0; q_ < 4; ++q_)
        o[(long)(n0 + a*16 + lk*4 + q_)*256 + col] = f2b(acc[a][q_] + bb);
  }
}

__global__ __launch_bounds__(256) void coarse_scores(
    const u16* __restrict__ sfp, const u16* __restrict__ tfp, float* __restrict__ Z)
{
  int n0 = blockIdx.y << 6, m0 = blockIdx.x << 6;
  int wv_ = threadIdx.x >> 6, L = threadIdx.x & 63, lr = L & 15, lk = L >> 4;
  f32x4 acc[4] = {};
  const u16* arow = sfp + (long)(n0 + lr)*256 + 8*lk;
  const u16* brow = tfp + (long)(m0 + wv_*16 + lr)*256 + 8*lk;
#pragma unroll
  for (int ks = 0; ks < 8; ++ks){
    bf16x8 b = *(const bf16x8*)(brow + ks*32);
#pragma unroll
    for (int a = 0; a < 4; ++a){
      bf16x8 av = *(const bf16x8*)(arow + a*16*256 + ks*32);
      acc[a] = mfma16(av, b, acc[a]);
    }
  }
  int col = m0 + wv_*16 + lr;
#pragma unroll
  for (int a = 0; a < 4; ++a)
#pragma unroll
    for (int q_ = 0; q_ < 4; ++q_)
      Z[(long)(n0 + a*16 + lk*4 + q_)*513 + col] = acc[a][q_]*0.0625f;
}

__global__ __launch_bounds__(256) void fill_border(float* Z, const float* __restrict__ alpha)
{
  int i = blockIdx.x*256 + threadIdx.x;
  if (i < ZDIM){
    float a = alpha[0];
    Z[(long)i*ZDIM + (ZDIM-1)] = a;
    Z[(long)(ZDIM-1)*ZDIM + i] = a;
  }
}

__global__ __launch_bounds__(256) void transpose_k(const float* __restrict__ A,
                                                   float* __restrict__ B, int n)
{
  __shared__ float t[32][33];
  int bx = blockIdx.x*32, by = blockIdx.y*32;
  int lx = threadIdx.x & 31, ly0 = threadIdx.x >> 5;
  for (int dy = 0; dy < 32; dy += 8){
    int x = bx + lx, y = by + ly0 + dy;
    if (x < n && y < n) t[ly0+dy][lx] = A[(long)y*n + x];
  }
  __syncthreads();
  for (int dy = 0; dy < 32; dy += 8){
    int x = by + lx, y = bx + ly0 + dy;
    if (x < n && y < n) B[(long)y*n + x] = t[lx][ly0+dy];
  }
}

// ======================= mega kernel roles =======================
static constexpr int ARENA = 142336;

// ---- transport role (blocks 0..15, 256 threads, sentinel dataflow) ----
__device__ void transport_role(char* arena, int bid,
    const float* __restrict__ Z, const float* __restrict__ Zt,
    float* Rr, float* Cc, float* UU, float* VV,
    float* __restrict__ out, float outadd)
{
  float* A = (float*)arena;
  float* B = A + TPROWS*513;
  float* RrL = B + TPROWS*513;
  float* CcL = RrL + 513;
  float* M   = CcL + 513;
  float* rown = M + 513;
  float* cown = rown + TPROWS;
  float* uown = cown + TPROWS;
  int tid = threadIdx.x;
  int wv_ = tid >> 6, lane = tid & 63;
  int r0 = bid * TPROWS;
  int nr = 513 - r0; if (nr > TPROWS) nr = TPROWS;

  for (int i = wv_; i < nr; i += 4){
    const float* zr  = Z  + (long)(r0+i)*513;
    const float* ztr = Zt + (long)(r0+i)*513;
    for (int j = lane; j < 513; j += 64){ A[i*513+j] = zr[j]; B[i*513+j] = ztr[j]; }
  }
  __syncthreads();
  for (int i = wv_; i < nr; i += 4){
    float m = -INFINITY;
    for (int j = lane; j < 513; j += 64) m = fmaxf(m, A[i*513+j]);
    for (int o = 32; o; o >>= 1) m = fmaxf(m, __shfl_xor(m, o));
    if (lane == 0){ rown[i] = m; astore(&Rr[r0+i], m); }
  }
  for (int j = tid; j < 513; j += 256) RrL[j] = fpoll(&Rr[j]);
  __syncthreads();
  for (int i = wv_; i < nr; i += 4){
    float m = -INFINITY;
    for (int j = lane; j < 513; j += 64) m = fmaxf(m, B[i*513+j] - RrL[j]);
    for (int o = 32; o; o >>= 1) m = fmaxf(m, __shfl_xor(m, o));
    if (lane == 0){ cown[i] = m; astore(&Cc[r0+i], m); }
  }
  for (int j = tid; j < 513; j += 256) CcL[j] = fpoll(&Cc[j]);
  __syncthreads();
  for (int i = wv_; i < nr; i += 4){
    float ro = rown[i], co = cown[i];
    for (int j = lane; j < 513; j += 64){
      A[i*513+j] = __expf(A[i*513+j] - ro - CcL[j]);
      B[i*513+j] = __expf(B[i*513+j] - co - RrL[j]);
    }
  }
  __syncthreads();
  const float EBM = 1.0f/1024.0f, EBL = 0.5f;
  for (int i = wv_; i < nr; i += 4){
    float s = 0.f;
    for (int j = lane; j < 513; j += 64) s += A[i*513+j];
    for (int o = 32; o; o >>= 1) s += __shfl_xor(s, o);
    if (lane == 0){
      int r = r0+i; float u = ((r < 512) ? EBM : EBL) / s;
      uown[i] = u; astore(&UU[r], u);
    }
  }
  for (int it = 0; it < 50; ++it){
    for (int j = tid; j < 513; j += 256) M[j] = fpoll(&UU[(long)it*640 + j]);
    __syncthreads();
    for (int i = wv_; i < nr; i += 4){
      float s = 0.f;
      for (int j = lane; j < 513; j += 64) s = fmaf(B[i*513+j], M[j], s);
      for (int o = 32; o; o >>= 1) s += __shfl_xor(s, o);
      if (lane == 0){
        int r = r0+i;
        astore(&VV[(long)it*640 + r], ((r < 512) ? EBM : EBL) / s);
      }
    }
    __syncthreads();
    if (it == 49) break;
    for (int j = tid; j < 513; j += 256) M[j] = fpoll(&VV[(long)it*640 + j]);
    __syncthreads();
    for (int i = wv_; i < nr; i += 4){
      float s = 0.f;
      for (int j = lane; j < 513; j += 64) s = fmaf(A[i*513+j], M[j], s);
      for (int o = 32; o; o >>= 1) s += __shfl_xor(s, o);
      if (lane == 0){
        int r = r0+i; float u = ((r < 512) ? EBM : EBL) / s;
        uown[i] = u; astore(&UU[(long)(it+1)*640 + r], u);
      }
    }
    __syncthreads();
  }
  for (int j = tid; j < 513; j += 256) M[j] = fpoll(&VV[49L*640 + j]);
  __syncthreads();
  for (int j = tid; j < 513; j += 256) M[j] = __logf(M[j]) - CcL[j];
  __syncthreads();
  for (int i = wv_; i < nr; i += 4){
    int r = r0 + i;
    float uu = __logf(uown[i]) - rown[i];
    const float* zr = Z + (long)r*513;
    float* orow = out + (long)r*513;
    for (int j = lane; j < 513; j += 64) orow[j] = zr[j] + uu + M[j] + outadd;
  }
}

// ---- local layer application (256 threads, x/s in LDS) ----
__device__ void layerapp(
    u16* __restrict__ x, const u16* __restrict__ s, u16* __restrict__ pool,
    const u16* __restrict__ Wq, const u16* __restrict__ Wk,
    const u16* __restrict__ Wv, const u16* __restrict__ Wm,
    const u16* __restrict__ W1, const u16* __restrict__ W2,
    const float* __restrict__ bq, const float* __restrict__ bk,
    const float* __restrict__ bv, const float* __restrict__ bm,
    const float* __restrict__ b1, const float* __restrict__ b2)
{
  int wv_ = threadIdx.x >> 6, L = threadIdx.x & 63, lr = L & 15, lk = L >> 4;
  u16* qS = pool; u16* kS = pool + 8192; u16* vT = pool + 16384; u16* msgS = pool + 24576;

#pragma unroll
  for (int proj = 0; proj < 3; ++proj){
    const u16* in = proj ? s : x;
    const u16* W = proj==0?Wq:proj==1?Wk:Wv;
    const float* bi = proj==0?bq:proj==1?bk:bv;
#pragma unroll
    for (int oi = 0; oi < 2; ++oi){
      int o0 = (wv_ + oi*4) << 4;
      f32x4 acc[4] = {};
      const u16* wrow = W + (long)(o0+lr)*128 + 8*lk;
      const u16* inr = in + (long)lr*128 + 8*lk;
#pragma unroll
      for (int ks = 0; ks < 4; ++ks){
        bf16x8 b = *(const bf16x8*)(wrow + ks*32);
#pragma unroll
        for (int a = 0; a < 4; ++a){
          bf16x8 av = *(const bf16x8*)(inr + a*16*128 + ks*32);
          acc[a] = mfma16(av, b, acc[a]);
        }
      }
      int col = o0 + lr; float bb = bi[col];
      if (proj < 2){
        u16* dst = (proj==0 ? qS : kS);
#pragma unroll
        for (int a = 0; a < 4; ++a)
#pragma unroll
          for (int q_ = 0; q_ < 4; ++q_)
            dst[(a*16 + lk*4 + q_)*128 + col] = f2b(acc[a][q_] + bb);
      } else {
#pragma unroll
        for (int a = 0; a < 4; ++a)
#pragma unroll
          for (int q_ = 0; q_ < 4; ++q_)
            vT[col*64 + a*16 + lk*4 + q_] = f2b(acc[a][q_] + bb);
      }
    }
  }
  __syncthreads();
  int h = wv_;
  bf16x8 qf[4], kf[4];
#pragma unroll
  for (int a = 0; a < 4; ++a){
    qf[a] = *(const bf16x8*)(&qS[(a*16+lr)*128 + h*32 + 8*lk]);
    kf[a] = *(const bf16x8*)(&kS[(a*16+lr)*128 + h*32 + 8*lk]);
  }
  f32x4 sc[4][4] = {};
#pragma unroll
  for (int b = 0; b < 4; ++b)
#pragma unroll
    for (int a = 0; a < 4; ++a)
      sc[a][b] = mfma16(qf[a], kf[b], sc[a][b]);
  const float SCs = 0.17677669529663687f;
  float invs[4][4];
#pragma unroll
  for (int a = 0; a < 4; ++a)
#pragma unroll
    for (int q_ = 0; q_ < 4; ++q_){
      float m = sc[a][0][q_];
#pragma unroll
      for (int b = 1; b < 4; ++b) m = fmaxf(m, sc[a][b][q_]);
      m = fmaxf(m, __shfl_xor(m, 1)); m = fmaxf(m, __shfl_xor(m, 2));
      m = fmaxf(m, __shfl_xor(m, 4)); m = fmaxf(m, __shfl_xor(m, 8));
      float ss = 0.f;
#pragma unroll
      for (int b = 0; b < 4; ++b){
        float e = __expf((sc[a][b][q_] - m)*SCs);
        sc[a][b][q_] = e; ss += e;
      }
      ss += __shfl_xor(ss,1); ss += __shfl_xor(ss,2); ss += __shfl_xor(ss,4); ss += __shfl_xor(ss,8);
      invs[a][q_] = 1.f/ss;
    }
  __syncthreads();
  u16* P = pool + h*4096;
#pragma unroll
  for (int a = 0; a < 4; ++a)
#pragma unroll
    for (int q_ = 0; q_ < 4; ++q_)
#pragma unroll
      for (int b = 0; b < 4; ++b)
        P[(a*16 + lk*4 + q_)*64 + b*16 + lr] = f2b(sc[a][b][q_] * invs[a][q_]);
  f32x4 mv[4][2] = {};
#pragma unroll
  for (int ks = 0; ks < 2; ++ks)
#pragma unroll
    for (int bt = 0; bt < 2; ++bt){
      bf16x8 bf = *(const bf16x8*)(&vT[(h*32 + bt*16 + lr)*64 + ks*32 + 8*lk]);
#pragma unroll
      for (int a = 0; a < 4; ++a){
        bf16x8 av = *(const bf16x8*)(&P[(a*16+lr)*64 + ks*32 + 8*lk]);
        mv[a][bt] = mfma16(av, bf, mv[a][bt]);
      }
    }
#pragma unroll
  for (int a = 0; a < 4; ++a)
#pragma unroll
    for (int bt = 0; bt < 2; ++bt)
#pragma unroll
      for (int q_ = 0; q_ < 4; ++q_)
        msgS[(a*16 + lk*4 + q_)*128 + h*32 + bt*16 + lr] = f2b(mv[a][bt][q_]);
  __syncthreads();
  u16* m2 = pool;
#pragma unroll
  for (int oi = 0; oi < 2; ++oi){
    int o0 = (wv_ + oi*4) << 4;
    f32x4 acc[4] = {};
    const u16* wrow = Wm + (long)(o0+lr)*128 + 8*lk;
#pragma unroll
    for (int ks = 0; ks < 4; ++ks){
      bf16x8 b = *(const bf16x8*)(wrow + ks*32);
#pragma unroll
      for (int a = 0; a < 4; ++a){
        bf16x8 av = *(const bf16x8*)(&msgS[(a*16+lr)*128 + ks*32 + 8*lk]);
        acc[a] = mfma16(av, b, acc[a]);
      }
    }
    int col = o0+lr; float bb = bm[col];
#pragma unroll
    for (int a = 0; a < 4; ++a)
#pragma unroll
      for (int q_ = 0; q_ < 4; ++q_)
        m2[(a*16+lk*4+q_)*128 + col] = f2b(acc[a][q_] + bb);
  }
  __syncthreads();
  u16* h1 = pool + 8192;
#pragma unroll
  for (int oi = 0; oi < 4; ++oi){
    int o0 = (wv_*4 + oi) << 4;
    f32x4 acc[4] = {};
    const u16* wrow = W1 + (long)(o0+lr)*256 + 8*lk;
#pragma unroll
    for (int ks = 0; ks < 8; ++ks){
      int kk = ks*32;
      bf16x8 b = *(const bf16x8*)(wrow + kk);
#pragma unroll
      for (int a = 0; a < 4; ++a){
        bf16x8 av;
        if (kk < 128) av = *(const bf16x8*)(x + (long)(a*16+lr)*128 + kk + 8*lk);
        else          av = *(const bf16x8*)(&m2[(a*16+lr)*128 + kk - 128 + 8*lk]);
        acc[a] = mfma16(av, b, acc[a]);
      }
    }
    int col = o0+lr; float bb = b1[col];
#pragma unroll
    for (int a = 0; a < 4; ++a)
#pragma unroll
      for (int q_ = 0; q_ < 4; ++q_)
        h1[(a*16+lk*4+q_)*256 + col] = f2b(fmaxf(acc[a][q_] + bb, 0.f));
  }
  __syncthreads();
#pragma unroll
  for (int oi = 0; oi < 2; ++oi){
    int o0 = (wv_ + oi*4) << 4;
    f32x4 acc[4] = {};
    const u16* wrow = W2 + (long)(o0+lr)*256 + 8*lk;
#pragma unroll
    for (int ks = 0; ks < 8; ++ks){
      bf16x8 b = *(const bf16x8*)(wrow + ks*32);
#pragma unroll
      for (int a = 0; a < 4; ++a){
        bf16x8 av = *(const bf16x8*)(&h1[(a*16+lr)*256 + ks*32 + 8*lk]);
        acc[a] = mfma16(av, b, acc[a]);
      }
    }
    int col = o0+lr; float bb = b2[col];
#pragma unroll
    for (int a = 0; a < 4; ++a)
#pragma unroll
      for (int q_ = 0; q_ < 4; ++q_){
        int ri = (a*16+lk*4+q_)*128 + col;
        x[ri] = f2b(acc[a][q_] + bb + b2f(x[ri]));
      }
  }
  __syncthreads();
}

// ---- local role (blocks 16..271): full per-patch pipeline ----
__device__ void local_role(char* arena, int c,
    const float* __restrict__ Fs, const float* __restrict__ Ft,
    const int* __restrict__ patch_s, const int* __restrict__ patch_t,
    const int* __restrict__ corr,
    const int* __restrict__ cnt_s, const int* __restrict__ cnt_t,
    const u16* WlQ, const u16* WlK, const u16* WlV, const u16* WlM,
    const u16* Wl1, const u16* Wl2, const u16* Wlfp,
    const float* lbq, const float* lbk, const float* lbv, const float* lbm,
    const float* lb1, const float* lb2, const float* lfpB,
    float* __restrict__ out_ls)
{
  u16* X    = (u16*)arena;                 // [2][64][128] bf16 (32 KB)
  u16* pool = (u16*)(arena + 32768);       // 64 KB
  float* LA = (float*)(arena + 98304);     // 65*66
  float* ET = (float*)(arena + 115712);    // 65*66
  float* uvec = (float*)(arena + 133120);
  float* vvec = (float*)(arena + 133440);
  float* u0s  = (float*)(arena + 133760);
  float* Ul   = (float*)(arena + 134080);
  float* Vl   = (float*)(arena + 134400);
  int* sel    = (int*)(arena + 134720);    // [128]
  int tid = threadIdx.x;

  if (tid < 128){
    int side = tid >> 6, n = tid & 63;
    int node = corr[c*2 + side];
    sel[tid] = (side ? patch_t : patch_s)[node*KP + n];
  }
  __syncthreads();
  for (int e = tid; e < 16384; e += 256){
    int side = e >> 13, r = e & 8191, n = r >> 7, d = r & 127;
    const float* F = side ? Ft : Fs;
    X[e] = f2b(F[(long)sel[side*64 + n]*128 + d]);
  }
  __syncthreads();

  for (int l = 0; l < 3; ++l){
    const u16* wq = WlQ + (size_t)l*16384; const u16* wk = WlK + (size_t)l*16384;
    const u16* wv = WlV + (size_t)l*16384; const u16* wm = WlM + (size_t)l*16384;
    const u16* w1 = Wl1 + (size_t)l*65536; const u16* w2 = Wl2 + (size_t)l*32768;
    const float* bq = lbq + (size_t)l*128; const float* bk = lbk + (size_t)l*128;
    const float* bv = lbv + (size_t)l*128; const float* bm = lbm + (size_t)l*128;
    const float* b1 = lb1 + (size_t)l*256; const float* b2 = lb2 + (size_t)l*128;
    int cross = (l == 1);
    layerapp(X,        X + (cross ? 8192 : 0), pool, wq,wk,wv,wm,w1,w2, bq,bk,bv,bm,b1,b2);
    layerapp(X + 8192, X + (cross ? 0 : 8192), pool, wq,wk,wv,wm,w1,w2, bq,bk,bv,bm,b1,b2);
  }

  // lfp projection -> sp/tp
  u16* sp = pool; u16* tp = pool + 8192;
  int wv4 = tid >> 6, L = tid & 63, lr = L & 15, lk = L >> 4;
  for (int u_ = wv4; u_ < 16; u_ += 4){
    int sideSel = u_ >> 3, ot = u_ & 7;
    const u16* in = X + sideSel*8192;
    u16* dst = sideSel ? tp : sp;
    int o0 = ot << 4;
    f32x4 acc[4] = {};
    const u16* wrow = Wlfp + (long)(o0+lr)*128 + 8*lk;
    const u16* inr = in + (long)lr*128 + 8*lk;
#pragma unroll
    for (int ks = 0; ks < 4; ++ks){
      bf16x8 b = *(const bf16x8*)(wrow + ks*32);
#pragma unroll
      for (int a = 0; a < 4; ++a){
        bf16x8 av = *(const bf16x8*)(inr + a*16*128 + ks*32);
        acc[a] = mfma16(av, b, acc[a]);
      }
    }
    int col = o0 + lr; float bb = lfpB[col];
#pragma unroll
    for (int a = 0; a < 4; ++a)
#pragma unroll
      for (int q_ = 0; q_ < 4; ++q_)
        dst[(a*16 + lk*4 + q_)*128 + col] = f2b(acc[a][q_] + bb);
  }
  __syncthreads();

  // scores -> LA (masked)
  int cs = cnt_s[corr[c*2]], ct = cnt_t[corr[c*2+1]];
  for (int t_ = wv4; t_ < 16; t_ += 4){
    int mt = t_ >> 2, nt = t_ & 3;
    f32x4 acc = {};
    const u16* arow = sp + (mt*16 + lr)*128 + 8*lk;
    const u16* brow = tp + (nt*16 + lr)*128 + 8*lk;
#pragma unroll
    for (int ks = 0; ks < 4; ++ks){
      bf16x8 a = *(const bf16x8*)(arow + ks*32);
      bf16x8 b = *(const bf16x8*)(brow + ks*32);
      acc = mfma16(a, b, acc);
    }
    const float SCS = 0.08838834764831845f;
#pragma unroll
    for (int q_ = 0; q_ < 4; ++q_){
      int row = mt*16 + lk*4 + q_;
      int col = nt*16 + lr;
      float v = acc[q_] * SCS;
      if (row >= cs || col >= ct) v = -1000000.0f;
      LA[row*66 + col] = v;
    }
  }
  if (tid < 65){ LA[64*66 + tid] = 0.f; LA[tid*66 + 64] = 0.f; uvec[tid] = 1.f; vvec[tid] = 1.f; }
  __syncthreads();

  // initial row pass (log domain); E overlays sp/tp
  float* E = (float*)pool;
  int g = tid >> 2, sub = tid & 3;
  {
    float mx = -INFINITY;
    for (int j = sub; j < 65; j += 4) mx = fmaxf(mx, LA[g*66 + j]);
    mx = fmaxf(mx, __shfl_xor(mx, 1)); mx = fmaxf(mx, __shfl_xor(mx, 2));
    float s = 0.f;
    for (int j = sub; j < 65; j += 4) s += __expf(LA[g*66 + j] - mx);
    s += __shfl_xor(s, 1); s += __shfl_xor(s, 2);
    float u0 = mx + __logf(s);
    if (sub == 0) u0s[g] = u0;
    for (int j = sub; j < 65; j += 4){
      float e = __expf(LA[g*66 + j] - u0);
      E[g*66 + j] = e;
      ET[j*66 + g] = e;
    }
  }
  if (tid < 65){
    E[64*66 + tid] = 1.f;
    ET[tid*66 + 64] = 1.f;
    if (tid == 64) u0s[64] = 0.f;
  }
  __syncthreads();
  for (int it = 0; it < 50; ++it){
    {
      float s = 0.f;
      for (int r = sub; r < 65; r += 4) s = fmaf(ET[g*66 + r], uvec[r], s);
      s += __shfl_xor(s, 1); s += __shfl_xor(s, 2);
      if (sub == 0) vvec[g] = 1.f / s;
    }
    __syncthreads();
    if (it == 49) break;
    {
      float s = 0.f;
      for (int j = sub; j < 65; j += 4) s = fmaf(E[g*66 + j], vvec[j], s);
      s += __shfl_xor(s, 1); s += __shfl_xor(s, 2);
      if (sub == 0) uvec[g] = 1.f / s;
    }
    __syncthreads();
  }
  __syncthreads();
  if (tid < 65){ Ul[tid] = u0s[tid] - __logf(uvec[tid]); Vl[tid] = -__logf(vvec[tid]); }
  __syncthreads();
  for (int e = tid; e < 4225; e += 256){
    int r = e / 65, c2 = e % 65;
    out_ls[(long)c*4225 + e] = LA[r*66 + c2] - Ul[r] - Vl[c2];
  }
}

// ---- gt role (blocks 272..527) ----
__device__ void gt_role(char* arena, int c,
    const float* __restrict__ sraw, const float* __restrict__ traw,
    const float* __restrict__ rot, const float* __restrict__ trans,
    const int* __restrict__ patch_s, const int* __restrict__ patch_t,
    const int* __restrict__ corr,
    const int* __restrict__ cnt_s, const int* __restrict__ cnt_t,
    float* __restrict__ out)
{
#pragma clang fp contract(off)
  float* sx = (float*)arena;         float* sy = sx + 64;
  float* sz = sy + 64;               float* spp = sz + 64;
  float* txa = spp + 64;             float* tya = txa + 64;
  float* tza = tya + 64;             float* tpp = tza + 64;
  float* g   = tpp + 64;             // 64*65
  float* rowsum = g + 64*65;
  float* colsum = rowsum + 64;
  int tid = threadIdx.x;
  int sn = corr[c*2], tn = corr[c*2+1];
  int cs = cnt_s[sn], ct = cnt_t[tn];
  if (tid < 64){
    int idx = patch_s[sn*KP + tid];
    float p0 = sraw[(long)idx*3], p1 = sraw[(long)idx*3+1], p2 = sraw[(long)idx*3+2];
    float a0 = fmaf(rot[2], p2, fmaf(rot[1], p1, rot[0]*p0)) + trans[0];
    float a1 = fmaf(rot[5], p2, fmaf(rot[4], p1, rot[3]*p0)) + trans[1];
    float a2 = fmaf(rot[8], p2, fmaf(rot[7], p1, rot[6]*p0)) + trans[2];
    sx[tid]=a0; sy[tid]=a1; sz[tid]=a2;
    spp[tid] = a0*a0 + a1*a1 + a2*a2;
  } else if (tid < 128){
    int l = tid - 64;
    int idx = patch_t[tn*KP + l];
    float p0 = traw[(long)idx*3], p1 = traw[(long)idx*3+1], p2 = traw[(long)idx*3+2];
    txa[l]=p0; tya[l]=p1; tza[l]=p2;
    tpp[l] = p0*p0 + p1*p1 + p2*p2;
  }
  __syncthreads();
  for (int e = tid; e < 4096; e += 256){
    int n = e >> 6, m = e & 63;
    float dot = fmaf(sz[n], tza[m], fmaf(sy[n], tya[m], sx[n]*txa[m]));
    float d2 = (spp[n] + tpp[m]) - 2.0f*dot;
    d2 = fmaxf(d2, 0.f);
    g[n*65 + m] = (sqrtf(d2) < 0.1f) ? 1.f : 0.f;
  }
  __syncthreads();
  if (tid < 64){
    float s = 0.f;
    for (int m = 0; m < 64; ++m) s += g[tid*65 + m];
    rowsum[tid] = fmaxf(1.f - s, 0.f);
  } else if (tid < 128){
    int m = tid - 64;
    float s = 0.f;
    for (int n = 0; n < 64; ++n) s += g[n*65 + m];
    colsum[m] = fmaxf(1.f - s, 0.f);
  }
  __syncthreads();
  float* o = out + (long)c*4225;
  for (int e = tid; e < 4225; e += 256){
    int r = e / 65, col = e % 65;
    float v;
    if (r < 64 && col < 64) v = g[r*65 + col];
    else if (r < 64)        v = rowsum[r];
    else if (col < 64)      v = colsum[col];
    else                    v = 0.f;
    if (r < 64 && r >= cs)    v = 0.f;
    if (col < 64 && col >= ct) v = 0.f;
    o[e] = v;
  }
}

// ---- mega kernel: transport ∥ local ∥ gt ----
__global__ __launch_bounds__(256) void mega(
    const float* Z, const float* Zt, float* Rr, float* Cc, float* UU, float* VV,
    float* out0, float outadd,
    const float* Fs, const float* Ft,
    const int* patch_s, const int* patch_t, const int* corr,
    const int* cnt_s, const int* cnt_t,
    const u16* WlQ, const u16* WlK, const u16* WlV, const u16* WlM,
    const u16* Wl1, const u16* Wl2, const u16* Wlfp,
    const float* lbq, const float* lbk, const float* lbv, const float* lbm,
    const float* lb1, const float* lb2, const float* lfpB,
    float* out_ls,
    const float* sraw, const float* traw, const float* rot, const float* trans,
    float* out_gt)
{
  __shared__ __align__(16) char arena[ARENA];
  int b = blockIdx.x;
  if (b < TPNB)
    transport_role(arena, b, Z, Zt, Rr, Cc, UU, VV, out0, outadd);
  else if (b < TPNB + CC)
    local_role(arena, b - TPNB, Fs, Ft, patch_s, patch_t, corr, cnt_s, cnt_t,
               WlQ, WlK, WlV, WlM, Wl1, Wl2, Wlfp,
               lbq, lbk, lbv, lbm, lb1, lb2, lfpB, out_ls);
  else
    gt_role(arena, b - TPNB - CC, sraw, traw, rot, trans,
            patch_s, patch_t, corr, cnt_s, cnt_t, out_gt);
}

// ======================= host =======================
extern "C" void kernel_launch(void* const* d_in, const int* in_sizes, int n_in,
                              void* d_out, int out_size, void* d_ws, size_t ws_size,
                              hipStream_t stream)
{
  const float* src_pcd_c  = (const float*)d_in[0];
  const float* tgt_pcd_c  = (const float*)d_in[1];
  const float* src_node_c = (const float*)d_in[2];
  const float* tgt_node_c = (const float*)d_in[3];
  const float* src_feats  = (const float*)d_in[4];
  const float* tgt_feats  = (const float*)d_in[5];
  const float* src_final  = (const float*)d_in[6];
  const float* tgt_final  = (const float*)d_in[7];
  const float* rot        = (const float*)d_in[8];
  const float* trans      = (const float*)d_in[9];
  const float* src_raw    = (const float*)d_in[10];
  const float* tgt_raw    = (const float*)d_in[11];
  const int*   node_corr  = (const int*)d_in[12];
  const float* c_wq = (const float*)d_in[13]; const float* c_bq = (const float*)d_in[14];
  const float* c_wk = (const float*)d_in[15]; const float* c_bk = (const float*)d_in[16];
  const float* c_wv = (const float*)d_in[17]; const float* c_bv = (const float*)d_in[18];
  const float* c_wm = (const float*)d_in[19]; const float* c_bm = (const float*)d_in[20];
  const float* c_w1 = (const float*)d_in[21]; const float* c_b1 = (const float*)d_in[22];
  const float* c_w2 = (const float*)d_in[23]; const float* c_b2 = (const float*)d_in[24];
  const float* l_wq = (const float*)d_in[25]; const float* l_bq = (const float*)d_in[26];
  const float* l_wk = (const float*)d_in[27]; const float* l_bk = (const float*)d_in[28];
  const float* l_wv = (const float*)d_in[29]; const float* l_bv = (const float*)d_in[30];
  const float* l_wm = (const float*)d_in[31]; const float* l_bm = (const float*)d_in[32];
  const float* l_w1 = (const float*)d_in[33]; const float* l_b1 = (const float*)d_in[34];
  const float* l_w2 = (const float*)d_in[35]; const float* l_b2 = (const float*)d_in[36];
  const float* fp_w = (const float*)d_in[37]; const float* fp_b = (const float*)d_in[38];
  const float* lfp_w = (const float*)d_in[39]; const float* lfp_b = (const float*)d_in[40];
  const float* bin_score = (const float*)d_in[41];

  const int NS = in_sizes[0] / 3;
  const int NT = in_sizes[1] / 3;

  float* FB = (float*)d_ws;
  size_t off = 0;
  auto falloc = [&](size_t n){ float* p = FB + off; off += (n + 63) & ~size_t(63); return p; };
  float* Zx  = falloc(263169);
  float* Zt  = falloc(263169);
  float* Rr  = falloc(640);
  float* Cc  = falloc(640);
  float* UU  = falloc(32000);
  float* VV  = falloc(32000);
  float* cff = falloc(262144);
  u16* cf   = (u16*)falloc(131072);
  u16* qb   = (u16*)falloc(131072);
  u16* kb   = (u16*)falloc(131072);
  u16* vtb  = (u16*)falloc(131072);
  u16* msgb = (u16*)falloc(131072);
  u16* sfpb = (u16*)falloc(131072);
  u16* wsb  = (u16*)falloc(1269760);

  int* IB = (int*)(FB + off);
  size_t ioff = 0;
  auto ialloc = [&](size_t n){ int* p = IB + ioff; ioff += (n + 63) & ~size_t(63); return p; };
  int* id_s = ialloc(NS);
  int* id_t = ialloc(NT);
  const int nbs = (NS + 255) / 256, nbt = (NT + 255) / 256;
  int* hist_s = ialloc((size_t)nbs * NODES);
  int* hist_t = ialloc((size_t)nbt * NODES);
  int* cnt_s = ialloc(NODES);
  int* cnt_t = ialloc(NODES);
  int* patch_s = ialloc(NODES*KP);
  int* patch_t = ialloc(NODES*KP);

  float* out0 = (float*)d_out;
  float* out_ls = out0 + ZDIM*ZDIM;
  float* out_gt = out_ls + (long)CC*65*65;

  u16* WcQ = wsb + 0;
  u16* WcK = wsb + 196608;
  u16* WcV = wsb + 393216;
  u16* WcM = wsb + 589824;
  u16* Wc1 = wsb + 786432;
  u16* Wc2 = wsb + 1572864;
  u16* Wfp = wsb + 1966080;
  u16* WlQ = wsb + 2031616;
  u16* WlK = wsb + 2080768;
  u16* WlV = wsb + 2129920;
  u16* WlM = wsb + 2179072;
  u16* Wl1 = wsb + 2228224;
  u16* Wl2 = wsb + 2424832;
  u16* Wlfp = wsb + 2523136;

  // sentinel fill for transport dataflow (Rr/Cc/UU/VV are contiguous)
  hipMemsetAsync(Rr, 0xFF, (640 + 640 + 32000 + 32000)*sizeof(float), stream);

  conv_weights<<<(2539520+255)/256, 256, 0, stream>>>(
      c_wq, c_wk, c_wv, c_wm, c_w1, c_w2, fp_w,
      l_wq, l_wk, l_wv, l_wm, l_w1, l_w2, lfp_w, wsb);

  // ---- NN + patches ----
  nn_hist_kernel<<<nbs + nbt, 256, 0, stream>>>(
      src_pcd_c, NS, src_node_c, id_s, hist_s,
      tgt_pcd_c, NT, tgt_node_c, id_t, hist_t, nbs);
  scan_kernel<<<2, 512, 0, stream>>>(hist_s, nbs, cnt_s, hist_t, nbt, cnt_t);
  hipMemsetAsync(patch_s, 0, NODES*KP*sizeof(int), stream);
  hipMemsetAsync(patch_t, 0, NODES*KP*sizeof(int), stream);
  rank_kernel<<<nbs + nbt, 256, 0, stream>>>(
      id_s, NS, hist_s, patch_s, id_t, NT, hist_t, patch_t, nbs);

  // ---- coarse transformer (sequential-cross semantics) ----
  tr_in<<<1024, 256, 0, stream>>>(src_feats, tgt_feats, cf, cff);
  int crossL[3] = {0, 1, 0};
  for (int l = 0; l < 3; ++l){
    u16* wq = WcQ + (size_t)l*65536; u16* wk = WcK + (size_t)l*65536;
    u16* wv = WcV + (size_t)l*65536; u16* wm = WcM + (size_t)l*65536;
    u16* w1 = Wc1 + (size_t)l*262144; u16* w2 = Wc2 + (size_t)l*131072;
    const float* bq = c_bq + (size_t)l*256; const float* bk = c_bk + (size_t)l*256;
    const float* bv = c_bv + (size_t)l*256; const float* bm = c_bm + (size_t)l*256;
    const float* b1 = c_b1 + (size_t)l*512; const float* b2 = c_b2 + (size_t)l*256;
    if (!crossL[l]){
      coarse_qkv<<<48, 256, 0, stream>>>(cf, 0, 0, wq, wk, wv, bq, bk, bv, qb, kb, vtb);
      coarse_attn<<<64, 256, 0, stream>>>(qb, kb, vtb, msgb, 0);
      coarse_ffn<<<16, 512, 0, stream>>>(msgb, cf, cff, wm, bm, w1, b1, w2, b2, 0);
    } else {
      for (int sd = 0; sd < 2; ++sd){
        coarse_qkv<<<24, 256, 0, stream>>>(cf, 1, sd, wq, wk, wv, bq, bk, bv, qb, kb, vtb);
        coarse_attn<<<32, 256, 0, stream>>>(qb, kb, vtb, msgb, sd);
        coarse_ffn<<<8, 512, 0, stream>>>(msgb, cf, cff, wm, bm, w1, b1, w2, b2, sd);
      }
    }
  }
  coarse_proj<<<16, 256, 0, stream>>>(cf, Wfp, fp_b, sfpb);
  coarse_scores<<<dim3(8,8), 256, 0, stream>>>(sfpb, sfpb + 131072, Zx);
  fill_border<<<3, 256, 0, stream>>>(Zx, bin_score);
  transpose_k<<<dim3(17,17), 256, 0, stream>>>(Zx, Zt, ZDIM);

  // ---- mega: transport ∥ full local pipeline ∥ gt ----
  mega<<<TPNB + CC + CC, 256, 0, stream>>>(
      Zx, Zt, Rr, Cc, UU, VV, out0, logf(1024.0f),
      src_final, tgt_final, patch_s, patch_t, node_corr, cnt_s, cnt_t,
      WlQ, WlK, WlV, WlM, Wl1, Wl2, Wlfp,
      l_bq, l_bk, l_bv, l_bm, l_b1, l_b2, lfp_b,
      out_ls,
      src_raw, tgt_raw, rot, trans, out_gt);

  (void)n_in; (void)out_size; (void)ws_size;
}

// Round 8
// 971.692 us; speedup vs baseline: 1.4461x; 1.4461x over previous
//
#include <hip/hip_runtime.h>
#include <math.h>

static constexpr int NODES = 512;
static constexpr int CC    = 256;
static constexpr int KP    = 64;
static constexpr int ZDIM  = 513;
static constexpr int TPNB  = 16;
static constexpr int TPROWS = 33;

typedef unsigned short u16;
typedef short bf16x8 __attribute__((ext_vector_type(8)));
typedef float f32x4 __attribute__((ext_vector_type(4)));

__device__ __forceinline__ u16 f2b(float f){
  unsigned u = __float_as_uint(f);
  unsigned r = (u + 0x7FFF + ((u >> 16) & 1)) >> 16;
  return (u16)r;
}
__device__ __forceinline__ float b2f(u16 h){ return __uint_as_float(((unsigned)h) << 16); }
__device__ __forceinline__ f32x4 mfma16(bf16x8 a, bf16x8 b, f32x4 c){
  return __builtin_amdgcn_mfma_f32_16x16x32_bf16(a, b, c, 0, 0, 0);
}
__device__ __forceinline__ void astore(float* p, float v){
  __hip_atomic_store(p, v, __ATOMIC_RELAXED, __HIP_MEMORY_SCOPE_AGENT);
}
__device__ __forceinline__ float fpoll(const float* p){
  const unsigned* up = (const unsigned*)p;
  unsigned v = __hip_atomic_load(up, __ATOMIC_RELAXED, __HIP_MEMORY_SCOPE_AGENT);
  while (v == 0xFFFFFFFFu)
    v = __hip_atomic_load(up, __ATOMIC_RELAXED, __HIP_MEMORY_SCOPE_AGENT);
  return __uint_as_float(v);
}
__device__ __forceinline__ void fpoll2(const float* p0, const float* p1,
                                       float* a, float* b){
  const unsigned* u0 = (const unsigned*)p0;
  const unsigned* u1 = (const unsigned*)p1;
  unsigned x = __hip_atomic_load(u0, __ATOMIC_RELAXED, __HIP_MEMORY_SCOPE_AGENT);
  unsigned y = __hip_atomic_load(u1, __ATOMIC_RELAXED, __HIP_MEMORY_SCOPE_AGENT);
  while (x == 0xFFFFFFFFu || y == 0xFFFFFFFFu){
    if (x == 0xFFFFFFFFu) x = __hip_atomic_load(u0, __ATOMIC_RELAXED, __HIP_MEMORY_SCOPE_AGENT);
    if (y == 0xFFFFFFFFu) y = __hip_atomic_load(u1, __ATOMIC_RELAXED, __HIP_MEMORY_SCOPE_AGENT);
  }
  *a = __uint_as_float(x); *b = __uint_as_float(y);
}

// ======================= prep: conv_weights ∥ nn_hist ∥ tr_in =======================
static constexpr int NBW = (2539520 + 255) / 256;   // 9920

__global__ __launch_bounds__(256) void prep(
  const float* cwq, const float* cwk, const float* cwv, const float* cwm,
  const float* cw1, const float* cw2, const float* fpw,
  const float* lwq, const float* lwk, const float* lwv, const float* lwm,
  const float* lw1, const float* lw2, const float* lfp, u16* __restrict__ dst,
  const float* __restrict__ pts_s, int ns, const float* __restrict__ nodes_s,
  int* __restrict__ id_s, int* __restrict__ hist_s,
  const float* __restrict__ pts_t, int ntt, const float* __restrict__ nodes_t,
  int* __restrict__ id_t, int* __restrict__ hist_t, int nbs, int nbnn,
  const float* __restrict__ fs, const float* __restrict__ ft,
  u16* __restrict__ cf, float* __restrict__ cff)
{
  int blk = blockIdx.x;
  int t = threadIdx.x;
  if (blk < NBW){
    int i = blk*256 + t;
    if (i >= 2539520) return;
    const float* s; int off;
    if      (i <  196608){ s=cwq; off=0; }
    else if (i <  393216){ s=cwk; off=196608; }
    else if (i <  589824){ s=cwv; off=393216; }
    else if (i <  786432){ s=cwm; off=589824; }
    else if (i < 1572864){ s=cw1; off=786432; }
    else if (i < 1966080){ s=cw2; off=1572864; }
    else if (i < 2031616){ s=fpw; off=1966080; }
    else if (i < 2080768){ s=lwq; off=2031616; }
    else if (i < 2129920){ s=lwk; off=2080768; }
    else if (i < 2179072){ s=lwv; off=2129920; }
    else if (i < 2228224){ s=lwm; off=2179072; }
    else if (i < 2424832){ s=lw1; off=2228224; }
    else if (i < 2523136){ s=lw2; off=2424832; }
    else                 { s=lfp; off=2523136; }
    dst[i] = f2b(s[i - off]);
    return;
  }
  if (blk < NBW + nbnn){
#pragma clang fp contract(off)
    __shared__ float nx[NODES], ny[NODES], nz[NODES], nn[NODES];
    __shared__ int h[NODES];
    int b2 = blk - NBW;
    const float* pts; const float* nodes; int* out; int* hist; int n; int bb;
    if (b2 < nbs){ pts=pts_s; nodes=nodes_s; out=id_s; hist=hist_s; n=ns; bb=b2; }
    else         { pts=pts_t; nodes=nodes_t; out=id_t; hist=hist_t; n=ntt; bb=b2-nbs; }
    for (int m = t; m < NODES; m += 256){
      float a = nodes[m*3+0], b = nodes[m*3+1], c = nodes[m*3+2];
      nx[m]=a; ny[m]=b; nz[m]=c;
      nn[m] = a*a + b*b + c*c;
      h[m] = 0;
    }
    __syncthreads();
    int i = bb*256 + t;
    if (i < n){
      float p0 = pts[i*3+0], p1 = pts[i*3+1], p2 = pts[i*3+2];
      float pp = p0*p0 + p1*p1 + p2*p2;
      float best = INFINITY; int bi = 0;
      for (int m = 0; m < NODES; ++m){
        float dot = fmaf(p2, nz[m], fmaf(p1, ny[m], p0*nx[m]));
        float d = (pp - 2.0f*dot) + nn[m];
        if (d < best){ best = d; bi = m; }
      }
      out[i] = bi;
      atomicAdd(&h[bi], 1);
    }
    __syncthreads();
    hist[(long)bb*NODES + t]       = h[t];
    hist[(long)bb*NODES + t + 256] = h[t+256];
    return;
  }
  {
    int i = (blk - NBW - nbnn)*256 + t;
    if (i >= 262144) return;
    int side = i >> 17; int r = i & 131071; int d = r >> 9; int n = r & 511;
    float v = (side ? ft : fs)[r];
    long o = ((long)side*512 + n)*256 + d;
    cf[o] = f2b(v);
    cff[o] = v;
  }
}

// ======================= parallel scan: 256 blocks, wave per node-task =======================
__global__ __launch_bounds__(256) void scan_kernel2(
    int* __restrict__ hist_s, int nbs, int* __restrict__ cnt_s,
    int* __restrict__ hist_t, int nbt, int* __restrict__ cnt_t)
{
  int task = blockIdx.x*4 + (threadIdx.x >> 6);
  int lane = threadIdx.x & 63;
  int which = task >> 9;
  int m = task & 511;
  int* hist = which ? hist_t : hist_s;
  int nb = which ? nbt : nbs;
  int* counts = which ? cnt_t : cnt_s;
  int chunk = (nb + 63) >> 6;          // ≤ 7 for nb ≤ 448
  int vals[7];
  int b0 = lane * chunk;
  int localsum = 0;
#pragma unroll
  for (int k = 0; k < 7; ++k){
    int b = b0 + k;
    int v = (k < chunk && b < nb) ? hist[(long)b*NODES + m] : 0;
    vals[k] = v; localsum += v;
  }
  int pre = localsum;
  for (int o = 1; o < 64; o <<= 1){
    int y = __shfl_up(pre, o);
    if (lane >= o) pre += y;
  }
  int total = __shfl(pre, 63);
  int run = pre - localsum;
#pragma unroll
  for (int k = 0; k < 7; ++k){
    int b = b0 + k;
    if (k < chunk && b < nb){ hist[(long)b*NODES + m] = run; run += vals[k]; }
  }
  if (lane == 0) counts[m] = total;
}

__global__ __launch_bounds__(256) void rank_kernel(
    const int* __restrict__ id_s, int ns, const int* __restrict__ hist_s, int* __restrict__ patch_s,
    const int* __restrict__ id_t, int ntt, const int* __restrict__ hist_t, int* __restrict__ patch_t,
    int nbs)
{
  __shared__ int lid[256];
  int blk = blockIdx.x;
  const int* id; const int* hist; int* patch; int n; int bb;
  if (blk < nbs){ id=id_s; hist=hist_s; patch=patch_s; n=ns; bb=blk; }
  else          { id=id_t; hist=hist_t; patch=patch_t; n=ntt; bb=blk-nbs; }
  int t = threadIdx.x;
  int i = bb*256 + t;
  lid[t] = (i < n) ? id[i] : -1;
  __syncthreads();
  if (i >= n) return;
  int m = lid[t];
  int r = hist[(long)bb*NODES + m];
  for (int q = 0; q < t; ++q) r += (lid[q] == m) ? 1 : 0;
  if (r < KP) patch[m*KP + r] = i;
}

// ======================= coarse transformer (bf16 MFMA, [n][d]) =======================
__global__ __launch_bounds__(256) void coarse_qkv(
    const u16* __restrict__ cf, int cross, int side0,
    const u16* __restrict__ Wq, const u16* __restrict__ Wk, const u16* __restrict__ Wv,
    const float* __restrict__ bq, const float* __restrict__ bk, const float* __restrict__ bv,
    u16* __restrict__ qb, u16* __restrict__ kb, u16* __restrict__ vtb)
{
  int z = blockIdx.x;
  int side = side0 + z/24, rem = z%24, proj = rem >> 3, slice = rem & 7;
  const u16* x = cf + (long)side*131072;
  const u16* s = cross ? cf + (long)(1-side)*131072 : x;
  const u16* in = (proj == 0) ? x : s;
  const u16* W  = (proj==0)?Wq:(proj==1)?Wk:Wv;
  const float* bi = (proj==0)?bq:(proj==1)?bk:bv;
  int n0 = slice << 6;
  int wv_ = threadIdx.x >> 6, L = threadIdx.x & 63, lr = L & 15, lk = L >> 4;
  const u16* inb = in + (long)(n0 + lr)*256 + 8*lk;
  for (int oi = 0; oi < 4; ++oi){
    int o0 = (wv_*4 + oi) << 4;
    const u16* wrow = W + (long)(o0 + lr)*256 + 8*lk;
    f32x4 acc[4] = {};
#pragma unroll
    for (int ks = 0; ks < 8; ++ks){
      bf16x8 b = *(const bf16x8*)(wrow + ks*32);
#pragma unroll
      for (int a = 0; a < 4; ++a){
        bf16x8 av = *(const bf16x8*)(inb + a*16*256 + ks*32);
        acc[a] = mfma16(av, b, acc[a]);
      }
    }
    int col = o0 + lr;
    float bvv = bi[col];
    if (proj < 2){
      u16* o = (proj==0 ? qb : kb) + ((long)side*512 + n0)*256 + col;
#pragma unroll
      for (int a = 0; a < 4; ++a)
#pragma unroll
        for (int q_ = 0; q_ < 4; ++q_)
          o[(long)(a*16 + lk*4 + q_)*256] = f2b(acc[a][q_] + bvv);
    } else {
      u16* o = vtb + ((long)side*256 + col)*512 + n0;
#pragma unroll
      for (int a = 0; a < 4; ++a)
#pragma unroll
        for (int q_ = 0; q_ < 4; ++q_)
          o[a*16 + lk*4 + q_] = f2b(acc[a][q_] + bvv);
    }
  }
}

__global__ __launch_bounds__(256) void coarse_attn(
    const u16* __restrict__ qb, const u16* __restrict__ kb,
    const u16* __restrict__ vtb, u16* __restrict__ msgb, int side0)
{
  __shared__ u16 P[64][512];
  __shared__ float rmx[64][4], rsm[64][4];
  int z = blockIdx.x;
  int side = side0 + (z >> 5); int rem = z & 31;
  int head = rem >> 3, qs = rem & 7;
  int wv_ = threadIdx.x >> 6, L = threadIdx.x & 63, lr = L & 15, lk = L >> 4;
  const u16* q = qb + ((long)side*512 + qs*64)*256 + head*64;
  const u16* k = kb + (long)side*512*256 + head*64;
  const u16* vt = vtb + ((long)side*256 + head*64)*512;

  bf16x8 af[4][2];
#pragma unroll
  for (int a = 0; a < 4; ++a)
#pragma unroll
    for (int ks = 0; ks < 2; ++ks)
      af[a][ks] = *(const bf16x8*)(q + (long)(a*16 + lr)*256 + ks*32 + 8*lk);

  f32x4 sc[4][8] = {};
  for (int b = 0; b < 8; ++b){
    const u16* krow = k + (long)(wv_*128 + b*16 + lr)*256 + 8*lk;
#pragma unroll
    for (int ks = 0; ks < 2; ++ks){
      bf16x8 bf = *(const bf16x8*)(krow + ks*32);
#pragma unroll
      for (int a = 0; a < 4; ++a)
        sc[a][b] = mfma16(af[a][ks], bf, sc[a][b]);
    }
  }
  const float SC = 0.125f;
#pragma unroll
  for (int a = 0; a < 4; ++a)
#pragma unroll
    for (int q_ = 0; q_ < 4; ++q_){
      float m = sc[a][0][q_];
#pragma unroll
      for (int b = 1; b < 8; ++b) m = fmaxf(m, sc[a][b][q_]);
      m = fmaxf(m, __shfl_xor(m, 1)); m = fmaxf(m, __shfl_xor(m, 2));
      m = fmaxf(m, __shfl_xor(m, 4)); m = fmaxf(m, __shfl_xor(m, 8));
      if (lr == 0) rmx[a*16 + lk*4 + q_][wv_] = m;
    }
  __syncthreads();
#pragma unroll
  for (int a = 0; a < 4; ++a)
#pragma unroll
    for (int q_ = 0; q_ < 4; ++q_){
      int row = a*16 + lk*4 + q_;
      float m = fmaxf(fmaxf(rmx[row][0], rmx[row][1]), fmaxf(rmx[row][2], rmx[row][3]));
      float s = 0.f;
#pragma unroll
      for (int b = 0; b < 8; ++b){
        float e = __expf((sc[a][b][q_] - m)*SC);
        sc[a][b][q_] = e; s += e;
      }
      s += __shfl_xor(s,1); s += __shfl_xor(s,2); s += __shfl_xor(s,4); s += __shfl_xor(s,8);
      if (lr == 0) rsm[row][wv_] = s;
    }
  __syncthreads();
#pragma unroll
  for (int a = 0; a < 4; ++a)
#pragma unroll
    for (int q_ = 0; q_ < 4; ++q_){
      int row = a*16 + lk*4 + q_;
      float inv = 1.f / (rsm[row][0]+rsm[row][1]+rsm[row][2]+rsm[row][3]);
#pragma unroll
      for (int b = 0; b < 8; ++b)
        P[row][wv_*128 + b*16 + lr] = f2b(sc[a][b][q_] * inv);
    }
  __syncthreads();
  f32x4 mv[4] = {};
  for (int ks = 0; ks < 16; ++ks){
    bf16x8 bf = *(const bf16x8*)(vt + (long)(wv_*16 + lr)*512 + ks*32 + 8*lk);
#pragma unroll
    for (int a = 0; a < 4; ++a){
      bf16x8 av = *(const bf16x8*)(&P[a*16 + lr][ks*32 + 8*lk]);
      mv[a] = mfma16(av, bf, mv[a]);
    }
  }
  u16* o = msgb + ((long)side*512 + qs*64)*256 + head*64 + wv_*16 + lr;
#pragma unroll
  for (int a = 0; a < 4; ++a)
#pragma unroll
    for (int q_ = 0; q_ < 4; ++q_)
      o[(long)(a*16 + lk*4 + q_)*256] = f2b(mv[a][q_]);
}

__global__ __launch_bounds__(512) void coarse_ffn(
    const u16* __restrict__ msgb, u16* __restrict__ cf, float* __restrict__ cff,
    const u16* __restrict__ Wm, const float* __restrict__ bm,
    const u16* __restrict__ W1, const float* __restrict__ b1,
    const u16* __restrict__ W2, const float* __restrict__ b2, int side0)
{
  __shared__ u16 m2[64*256];
  __shared__ u16 h1[64*512];
  int z = blockIdx.x;
  int side = side0 + (z >> 3), slice = z & 7;
  int wv_ = threadIdx.x >> 6, L = threadIdx.x & 63, lr = L & 15, lk = L >> 4;
  const u16* msg = msgb + ((long)side*512 + slice*64)*256;
  u16* x = cf + ((long)side*512 + slice*64)*256;
  float* xf = cff + ((long)side*512 + slice*64)*256;
  for (int oi = 0; oi < 2; ++oi){
    int o0 = (wv_*2 + oi) << 4;
    f32x4 acc[4] = {};
    const u16* wrow = Wm + (long)(o0+lr)*256 + 8*lk;
#pragma unroll
    for (int ks = 0; ks < 8; ++ks){
      bf16x8 b = *(const bf16x8*)(wrow + ks*32);
#pragma unroll
      for (int a = 0; a < 4; ++a){
        bf16x8 av = *(const bf16x8*)(msg + (long)(a*16+lr)*256 + ks*32 + 8*lk);
        acc[a] = mfma16(av, b, acc[a]);
      }
    }
    int col = o0 + lr; float bb = bm[col];
#pragma unroll
    for (int a = 0; a < 4; ++a)
#pragma unroll
      for (int q_ = 0; q_ < 4; ++q_)
        m2[(a*16+lk*4+q_)*256 + col] = f2b(acc[a][q_] + bb);
  }
  __syncthreads();
  for (int oi = 0; oi < 4; ++oi){
    int o0 = (wv_*4 + oi) << 4;
    f32x4 acc[4] = {};
    const u16* wrow = W1 + (long)(o0+lr)*512 + 8*lk;
#pragma unroll
    for (int ks = 0; ks < 16; ++ks){
      int kk = ks*32;
      bf16x8 b = *(const bf16x8*)(wrow + kk);
#pragma unroll
      for (int a = 0; a < 4; ++a){
        bf16x8 av;
        if (kk < 256) av = *(const bf16x8*)(x + (long)(a*16+lr)*256 + kk + 8*lk);
        else          av = *(const bf16x8*)(&m2[(a*16+lr)*256 + kk - 256 + 8*lk]);
        acc[a] = mfma16(av, b, acc[a]);
      }
    }
    int col = o0 + lr; float bb = b1[col];
#pragma unroll
    for (int a = 0; a < 4; ++a)
#pragma unroll
      for (int q_ = 0; q_ < 4; ++q_)
        h1[(a*16+lk*4+q_)*512 + col] = f2b(fmaxf(acc[a][q_] + bb, 0.f));
  }
  __syncthreads();
  for (int oi = 0; oi < 2; ++oi){
    int o0 = (wv_*2 + oi) << 4;
    f32x4 acc[4] = {};
    const u16* wrow = W2 + (long)(o0+lr)*512 + 8*lk;
#pragma unroll
    for (int ks = 0; ks < 16; ++ks){
      bf16x8 b = *(const bf16x8*)(wrow + ks*32);
#pragma unroll
      for (int a = 0; a < 4; ++a){
        bf16x8 av = *(const bf16x8*)(&h1[(a*16+lr)*512 + ks*32 + 8*lk]);
        acc[a] = mfma16(av, b, acc[a]);
      }
    }
    int col = o0 + lr; float bb = b2[col];
#pragma unroll
    for (int a = 0; a < 4; ++a)
#pragma unroll
      for (int q_ = 0; q_ < 4; ++q_){
        long idx = (long)(a*16+lk*4+q_)*256 + col;
        float v = acc[a][q_] + bb + xf[idx];
        xf[idx] = v;
        x[idx] = f2b(v);
      }
  }
}

__global__ __launch_bounds__(256) void coarse_proj(
    const u16* __restrict__ cf, const u16* __restrict__ W,
    const float* __restrict__ bias, u16* __restrict__ out)
{
  int z = blockIdx.x;
  int side = z >> 3, slice = z & 7;
  const u16* in = cf + (long)side*131072;
  u16* o = out + (long)side*131072;
  int n0 = slice << 6;
  int wv_ = threadIdx.x >> 6, L = threadIdx.x & 63, lr = L & 15, lk = L >> 4;
  const u16* inb = in + (long)(n0 + lr)*256 + 8*lk;
  for (int oi = 0; oi < 4; ++oi){
    int o0 = (wv_*4 + oi) << 4;
    const u16* wrow = W + (long)(o0 + lr)*256 + 8*lk;
    f32x4 acc[4] = {};
#pragma unroll
    for (int ks = 0; ks < 8; ++ks){
      bf16x8 b = *(const bf16x8*)(wrow + ks*32);
#pragma unroll
      for (int a = 0; a < 4; ++a){
        bf16x8 av = *(const bf16x8*)(inb + a*16*256 + ks*32);
        acc[a] = mfma16(av, b, acc[a]);
      }
    }
    int col = o0 + lr; float bb = bias[col];
#pragma unroll
    for (int a = 0; a < 4; ++a)
#pragma unroll
      for (int q_ = 0; q_ < 4; ++q_)
        o[(long)(n0 + a*16 + lk*4 + q_)*256 + col] = f2b(acc[a][q_] + bb);
  }
}

__global__ __launch_bounds__(256) void coarse_scores(
    const u16* __restrict__ sfp, const u16* __restrict__ tfp, float* __restrict__ Z)
{
  int n0 = blockIdx.y << 6, m0 = blockIdx.x << 6;
  int wv_ = threadIdx.x >> 6, L = threadIdx.x & 63, lr = L & 15, lk = L >> 4;
  f32x4 acc[4] = {};
  const u16* arow = sfp + (long)(n0 + lr)*256 + 8*lk;
  const u16* brow = tfp + (long)(m0 + wv_*16 + lr)*256 + 8*lk;
#pragma unroll
  for (int ks = 0; ks < 8; ++ks){
    bf16x8 b = *(const bf16x8*)(brow + ks*32);
#pragma unroll
    for (int a = 0; a < 4; ++a){
      bf16x8 av = *(const bf16x8*)(arow + a*16*256 + ks*32);
      acc[a] = mfma16(av, b, acc[a]);
    }
  }
  int col = m0 + wv_*16 + lr;
#pragma unroll
  for (int a = 0; a < 4; ++a)
#pragma unroll
    for (int q_ = 0; q_ < 4; ++q_)
      Z[(long)(n0 + a*16 + lk*4 + q_)*513 + col] = acc[a][q_]*0.0625f;
}

__global__ __launch_bounds__(256) void fill_border(float* Z, const float* __restrict__ alpha)
{
  int i = blockIdx.x*256 + threadIdx.x;
  if (i < ZDIM){
    float a = alpha[0];
    Z[(long)i*ZDIM + (ZDIM-1)] = a;
    Z[(long)(ZDIM-1)*ZDIM + i] = a;
  }
}

__global__ __launch_bounds__(256) void transpose_k(const float* __restrict__ A,
                                                   float* __restrict__ B, int n)
{
  __shared__ float t[32][33];
  int bx = blockIdx.x*32, by = blockIdx.y*32;
  int lx = threadIdx.x & 31, ly0 = threadIdx.x >> 5;
  for (int dy = 0; dy < 32; dy += 8){
    int x = bx + lx, y = by + ly0 + dy;
    if (x < n && y < n) t[ly0+dy][lx] = A[(long)y*n + x];
  }
  __syncthreads();
  for (int dy = 0; dy < 32; dy += 8){
    int x = by + lx, y = bx + ly0 + dy;
    if (x < n && y < n) B[(long)y*n + x] = t[lx][ly0+dy];
  }
}

// ======================= mega kernel roles (512 threads) =======================
static constexpr int ARENA = 142336;

// ---- transport role (XCD-pinned blocks, 512 threads, sentinel dataflow) ----
__device__ void transport_role(char* arena, int bid,
    const float* __restrict__ Z, const float* __restrict__ Zt,
    float* Rr, float* Cc, float* UU, float* VV,
    float* __restrict__ out, float outadd)
{
  float* A = (float*)arena;
  float* B = A + TPROWS*513;
  float* RrL = B + TPROWS*513;
  float* CcL = RrL + 513;
  float* M   = CcL + 513;
  float* rown = M + 513;
  float* cown = rown + TPROWS;
  float* uown = cown + TPROWS;
  int tid = threadIdx.x;
  int wv_ = tid >> 6, lane = tid & 63;
  int r0 = bid * TPROWS;
  int nr = 513 - r0; if (nr > TPROWS) nr = TPROWS;

  for (int i = wv_; i < nr; i += 8){
    const float* zr  = Z  + (long)(r0+i)*513;
    const float* ztr = Zt + (long)(r0+i)*513;
    for (int j = lane; j < 513; j += 64){ A[i*513+j] = zr[j]; B[i*513+j] = ztr[j]; }
  }
  __syncthreads();
  for (int i = wv_; i < nr; i += 8){
    float m = -INFINITY;
    for (int j = lane; j < 513; j += 64) m = fmaxf(m, A[i*513+j]);
    for (int o = 32; o; o >>= 1) m = fmaxf(m, __shfl_xor(m, o));
    if (lane == 0){ rown[i] = m; astore(&Rr[r0+i], m); }
  }
  if (tid == 0)      fpoll2(&Rr[0], &Rr[512], &RrL[0], &RrL[512]);
  else if (tid < 512) RrL[tid] = fpoll(&Rr[tid]);
  __syncthreads();
  for (int i = wv_; i < nr; i += 8){
    float m = -INFINITY;
    for (int j = lane; j < 513; j += 64) m = fmaxf(m, B[i*513+j] - RrL[j]);
    for (int o = 32; o; o >>= 1) m = fmaxf(m, __shfl_xor(m, o));
    if (lane == 0){ cown[i] = m; astore(&Cc[r0+i], m); }
  }
  if (tid == 0)      fpoll2(&Cc[0], &Cc[512], &CcL[0], &CcL[512]);
  else if (tid < 512) CcL[tid] = fpoll(&Cc[tid]);
  __syncthreads();
  for (int i = wv_; i < nr; i += 8){
    float ro = rown[i], co = cown[i];
    for (int j = lane; j < 513; j += 64){
      A[i*513+j] = __expf(A[i*513+j] - ro - CcL[j]);
      B[i*513+j] = __expf(B[i*513+j] - co - RrL[j]);
    }
  }
  __syncthreads();
  const float EBM = 1.0f/1024.0f, EBL = 0.5f;
  for (int i = wv_; i < nr; i += 8){
    float s = 0.f;
    for (int j = lane; j < 513; j += 64) s += A[i*513+j];
    for (int o = 32; o; o >>= 1) s += __shfl_xor(s, o);
    if (lane == 0){
      int r = r0+i; float u = ((r < 512) ? EBM : EBL) / s;
      uown[i] = u; astore(&UU[r], u);
    }
  }
  for (int it = 0; it < 50; ++it){
    const float* src = &UU[(long)it*640];
    if (tid == 0)      fpoll2(&src[0], &src[512], &M[0], &M[512]);
    else if (tid < 512) M[tid] = fpoll(&src[tid]);
    __syncthreads();
    for (int i = wv_; i < nr; i += 8){
      float s = 0.f;
      for (int j = lane; j < 513; j += 64) s = fmaf(B[i*513+j], M[j], s);
      for (int o = 32; o; o >>= 1) s += __shfl_xor(s, o);
      if (lane == 0){
        int r = r0+i;
        astore(&VV[(long)it*640 + r], ((r < 512) ? EBM : EBL) / s);
      }
    }
    __syncthreads();
    if (it == 49) break;
    const float* srcv = &VV[(long)it*640];
    if (tid == 0)      fpoll2(&srcv[0], &srcv[512], &M[0], &M[512]);
    else if (tid < 512) M[tid] = fpoll(&srcv[tid]);
    __syncthreads();
    for (int i = wv_; i < nr; i += 8){
      float s = 0.f;
      for (int j = lane; j < 513; j += 64) s = fmaf(A[i*513+j], M[j], s);
      for (int o = 32; o; o >>= 1) s += __shfl_xor(s, o);
      if (lane == 0){
        int r = r0+i; float u = ((r < 512) ? EBM : EBL) / s;
        uown[i] = u; astore(&UU[(long)(it+1)*640 + r], u);
      }
    }
    __syncthreads();
  }
  {
    const float* srcv = &VV[49L*640];
    if (tid == 0)      fpoll2(&srcv[0], &srcv[512], &M[0], &M[512]);
    else if (tid < 512) M[tid] = fpoll(&srcv[tid]);
  }
  __syncthreads();
  for (int j = tid; j < 513; j += 512) M[j] = __logf(M[j]) - CcL[j];
  __syncthreads();
  for (int i = wv_; i < nr; i += 8){
    int r = r0 + i;
    float uu = __logf(uown[i]) - rown[i];
    const float* zr = Z + (long)r*513;
    float* orow = out + (long)r*513;
    for (int j = lane; j < 513; j += 64) orow[j] = zr[j] + uu + M[j] + outadd;
  }
}

// ---- local layer application (512 threads, x/s in LDS) ----
__device__ void layerapp(
    u16* __restrict__ x, const u16* __restrict__ s, u16* __restrict__ pool,
    const u16* __restrict__ Wq, const u16* __restrict__ Wk,
    const u16* __restrict__ Wv, const u16* __restrict__ Wm,
    const u16* __restrict__ W1, const u16* __restrict__ W2,
    const float* __restrict__ bq, const float* __restrict__ bk,
    const float* __restrict__ bv, const float* __restrict__ bm,
    const float* __restrict__ b1, const float* __restrict__ b2)
{
  int tid = threadIdx.x;
  int wv8 = tid >> 6, L = tid & 63, lr = L & 15, lk = L >> 4;
  u16* qS = pool; u16* kS = pool + 8192; u16* vT = pool + 16384; u16* msgS = pool + 24576;

  // qkv: 8 o-tiles, one per wave, per proj
#pragma unroll
  for (int proj = 0; proj < 3; ++proj){
    const u16* in = proj ? s : x;
    const u16* W = proj==0?Wq:proj==1?Wk:Wv;
    const float* bi = proj==0?bq:proj==1?bk:bv;
    int o0 = wv8 << 4;
    f32x4 acc[4] = {};
    const u16* wrow = W + (long)(o0+lr)*128 + 8*lk;
    const u16* inr = in + (long)lr*128 + 8*lk;
#pragma unroll
    for (int ks = 0; ks < 4; ++ks){
      bf16x8 b = *(const bf16x8*)(wrow + ks*32);
#pragma unroll
      for (int a = 0; a < 4; ++a){
        bf16x8 av = *(const bf16x8*)(inr + a*16*128 + ks*32);
        acc[a] = mfma16(av, b, acc[a]);
      }
    }
    int col = o0 + lr; float bb = bi[col];
    if (proj < 2){
      u16* dst = (proj==0 ? qS : kS);
#pragma unroll
      for (int a = 0; a < 4; ++a)
#pragma unroll
        for (int q_ = 0; q_ < 4; ++q_)
          dst[(a*16 + lk*4 + q_)*128 + col] = f2b(acc[a][q_] + bb);
    } else {
#pragma unroll
      for (int a = 0; a < 4; ++a)
#pragma unroll
        for (int q_ = 0; q_ < 4; ++q_)
          vT[col*64 + a*16 + lk*4 + q_] = f2b(acc[a][q_] + bb);
    }
  }
  __syncthreads();
  // scores: head h = wv8>>1, half of a-tiles per wave
  int h = wv8 >> 1, half = wv8 & 1;
  bf16x8 qf[2], kf[4];
#pragma unroll
  for (int ai = 0; ai < 2; ++ai){
    int a = half*2 + ai;
    qf[ai] = *(const bf16x8*)(&qS[(a*16+lr)*128 + h*32 + 8*lk]);
  }
#pragma unroll
  for (int b = 0; b < 4; ++b)
    kf[b] = *(const bf16x8*)(&kS[(b*16+lr)*128 + h*32 + 8*lk]);
  f32x4 sc[2][4] = {};
#pragma unroll
  for (int b = 0; b < 4; ++b)
#pragma unroll
    for (int ai = 0; ai < 2; ++ai)
      sc[ai][b] = mfma16(qf[ai], kf[b], sc[ai][b]);
  const float SCs = 0.17677669529663687f;
  float invs[2][4];
#pragma unroll
  for (int ai = 0; ai < 2; ++ai)
#pragma unroll
    for (int q_ = 0; q_ < 4; ++q_){
      float m = sc[ai][0][q_];
#pragma unroll
      for (int b = 1; b < 4; ++b) m = fmaxf(m, sc[ai][b][q_]);
      m = fmaxf(m, __shfl_xor(m, 1)); m = fmaxf(m, __shfl_xor(m, 2));
      m = fmaxf(m, __shfl_xor(m, 4)); m = fmaxf(m, __shfl_xor(m, 8));
      float ss = 0.f;
#pragma unroll
      for (int b = 0; b < 4; ++b){
        float e = __expf((sc[ai][b][q_] - m)*SCs);
        sc[ai][b][q_] = e; ss += e;
      }
      ss += __shfl_xor(ss,1); ss += __shfl_xor(ss,2); ss += __shfl_xor(ss,4); ss += __shfl_xor(ss,8);
      invs[ai][q_] = 1.f/ss;
    }
  __syncthreads();   // all qS/kS reads done before P overwrites
  u16* P = pool + h*4096;
#pragma unroll
  for (int ai = 0; ai < 2; ++ai){
    int a = half*2 + ai;
#pragma unroll
    for (int q_ = 0; q_ < 4; ++q_)
#pragma unroll
      for (int b = 0; b < 4; ++b)
        P[(a*16 + lk*4 + q_)*64 + b*16 + lr] = f2b(sc[ai][b][q_] * invs[ai][q_]);
  }
  f32x4 mv[2][2] = {};
#pragma unroll
  for (int ks = 0; ks < 2; ++ks)
#pragma unroll
    for (int bt = 0; bt < 2; ++bt){
      bf16x8 bf = *(const bf16x8*)(&vT[(h*32 + bt*16 + lr)*64 + ks*32 + 8*lk]);
#pragma unroll
      for (int ai = 0; ai < 2; ++ai){
        int a = half*2 + ai;
        bf16x8 av = *(const bf16x8*)(&P[(a*16+lr)*64 + ks*32 + 8*lk]);
        mv[ai][bt] = mfma16(av, bf, mv[ai][bt]);
      }
    }
#pragma unroll
  for (int ai = 0; ai < 2; ++ai){
    int a = half*2 + ai;
#pragma unroll
    for (int bt = 0; bt < 2; ++bt)
#pragma unroll
      for (int q_ = 0; q_ < 4; ++q_)
        msgS[(a*16 + lk*4 + q_)*128 + h*32 + bt*16 + lr] = f2b(mv[ai][bt][q_]);
  }
  __syncthreads();
  // wm: 8 o-tiles, one per wave
  u16* m2 = pool;
  {
    int o0 = wv8 << 4;
    f32x4 acc[4] = {};
    const u16* wrow = Wm + (long)(o0+lr)*128 + 8*lk;
#pragma unroll
    for (int ks = 0; ks < 4; ++ks){
      bf16x8 b = *(const bf16x8*)(wrow + ks*32);
#pragma unroll
      for (int a = 0; a < 4; ++a){
        bf16x8 av = *(const bf16x8*)(&msgS[(a*16+lr)*128 + ks*32 + 8*lk]);
        acc[a] = mfma16(av, b, acc[a]);
      }
    }
    int col = o0+lr; float bb = bm[col];
#pragma unroll
    for (int a = 0; a < 4; ++a)
#pragma unroll
      for (int q_ = 0; q_ < 4; ++q_)
        m2[(a*16+lk*4+q_)*128 + col] = f2b(acc[a][q_] + bb);
  }
  __syncthreads();
  // w1: 16 o-tiles over 8 waves (2 each), relu
  u16* h1 = pool + 8192;
#pragma unroll
  for (int oi = 0; oi < 2; ++oi){
    int o0 = (wv8*2 + oi) << 4;
    f32x4 acc[4] = {};
    const u16* wrow = W1 + (long)(o0+lr)*256 + 8*lk;
#pragma unroll
    for (int ks = 0; ks < 8; ++ks){
      int kk = ks*32;
      bf16x8 b = *(const bf16x8*)(wrow + kk);
#pragma unroll
      for (int a = 0; a < 4; ++a){
        bf16x8 av;
        if (kk < 128) av = *(const bf16x8*)(x + (long)(a*16+lr)*128 + kk + 8*lk);
        else          av = *(const bf16x8*)(&m2[(a*16+lr)*128 + kk - 128 + 8*lk]);
        acc[a] = mfma16(av, b, acc[a]);
      }
    }
    int col = o0+lr; float bb = b1[col];
#pragma unroll
    for (int a = 0; a < 4; ++a)
#pragma unroll
      for (int q_ = 0; q_ < 4; ++q_)
        h1[(a*16+lk*4+q_)*256 + col] = f2b(fmaxf(acc[a][q_] + bb, 0.f));
  }
  __syncthreads();
  // w2 + residual: 8 o-tiles, one per wave
  {
    int o0 = wv8 << 4;
    f32x4 acc[4] = {};
    const u16* wrow = W2 + (long)(o0+lr)*256 + 8*lk;
#pragma unroll
    for (int ks = 0; ks < 8; ++ks){
      bf16x8 b = *(const bf16x8*)(wrow + ks*32);
#pragma unroll
      for (int a = 0; a < 4; ++a){
        bf16x8 av = *(const bf16x8*)(&h1[(a*16+lr)*256 + ks*32 + 8*lk]);
        acc[a] = mfma16(av, b, acc[a]);
      }
    }
    int col = o0+lr; float bb = b2[col];
#pragma unroll
    for (int a = 0; a < 4; ++a)
#pragma unroll
      for (int q_ = 0; q_ < 4; ++q_){
        int ri = (a*16+lk*4+q_)*128 + col;
        x[ri] = f2b(acc[a][q_] + bb + b2f(x[ri]));
      }
  }
  __syncthreads();
}

// ---- local role: full per-patch pipeline (512 threads) ----
__device__ void local_role(char* arena, int c,
    const float* __restrict__ Fs, const float* __restrict__ Ft,
    const int* __restrict__ patch_s, const int* __restrict__ patch_t,
    const int* __restrict__ corr,
    const int* __restrict__ cnt_s, const int* __restrict__ cnt_t,
    const u16* WlQ, const u16* WlK, const u16* WlV, const u16* WlM,
    const u16* Wl1, const u16* Wl2, const u16* Wlfp,
    const float* lbq, const float* lbk, const float* lbv, const float* lbm,
    const float* lb1, const float* lb2, const float* lfpB,
    float* __restrict__ out_ls)
{
  u16* X    = (u16*)arena;                 // [2][64][128] bf16 (32 KB)
  u16* pool = (u16*)(arena + 32768);       // 64 KB
  float* LA = (float*)(arena + 98304);
  float* ET = (float*)(arena + 115712);
  float* uvec = (float*)(arena + 133120);
  float* vvec = (float*)(arena + 133440);
  float* u0s  = (float*)(arena + 133760);
  float* Ul   = (float*)(arena + 134080);
  float* Vl   = (float*)(arena + 134400);
  int* sel    = (int*)(arena + 134720);
  int tid = threadIdx.x;
  int wv8 = tid >> 6, L = tid & 63, lr = L & 15, lk = L >> 4;

  if (tid < 128){
    int side = tid >> 6, n = tid & 63;
    int node = corr[c*2 + side];
    sel[tid] = (side ? patch_t : patch_s)[node*KP + n];
  }
  __syncthreads();
  for (int e = tid; e < 16384; e += 512){
    int side = e >> 13, r = e & 8191, n = r >> 7, d = r & 127;
    const float* F = side ? Ft : Fs;
    X[e] = f2b(F[(long)sel[side*64 + n]*128 + d]);
  }
  __syncthreads();

  for (int l = 0; l < 3; ++l){
    const u16* wq = WlQ + (size_t)l*16384; const u16* wk = WlK + (size_t)l*16384;
    const u16* wv = WlV + (size_t)l*16384; const u16* wm = WlM + (size_t)l*16384;
    const u16* w1 = Wl1 + (size_t)l*65536; const u16* w2 = Wl2 + (size_t)l*32768;
    const float* bq = lbq + (size_t)l*128; const float* bk = lbk + (size_t)l*128;
    const float* bv = lbv + (size_t)l*128; const float* bm = lbm + (size_t)l*128;
    const float* b1 = lb1 + (size_t)l*256; const float* b2 = lb2 + (size_t)l*128;
    int cross = (l == 1);
    layerapp(X,        X + (cross ? 8192 : 0), pool, wq,wk,wv,wm,w1,w2, bq,bk,bv,bm,b1,b2);
    layerapp(X + 8192, X + (cross ? 0 : 8192), pool, wq,wk,wv,wm,w1,w2, bq,bk,bv,bm,b1,b2);
  }

  // lfp projection -> sp/tp (16 tiles over 8 waves)
  u16* sp = pool; u16* tp = pool + 8192;
  for (int u_ = wv8; u_ < 16; u_ += 8){
    int sideSel = u_ >> 3, ot = u_ & 7;
    const u16* in = X + sideSel*8192;
    u16* dst = sideSel ? tp : sp;
    int o0 = ot << 4;
    f32x4 acc[4] = {};
    const u16* wrow = Wlfp + (long)(o0+lr)*128 + 8*lk;
    const u16* inr = in + (long)lr*128 + 8*lk;
#pragma unroll
    for (int ks = 0; ks < 4; ++ks){
      bf16x8 b = *(const bf16x8*)(wrow + ks*32);
#pragma unroll
      for (int a = 0; a < 4; ++a){
        bf16x8 av = *(const bf16x8*)(inr + a*16*128 + ks*32);
        acc[a] = mfma16(av, b, acc[a]);
      }
    }
    int col = o0 + lr; float bb = lfpB[col];
#pragma unroll
    for (int a = 0; a < 4; ++a)
#pragma unroll
      for (int q_ = 0; q_ < 4; ++q_)
        dst[(a*16 + lk*4 + q_)*128 + col] = f2b(acc[a][q_] + bb);
  }
  __syncthreads();

  // scores -> LA (masked), 16 tiles over 8 waves
  int cs = cnt_s[corr[c*2]], ct = cnt_t[corr[c*2+1]];
  for (int t_ = wv8; t_ < 16; t_ += 8){
    int mt = t_ >> 2, nt = t_ & 3;
    f32x4 acc = {};
    const u16* arow = sp + (mt*16 + lr)*128 + 8*lk;
    const u16* brow = tp + (nt*16 + lr)*128 + 8*lk;
#pragma unroll
    for (int ks = 0; ks < 4; ++ks){
      bf16x8 a = *(const bf16x8*)(arow + ks*32);
      bf16x8 b = *(const bf16x8*)(brow + ks*32);
      acc = mfma16(a, b, acc);
    }
    const float SCS = 0.08838834764831845f;
#pragma unroll
    for (int q_ = 0; q_ < 4; ++q_){
      int row = mt*16 + lk*4 + q_;
      int col = nt*16 + lr;
      float v = acc[q_] * SCS;
      if (row >= cs || col >= ct) v = -1000000.0f;
      LA[row*66 + col] = v;
    }
  }
  if (tid < 65){ LA[64*66 + tid] = 0.f; LA[tid*66 + 64] = 0.f; uvec[tid] = 1.f; vvec[tid] = 1.f; }
  __syncthreads();

  // initial row pass (log domain); E overlays sp/tp
  float* E = (float*)pool;
  int g = tid >> 3, sub = tid & 7;
  {
    float mx = -INFINITY;
    for (int j = sub; j < 65; j += 8) mx = fmaxf(mx, LA[g*66 + j]);
    mx = fmaxf(mx, __shfl_xor(mx, 1)); mx = fmaxf(mx, __shfl_xor(mx, 2));
    mx = fmaxf(mx, __shfl_xor(mx, 4));
    float s = 0.f;
    for (int j = sub; j < 65; j += 8) s += __expf(LA[g*66 + j] - mx);
    s += __shfl_xor(s, 1); s += __shfl_xor(s, 2); s += __shfl_xor(s, 4);
    float u0 = mx + __logf(s);
    if (sub == 0) u0s[g] = u0;
    for (int j = sub; j < 65; j += 8){
      float e = __expf(LA[g*66 + j] - u0);
      E[g*66 + j] = e;
      ET[j*66 + g] = e;
    }
  }
  if (tid < 65){
    E[64*66 + tid] = 1.f;
    ET[tid*66 + 64] = 1.f;
    if (tid == 64) u0s[64] = 0.f;
  }
  __syncthreads();
  for (int it = 0; it < 50; ++it){
    {
      float s = 0.f;
      for (int r = sub; r < 65; r += 8) s = fmaf(ET[g*66 + r], uvec[r], s);
      s += __shfl_xor(s, 1); s += __shfl_xor(s, 2); s += __shfl_xor(s, 4);
      if (sub == 0) vvec[g] = 1.f / s;
    }
    __syncthreads();
    if (it == 49) break;
    {
      float s = 0.f;
      for (int j = sub; j < 65; j += 8) s = fmaf(E[g*66 + j], vvec[j], s);
      s += __shfl_xor(s, 1); s += __shfl_xor(s, 2); s += __shfl_xor(s, 4);
      if (sub == 0) uvec[g] = 1.f / s;
    }
    __syncthreads();
  }
  __syncthreads();
  if (tid < 65){ Ul[tid] = u0s[tid] - __logf(uvec[tid]); Vl[tid] = -__logf(vvec[tid]); }
  __syncthreads();
  for (int e = tid; e < 4225; e += 512){
    int r = e / 65, c2 = e % 65;
    out_ls[(long)c*4225 + e] = LA[r*66 + c2] - Ul[r] - Vl[c2];
  }
}

// ---- gt role (512 threads) ----
__device__ void gt_role(char* arena, int c,
    const float* __restrict__ sraw, const float* __restrict__ traw,
    const float* __restrict__ rot, const float* __restrict__ trans,
    const int* __restrict__ patch_s, const int* __restrict__ patch_t,
    const int* __restrict__ corr,
    const int* __restrict__ cnt_s, const int* __restrict__ cnt_t,
    float* __restrict__ out)
{
#pragma clang fp contract(off)
  float* sx = (float*)arena;         float* sy = sx + 64;
  float* sz = sy + 64;               float* spp = sz + 64;
  float* txa = spp + 64;             float* tya = txa + 64;
  float* tza = tya + 64;             float* tpp = tza + 64;
  float* g   = tpp + 64;
  float* rowsum = g + 64*65;
  float* colsum = rowsum + 64;
  int tid = threadIdx.x;
  int sn = corr[c*2], tn = corr[c*2+1];
  int cs = cnt_s[sn], ct = cnt_t[tn];
  if (tid < 64){
    int idx = patch_s[sn*KP + tid];
    float p0 = sraw[(long)idx*3], p1 = sraw[(long)idx*3+1], p2 = sraw[(long)idx*3+2];
    float a0 = fmaf(rot[2], p2, fmaf(rot[1], p1, rot[0]*p0)) + trans[0];
    float a1 = fmaf(rot[5], p2, fmaf(rot[4], p1, rot[3]*p0)) + trans[1];
    float a2 = fmaf(rot[8], p2, fmaf(rot[7], p1, rot[6]*p0)) + trans[2];
    sx[tid]=a0; sy[tid]=a1; sz[tid]=a2;
    spp[tid] = a0*a0 + a1*a1 + a2*a2;
  } else if (tid < 128){
    int l = tid - 64;
    int idx = patch_t[tn*KP + l];
    float p0 = traw[(long)idx*3], p1 = traw[(long)idx*3+1], p2 = traw[(long)idx*3+2];
    txa[l]=p0; tya[l]=p1; tza[l]=p2;
    tpp[l] = p0*p0 + p1*p1 + p2*p2;
  }
  __syncthreads();
  for (int e = tid; e < 4096; e += 512){
    int n = e >> 6, m = e & 63;
    float dot = fmaf(sz[n], tza[m], fmaf(sy[n], tya[m], sx[n]*txa[m]));
    float d2 = (spp[n] + tpp[m]) - 2.0f*dot;
    d2 = fmaxf(d2, 0.f);
    g[n*65 + m] = (sqrtf(d2) < 0.1f) ? 1.f : 0.f;
  }
  __syncthreads();
  if (tid < 64){
    float s = 0.f;
    for (int m = 0; m < 64; ++m) s += g[tid*65 + m];
    rowsum[tid] = fmaxf(1.f - s, 0.f);
  } else if (tid < 128){
    int m = tid - 64;
    float s = 0.f;
    for (int n = 0; n < 64; ++n) s += g[n*65 + m];
    colsum[m] = fmaxf(1.f - s, 0.f);
  }
  __syncthreads();
  float* o = out + (long)c*4225;
  for (int e = tid; e < 4225; e += 512){
    int r = e / 65, col = e % 65;
    float v;
    if (r < 64 && col < 64) v = g[r*65 + col];
    else if (r < 64)        v = rowsum[r];
    else if (col < 64)      v = colsum[col];
    else                    v = 0.f;
    if (r < 64 && r >= cs)    v = 0.f;
    if (col < 64 && col >= ct) v = 0.f;
    o[e] = v;
  }
}

// ---- mega kernel: transport (XCD-pinned) ∥ gt ∥ local ----
__global__ __launch_bounds__(512) void mega(
    const float* Z, const float* Zt, float* Rr, float* Cc, float* UU, float* VV,
    float* out0, float outadd,
    const float* Fs, const float* Ft,
    const int* patch_s, const int* patch_t, const int* corr,
    const int* cnt_s, const int* cnt_t,
    const u16* WlQ, const u16* WlK, const u16* WlV, const u16* WlM,
    const u16* Wl1, const u16* Wl2, const u16* Wlfp,
    const float* lbq, const float* lbk, const float* lbv, const float* lbm,
    const float* lb1, const float* lb2, const float* lfpB,
    float* out_ls,
    const float* sraw, const float* traw, const float* rot, const float* trans,
    float* out_gt)
{
  __shared__ __align__(16) char arena[ARENA];
  int b = blockIdx.x;
  if (b < 128){
    if ((b & 7) == 0)     // pin all transport blocks onto one XCD (round-robin map)
      transport_role(arena, b >> 3, Z, Zt, Rr, Cc, UU, VV, out0, outadd);
    return;
  }
  b -= 128;
  if (b < CC)
    gt_role(arena, b, sraw, traw, rot, trans,
            patch_s, patch_t, corr, cnt_s, cnt_t, out_gt);
  else
    local_role(arena, b - CC, Fs, Ft, patch_s, patch_t, corr, cnt_s, cnt_t,
               WlQ, WlK, WlV, WlM, Wl1, Wl2, Wlfp,
               lbq, lbk, lbv, lbm, lb1, lb2, lfpB, out_ls);
}

// ======================= host =======================
extern "C" void kernel_launch(void* const* d_in, const int* in_sizes, int n_in,
                              void* d_out, int out_size, void* d_ws, size_t ws_size,
                              hipStream_t stream)
{
  const float* src_pcd_c  = (const float*)d_in[0];
  const float* tgt_pcd_c  = (const float*)d_in[1];
  const float* src_node_c = (const float*)d_in[2];
  const float* tgt_node_c = (const float*)d_in[3];
  const float* src_feats  = (const float*)d_in[4];
  const float* tgt_feats  = (const float*)d_in[5];
  const float* src_final  = (const float*)d_in[6];
  const float* tgt_final  = (const float*)d_in[7];
  const float* rot        = (const float*)d_in[8];
  const float* trans      = (const float*)d_in[9];
  const float* src_raw    = (const float*)d_in[10];
  const float* tgt_raw    = (const float*)d_in[11];
  const int*   node_corr  = (const int*)d_in[12];
  const float* c_wq = (const float*)d_in[13]; const float* c_bq = (const float*)d_in[14];
  const float* c_wk = (const float*)d_in[15]; const float* c_bk = (const float*)d_in[16];
  const float* c_wv = (const float*)d_in[17]; const float* c_bv = (const float*)d_in[18];
  const float* c_wm = (const float*)d_in[19]; const float* c_bm = (const float*)d_in[20];
  const float* c_w1 = (const float*)d_in[21]; const float* c_b1 = (const float*)d_in[22];
  const float* c_w2 = (const float*)d_in[23]; const float* c_b2 = (const float*)d_in[24];
  const float* l_wq = (const float*)d_in[25]; const float* l_bq = (const float*)d_in[26];
  const float* l_wk = (const float*)d_in[27]; const float* l_bk = (const float*)d_in[28];
  const float* l_wv = (const float*)d_in[29]; const float* l_bv = (const float*)d_in[30];
  const float* l_wm = (const float*)d_in[31]; const float* l_bm = (const float*)d_in[32];
  const float* l_w1 = (const float*)d_in[33]; const float* l_b1 = (const float*)d_in[34];
  const float* l_w2 = (const float*)d_in[35]; const float* l_b2 = (const float*)d_in[36];
  const float* fp_w = (const float*)d_in[37]; const float* fp_b = (const float*)d_in[38];
  const float* lfp_w = (const float*)d_in[39]; const float* lfp_b = (const float*)d_in[40];
  const float* bin_score = (const float*)d_in[41];

  const int NS = in_sizes[0] / 3;
  const int NT = in_sizes[1] / 3;

  float* FB = (float*)d_ws;
  size_t off = 0;
  auto falloc = [&](size_t n){ float* p = FB + off; off += (n + 63) & ~size_t(63); return p; };
  float* Zx  = falloc(263169);
  float* Zt  = falloc(263169);
  float* Rr  = falloc(640);
  float* Cc  = falloc(640);
  float* UU  = falloc(32000);
  float* VV  = falloc(32000);
  float* cff = falloc(262144);
  u16* cf   = (u16*)falloc(131072);
  u16* qb   = (u16*)falloc(131072);
  u16* kb   = (u16*)falloc(131072);
  u16* vtb  = (u16*)falloc(131072);
  u16* msgb = (u16*)falloc(131072);
  u16* sfpb = (u16*)falloc(131072);
  u16* wsb  = (u16*)falloc(1269760);

  int* IB = (int*)(FB + off);
  size_t ioff = 0;
  auto ialloc = [&](size_t n){ int* p = IB + ioff; ioff += (n + 63) & ~size_t(63); return p; };
  int* id_s = ialloc(NS);
  int* id_t = ialloc(NT);
  const int nbs = (NS + 255) / 256, nbt = (NT + 255) / 256;
  int* hist_s = ialloc((size_t)nbs * NODES);
  int* hist_t = ialloc((size_t)nbt * NODES);
  int* cnt_s = ialloc(NODES);
  int* cnt_t = ialloc(NODES);
  int* patch_s = ialloc(NODES*KP);
  int* patch_t = ialloc(NODES*KP);

  float* out0 = (float*)d_out;
  float* out_ls = out0 + ZDIM*ZDIM;
  float* out_gt = out_ls + (long)CC*65*65;

  u16* WcQ = wsb + 0;
  u16* WcK = wsb + 196608;
  u16* WcV = wsb + 393216;
  u16* WcM = wsb + 589824;
  u16* Wc1 = wsb + 786432;
  u16* Wc2 = wsb + 1572864;
  u16* Wfp = wsb + 1966080;
  u16* WlQ = wsb + 2031616;
  u16* WlK = wsb + 2080768;
  u16* WlV = wsb + 2129920;
  u16* WlM = wsb + 2179072;
  u16* Wl1 = wsb + 2228224;
  u16* Wl2 = wsb + 2424832;
  u16* Wlfp = wsb + 2523136;

  // sentinel fill (Rr/Cc/UU/VV contiguous)
  hipMemsetAsync(Rr, 0xFF, (640 + 640 + 32000 + 32000)*sizeof(float), stream);
  hipMemsetAsync(patch_s, 0, NODES*KP*sizeof(int), stream);
  hipMemsetAsync(patch_t, 0, NODES*KP*sizeof(int), stream);

  // ---- prep: weights->bf16 ∥ nn+hist ∥ coarse feature transpose ----
  int nbnn = nbs + nbt;
  prep<<<NBW + nbnn + 1024, 256, 0, stream>>>(
      c_wq, c_wk, c_wv, c_wm, c_w1, c_w2, fp_w,
      l_wq, l_wk, l_wv, l_wm, l_w1, l_w2, lfp_w, wsb,
      src_pcd_c, NS, src_node_c, id_s, hist_s,
      tgt_pcd_c, NT, tgt_node_c, id_t, hist_t, nbs, nbnn,
      src_feats, tgt_feats, cf, cff);
  scan_kernel2<<<256, 256, 0, stream>>>(hist_s, nbs, cnt_s, hist_t, nbt, cnt_t);
  rank_kernel<<<nbs + nbt, 256, 0, stream>>>(
      id_s, NS, hist_s, patch_s, id_t, NT, hist_t, patch_t, nbs);

  // ---- coarse transformer (sequential-cross semantics) ----
  int crossL[3] = {0, 1, 0};
  for (int l = 0; l < 3; ++l){
    u16* wq = WcQ + (size_t)l*65536; u16* wk = WcK + (size_t)l*65536;
    u16* wv = WcV + (size_t)l*65536; u16* wm = WcM + (size_t)l*65536;
    u16* w1 = Wc1 + (size_t)l*262144; u16* w2 = Wc2 + (size_t)l*131072;
    const float* bq = c_bq + (size_t)l*256; const float* bk = c_bk + (size_t)l*256;
    const float* bv = c_bv + (size_t)l*256; const float* bm = c_bm + (size_t)l*256;
    const float* b1 = c_b1 + (size_t)l*512; const float* b2 = c_b2 + (size_t)l*256;
    if (!crossL[l]){
      coarse_qkv<<<48, 256, 0, stream>>>(cf, 0, 0, wq, wk, wv, bq, bk, bv, qb, kb, vtb);
      coarse_attn<<<64, 256, 0, stream>>>(qb, kb, vtb, msgb, 0);
      coarse_ffn<<<16, 512, 0, stream>>>(msgb, cf, cff, wm, bm, w1, b1, w2, b2, 0);
    } else {
      for (int sd = 0; sd < 2; ++sd){
        coarse_qkv<<<24, 256, 0, stream>>>(cf, 1, sd, wq, wk, wv, bq, bk, bv, qb, kb, vtb);
        coarse_attn<<<32, 256, 0, stream>>>(qb, kb, vtb, msgb, sd);
        coarse_ffn<<<8, 512, 0, stream>>>(msgb, cf, cff, wm, bm, w1, b1, w2, b2, sd);
      }
    }
  }
  coarse_proj<<<16, 256, 0, stream>>>(cf, Wfp, fp_b, sfpb);
  coarse_scores<<<dim3(8,8), 256, 0, stream>>>(sfpb, sfpb + 131072, Zx);
  fill_border<<<3, 256, 0, stream>>>(Zx, bin_score);
  transpose_k<<<dim3(17,17), 256, 0, stream>>>(Zx, Zt, ZDIM);

  // ---- mega: transport (pinned) ∥ gt ∥ full local pipeline ----
  mega<<<128 + CC + CC, 512, 0, stream>>>(
      Zx, Zt, Rr, Cc, UU, VV, out0, logf(1024.0f),
      src_final, tgt_final, patch_s, patch_t, node_corr, cnt_s, cnt_t,
      WlQ, WlK, WlV, WlM, Wl1, Wl2, Wlfp,
      l_bq, l_bk, l_bv, l_bm, l_b1, l_b2, lfp_b,
      out_ls,
      src_raw, tgt_raw, rot, trans, out_gt);

  (void)n_in; (void)out_size; (void)ws_size;
}

// Round 9
// 844.163 us; speedup vs baseline: 1.6646x; 1.1511x over previous
//
#include <hip/hip_runtime.h>
#include <math.h>

static constexpr int NODES = 512;
static constexpr int CC    = 256;
static constexpr int KP    = 64;
static constexpr int ZDIM  = 513;
static constexpr int TPNB  = 16;
static constexpr int TPROWS = 33;

typedef unsigned short u16;
typedef short bf16x8 __attribute__((ext_vector_type(8)));
typedef float f32x4 __attribute__((ext_vector_type(4)));

__device__ __forceinline__ u16 f2b(float f){
  unsigned u = __float_as_uint(f);
  unsigned r = (u + 0x7FFF + ((u >> 16) & 1)) >> 16;
  return (u16)r;
}
__device__ __forceinline__ float b2f(u16 h){ return __uint_as_float(((unsigned)h) << 16); }
__device__ __forceinline__ f32x4 mfma16(bf16x8 a, bf16x8 b, f32x4 c){
  return __builtin_amdgcn_mfma_f32_16x16x32_bf16(a, b, c, 0, 0, 0);
}
__device__ __forceinline__ void astore(float* p, float v){
  __hip_atomic_store(p, v, __ATOMIC_RELAXED, __HIP_MEMORY_SCOPE_AGENT);
}
__device__ __forceinline__ float fpoll(const float* p){
  const unsigned* up = (const unsigned*)p;
  unsigned v = __hip_atomic_load(up, __ATOMIC_RELAXED, __HIP_MEMORY_SCOPE_AGENT);
  while (v == 0xFFFFFFFFu)
    v = __hip_atomic_load(up, __ATOMIC_RELAXED, __HIP_MEMORY_SCOPE_AGENT);
  return __uint_as_float(v);
}
__device__ __forceinline__ void fpoll2(const float* p0, const float* p1,
                                       float* a, float* b){
  const unsigned* u0 = (const unsigned*)p0;
  const unsigned* u1 = (const unsigned*)p1;
  unsigned x = __hip_atomic_load(u0, __ATOMIC_RELAXED, __HIP_MEMORY_SCOPE_AGENT);
  unsigned y = __hip_atomic_load(u1, __ATOMIC_RELAXED, __HIP_MEMORY_SCOPE_AGENT);
  while (x == 0xFFFFFFFFu || y == 0xFFFFFFFFu){
    if (x == 0xFFFFFFFFu) x = __hip_atomic_load(u0, __ATOMIC_RELAXED, __HIP_MEMORY_SCOPE_AGENT);
    if (y == 0xFFFFFFFFu) y = __hip_atomic_load(u1, __ATOMIC_RELAXED, __HIP_MEMORY_SCOPE_AGENT);
  }
  *a = __uint_as_float(x); *b = __uint_as_float(y);
}

// ======================= prep: conv_weights ∥ nn_hist ∥ tr_in =======================
static constexpr int NBW = (2539520 + 255) / 256;   // 9920

__global__ __launch_bounds__(256) void prep(
  const float* cwq, const float* cwk, const float* cwv, const float* cwm,
  const float* cw1, const float* cw2, const float* fpw,
  const float* lwq, const float* lwk, const float* lwv, const float* lwm,
  const float* lw1, const float* lw2, const float* lfp, u16* __restrict__ dst,
  const float* __restrict__ pts_s, int ns, const float* __restrict__ nodes_s,
  int* __restrict__ id_s, int* __restrict__ hist_s,
  const float* __restrict__ pts_t, int ntt, const float* __restrict__ nodes_t,
  int* __restrict__ id_t, int* __restrict__ hist_t, int nbs, int nbnn,
  const float* __restrict__ fs, const float* __restrict__ ft,
  u16* __restrict__ cf, float* __restrict__ cff)
{
  int blk = blockIdx.x;
  int t = threadIdx.x;
  if (blk < NBW){
    int i = blk*256 + t;
    if (i >= 2539520) return;
    const float* s; int off;
    if      (i <  196608){ s=cwq; off=0; }
    else if (i <  393216){ s=cwk; off=196608; }
    else if (i <  589824){ s=cwv; off=393216; }
    else if (i <  786432){ s=cwm; off=589824; }
    else if (i < 1572864){ s=cw1; off=786432; }
    else if (i < 1966080){ s=cw2; off=1572864; }
    else if (i < 2031616){ s=fpw; off=1966080; }
    else if (i < 2080768){ s=lwq; off=2031616; }
    else if (i < 2129920){ s=lwk; off=2080768; }
    else if (i < 2179072){ s=lwv; off=2129920; }
    else if (i < 2228224){ s=lwm; off=2179072; }
    else if (i < 2424832){ s=lw1; off=2228224; }
    else if (i < 2523136){ s=lw2; off=2424832; }
    else                 { s=lfp; off=2523136; }
    dst[i] = f2b(s[i - off]);
    return;
  }
  if (blk < NBW + nbnn){
#pragma clang fp contract(off)
    __shared__ float nx[NODES], ny[NODES], nz[NODES], nn[NODES];
    __shared__ int h[NODES];
    int b2 = blk - NBW;
    const float* pts; const float* nodes; int* out; int* hist; int n; int bb;
    if (b2 < nbs){ pts=pts_s; nodes=nodes_s; out=id_s; hist=hist_s; n=ns; bb=b2; }
    else         { pts=pts_t; nodes=nodes_t; out=id_t; hist=hist_t; n=ntt; bb=b2-nbs; }
    for (int m = t; m < NODES; m += 256){
      float a = nodes[m*3+0], b = nodes[m*3+1], c = nodes[m*3+2];
      nx[m]=a; ny[m]=b; nz[m]=c;
      nn[m] = a*a + b*b + c*c;
      h[m] = 0;
    }
    __syncthreads();
    int i = bb*256 + t;
    if (i < n){
      float p0 = pts[i*3+0], p1 = pts[i*3+1], p2 = pts[i*3+2];
      float pp = p0*p0 + p1*p1 + p2*p2;
      float best = INFINITY; int bi = 0;
      for (int m = 0; m < NODES; ++m){
        float dot = fmaf(p2, nz[m], fmaf(p1, ny[m], p0*nx[m]));
        float d = (pp - 2.0f*dot) + nn[m];
        if (d < best){ best = d; bi = m; }
      }
      out[i] = bi;
      atomicAdd(&h[bi], 1);
    }
    __syncthreads();
    hist[(long)bb*NODES + t]       = h[t];
    hist[(long)bb*NODES + t + 256] = h[t+256];
    return;
  }
  {
    int i = (blk - NBW - nbnn)*256 + t;
    if (i >= 262144) return;
    int side = i >> 17; int r = i & 131071; int d = r >> 9; int n = r & 511;
    float v = (side ? ft : fs)[r];
    long o = ((long)side*512 + n)*256 + d;
    cf[o] = f2b(v);
    cff[o] = v;
  }
}

__global__ __launch_bounds__(256) void scan_kernel2(
    int* __restrict__ hist_s, int nbs, int* __restrict__ cnt_s,
    int* __restrict__ hist_t, int nbt, int* __restrict__ cnt_t)
{
  int task = blockIdx.x*4 + (threadIdx.x >> 6);
  int lane = threadIdx.x & 63;
  int which = task >> 9;
  int m = task & 511;
  int* hist = which ? hist_t : hist_s;
  int nb = which ? nbt : nbs;
  int* counts = which ? cnt_t : cnt_s;
  int chunk = (nb + 63) >> 6;
  int vals[7];
  int b0 = lane * chunk;
  int localsum = 0;
#pragma unroll
  for (int k = 0; k < 7; ++k){
    int b = b0 + k;
    int v = (k < chunk && b < nb) ? hist[(long)b*NODES + m] : 0;
    vals[k] = v; localsum += v;
  }
  int pre = localsum;
  for (int o = 1; o < 64; o <<= 1){
    int y = __shfl_up(pre, o);
    if (lane >= o) pre += y;
  }
  int total = __shfl(pre, 63);
  int run = pre - localsum;
#pragma unroll
  for (int k = 0; k < 7; ++k){
    int b = b0 + k;
    if (k < chunk && b < nb){ hist[(long)b*NODES + m] = run; run += vals[k]; }
  }
  if (lane == 0) counts[m] = total;
}

__global__ __launch_bounds__(256) void rank_kernel(
    const int* __restrict__ id_s, int ns, const int* __restrict__ hist_s, int* __restrict__ patch_s,
    const int* __restrict__ id_t, int ntt, const int* __restrict__ hist_t, int* __restrict__ patch_t,
    int nbs)
{
  __shared__ int lid[256];
  int blk = blockIdx.x;
  const int* id; const int* hist; int* patch; int n; int bb;
  if (blk < nbs){ id=id_s; hist=hist_s; patch=patch_s; n=ns; bb=blk; }
  else          { id=id_t; hist=hist_t; patch=patch_t; n=ntt; bb=blk-nbs; }
  int t = threadIdx.x;
  int i = bb*256 + t;
  lid[t] = (i < n) ? id[i] : -1;
  __syncthreads();
  if (i >= n) return;
  int m = lid[t];
  int r = hist[(long)bb*NODES + m];
  for (int q = 0; q < t; ++q) r += (lid[q] == m) ? 1 : 0;
  if (r < KP) patch[m*KP + r] = i;
}

// ======================= coarse transformer (bf16 MFMA, [n][d]) =======================
// qkv: 32-token slices. grid = nsides*48: z -> side=side0+z/48, rem=z%48, proj=rem>>4, slice=rem&15
__global__ __launch_bounds__(256) void coarse_qkv(
    const u16* __restrict__ cf, int cross, int side0,
    const u16* __restrict__ Wq, const u16* __restrict__ Wk, const u16* __restrict__ Wv,
    const float* __restrict__ bq, const float* __restrict__ bk, const float* __restrict__ bv,
    u16* __restrict__ qb, u16* __restrict__ kb, u16* __restrict__ vtb)
{
  int z = blockIdx.x;
  int side = side0 + z/48, rem = z%48, proj = rem >> 4, slice = rem & 15;
  const u16* x = cf + (long)side*131072;
  const u16* s = cross ? cf + (long)(1-side)*131072 : x;
  const u16* in = (proj == 0) ? x : s;
  const u16* W  = (proj==0)?Wq:(proj==1)?Wk:Wv;
  const float* bi = (proj==0)?bq:(proj==1)?bk:bv;
  int n0 = slice << 5;
  int wv_ = threadIdx.x >> 6, L = threadIdx.x & 63, lr = L & 15, lk = L >> 4;
  const u16* inb = in + (long)(n0 + lr)*256 + 8*lk;
  for (int oi = 0; oi < 4; ++oi){
    int o0 = (wv_*4 + oi) << 4;
    const u16* wrow = W + (long)(o0 + lr)*256 + 8*lk;
    f32x4 acc[2] = {};
#pragma unroll
    for (int ks = 0; ks < 8; ++ks){
      bf16x8 b = *(const bf16x8*)(wrow + ks*32);
#pragma unroll
      for (int a = 0; a < 2; ++a){
        bf16x8 av = *(const bf16x8*)(inb + a*16*256 + ks*32);
        acc[a] = mfma16(av, b, acc[a]);
      }
    }
    int col = o0 + lr;
    float bvv = bi[col];
    if (proj < 2){
      u16* o = (proj==0 ? qb : kb) + ((long)side*512 + n0)*256 + col;
#pragma unroll
      for (int a = 0; a < 2; ++a)
#pragma unroll
        for (int q_ = 0; q_ < 4; ++q_)
          o[(long)(a*16 + lk*4 + q_)*256] = f2b(acc[a][q_] + bvv);
    } else {
      u16* o = vtb + ((long)side*256 + col)*512 + n0;
#pragma unroll
      for (int a = 0; a < 2; ++a)
#pragma unroll
        for (int q_ = 0; q_ < 4; ++q_)
          o[a*16 + lk*4 + q_] = f2b(acc[a][q_] + bvv);
    }
  }
}

// attn: 32-row q slices. grid = nsides*64: z -> side=side0+z/64, rem: head=rem>>4, qs=rem&15
__global__ __launch_bounds__(256) void coarse_attn(
    const u16* __restrict__ qb, const u16* __restrict__ kb,
    const u16* __restrict__ vtb, u16* __restrict__ msgb, int side0)
{
  __shared__ u16 P[32*512];   // swizzled
  __shared__ float rmx[32][4], rsm[32][4];
  int z = blockIdx.x;
  int side = side0 + (z >> 6); int rem = z & 63;
  int head = rem >> 4, qs = rem & 15;
  int wv_ = threadIdx.x >> 6, L = threadIdx.x & 63, lr = L & 15, lk = L >> 4;
  const u16* q = qb + ((long)side*512 + qs*32)*256 + head*64;
  const u16* k = kb + (long)side*512*256 + head*64;
  const u16* vt = vtb + ((long)side*256 + head*64)*512;

  bf16x8 af[2][2];
#pragma unroll
  for (int a = 0; a < 2; ++a)
#pragma unroll
    for (int ks = 0; ks < 2; ++ks)
      af[a][ks] = *(const bf16x8*)(q + (long)(a*16 + lr)*256 + ks*32 + 8*lk);

  f32x4 sc[2][8] = {};
  for (int b = 0; b < 8; ++b){
    const u16* krow = k + (long)(wv_*128 + b*16 + lr)*256 + 8*lk;
#pragma unroll
    for (int ks = 0; ks < 2; ++ks){
      bf16x8 bf = *(const bf16x8*)(krow + ks*32);
#pragma unroll
      for (int a = 0; a < 2; ++a)
        sc[a][b] = mfma16(af[a][ks], bf, sc[a][b]);
    }
  }
  const float SC = 0.125f;
#pragma unroll
  for (int a = 0; a < 2; ++a)
#pragma unroll
    for (int q_ = 0; q_ < 4; ++q_){
      float m = sc[a][0][q_];
#pragma unroll
      for (int b = 1; b < 8; ++b) m = fmaxf(m, sc[a][b][q_]);
      m = fmaxf(m, __shfl_xor(m, 1)); m = fmaxf(m, __shfl_xor(m, 2));
      m = fmaxf(m, __shfl_xor(m, 4)); m = fmaxf(m, __shfl_xor(m, 8));
      if (lr == 0) rmx[a*16 + lk*4 + q_][wv_] = m;
    }
  __syncthreads();
#pragma unroll
  for (int a = 0; a < 2; ++a)
#pragma unroll
    for (int q_ = 0; q_ < 4; ++q_){
      int row = a*16 + lk*4 + q_;
      float m = fmaxf(fmaxf(rmx[row][0], rmx[row][1]), fmaxf(rmx[row][2], rmx[row][3]));
      float s = 0.f;
#pragma unroll
      for (int b = 0; b < 8; ++b){
        float e = __expf((sc[a][b][q_] - m)*SC);
        sc[a][b][q_] = e; s += e;
      }
      s += __shfl_xor(s,1); s += __shfl_xor(s,2); s += __shfl_xor(s,4); s += __shfl_xor(s,8);
      if (lr == 0) rsm[row][wv_] = s;
    }
  __syncthreads();
#pragma unroll
  for (int a = 0; a < 2; ++a)
#pragma unroll
    for (int q_ = 0; q_ < 4; ++q_){
      int row = a*16 + lk*4 + q_;
      float inv = 1.f / (rsm[row][0]+rsm[row][1]+rsm[row][2]+rsm[row][3]);
#pragma unroll
      for (int b = 0; b < 8; ++b)
        P[row*512 + ((wv_*128 + b*16 + lr) ^ ((row&7)<<3))] = f2b(sc[a][b][q_] * inv);
    }
  __syncthreads();
  f32x4 mv[2] = {};
  for (int ks = 0; ks < 16; ++ks){
    bf16x8 bf = *(const bf16x8*)(vt + (long)(wv_*16 + lr)*512 + ks*32 + 8*lk);
#pragma unroll
    for (int a = 0; a < 2; ++a){
      bf16x8 av = *(const bf16x8*)(&P[(a*16 + lr)*512 + ((ks*32 + 8*lk) ^ ((lr&7)<<3))]);
      mv[a] = mfma16(av, bf, mv[a]);
    }
  }
  u16* o = msgb + ((long)side*512 + qs*32)*256 + head*64 + wv_*16 + lr;
#pragma unroll
  for (int a = 0; a < 2; ++a)
#pragma unroll
    for (int q_ = 0; q_ < 4; ++q_)
      o[(long)(a*16 + lk*4 + q_)*256] = f2b(mv[a][q_]);
}

// ffn: 16-token slices, 256 threads. grid = nsides*32: z -> side=side0+z/32, slice=z&31
__global__ __launch_bounds__(256) void coarse_ffn(
    const u16* __restrict__ msgb, u16* __restrict__ cf, float* __restrict__ cff,
    const u16* __restrict__ Wm, const float* __restrict__ bm,
    const u16* __restrict__ W1, const float* __restrict__ b1,
    const u16* __restrict__ W2, const float* __restrict__ b2, int side0)
{
  __shared__ u16 m2[16*256];
  __shared__ u16 h1[16*512];
  int z = blockIdx.x;
  int side = side0 + (z >> 5), slice = z & 31;
  int wv_ = threadIdx.x >> 6, L = threadIdx.x & 63, lr = L & 15, lk = L >> 4;
  const u16* msg = msgb + ((long)side*512 + slice*16)*256;
  u16* x = cf + ((long)side*512 + slice*16)*256;
  float* xf = cff + ((long)side*512 + slice*16)*256;
  // wm
  for (int oi = 0; oi < 4; ++oi){
    int o0 = (wv_*4 + oi) << 4;
    f32x4 acc = {};
    const u16* wrow = Wm + (long)(o0+lr)*256 + 8*lk;
#pragma unroll
    for (int ks = 0; ks < 8; ++ks){
      bf16x8 b = *(const bf16x8*)(wrow + ks*32);
      bf16x8 av = *(const bf16x8*)(msg + (long)lr*256 + ks*32 + 8*lk);
      acc = mfma16(av, b, acc);
    }
    int col = o0 + lr; float bb = bm[col];
#pragma unroll
    for (int q_ = 0; q_ < 4; ++q_){
      int row = lk*4 + q_;
      m2[row*256 + (col ^ ((row&7)<<3))] = f2b(acc[q_] + bb);
    }
  }
  __syncthreads();
  // w1 (concat [x | m2], relu)
  for (int oi = 0; oi < 8; ++oi){
    int o0 = (wv_*8 + oi) << 4;
    f32x4 acc = {};
    const u16* wrow = W1 + (long)(o0+lr)*512 + 8*lk;
#pragma unroll
    for (int ks = 0; ks < 16; ++ks){
      int kk = ks*32;
      bf16x8 b = *(const bf16x8*)(wrow + kk);
      bf16x8 av;
      if (kk < 256) av = *(const bf16x8*)(x + (long)lr*256 + kk + 8*lk);
      else          av = *(const bf16x8*)(&m2[lr*256 + ((kk - 256 + 8*lk) ^ ((lr&7)<<3))]);
      acc = mfma16(av, b, acc);
    }
    int col = o0 + lr; float bb = b1[col];
#pragma unroll
    for (int q_ = 0; q_ < 4; ++q_){
      int row = lk*4 + q_;
      h1[row*512 + (col ^ ((row&7)<<3))] = f2b(fmaxf(acc[q_] + bb, 0.f));
    }
  }
  __syncthreads();
  // w2 + residual (fp32 stream)
  for (int oi = 0; oi < 4; ++oi){
    int o0 = (wv_*4 + oi) << 4;
    f32x4 acc = {};
    const u16* wrow = W2 + (long)(o0+lr)*512 + 8*lk;
#pragma unroll
    for (int ks = 0; ks < 16; ++ks){
      bf16x8 b = *(const bf16x8*)(wrow + ks*32);
      bf16x8 av = *(const bf16x8*)(&h1[lr*512 + ((ks*32 + 8*lk) ^ ((lr&7)<<3))]);
      acc = mfma16(av, b, acc);
    }
    int col = o0 + lr; float bb = b2[col];
#pragma unroll
    for (int q_ = 0; q_ < 4; ++q_){
      long idx = (long)(lk*4+q_)*256 + col;
      float v = acc[q_] + bb + xf[idx];
      xf[idx] = v;
      x[idx] = f2b(v);
    }
  }
}

// proj: 32-token slices. grid 32: z -> side=z>>4, slice=z&15
__global__ __launch_bounds__(256) void coarse_proj(
    const u16* __restrict__ cf, const u16* __restrict__ W,
    const float* __restrict__ bias, u16* __restrict__ out)
{
  int z = blockIdx.x;
  int side = z >> 4, slice = z & 15;
  const u16* in = cf + (long)side*131072;
  u16* o = out + (long)side*131072;
  int n0 = slice << 5;
  int wv_ = threadIdx.x >> 6, L = threadIdx.x & 63, lr = L & 15, lk = L >> 4;
  const u16* inb = in + (long)(n0 + lr)*256 + 8*lk;
  for (int oi = 0; oi < 4; ++oi){
    int o0 = (wv_*4 + oi) << 4;
    const u16* wrow = W + (long)(o0 + lr)*256 + 8*lk;
    f32x4 acc[2] = {};
#pragma unroll
    for (int ks = 0; ks < 8; ++ks){
      bf16x8 b = *(const bf16x8*)(wrow + ks*32);
#pragma unroll
      for (int a = 0; a < 2; ++a){
        bf16x8 av = *(const bf16x8*)(inb + a*16*256 + ks*32);
        acc[a] = mfma16(av, b, acc[a]);
      }
    }
    int col = o0 + lr; float bb = bias[col];
#pragma unroll
    for (int a = 0; a < 2; ++a)
#pragma unroll
      for (int q_ = 0; q_ < 4; ++q_)
        o[(long)(n0 + a*16 + lk*4 + q_)*256 + col] = f2b(acc[a][q_] + bb);
  }
}

__global__ __launch_bounds__(256) void coarse_scores(
    const u16* __restrict__ sfp, const u16* __restrict__ tfp, float* __restrict__ Z)
{
  int n0 = blockIdx.y << 6, m0 = blockIdx.x << 6;
  int wv_ = threadIdx.x >> 6, L = threadIdx.x & 63, lr = L & 15, lk = L >> 4;
  f32x4 acc[4] = {};
  const u16* arow = sfp + (long)(n0 + lr)*256 + 8*lk;
  const u16* brow = tfp + (long)(m0 + wv_*16 + lr)*256 + 8*lk;
#pragma unroll
  for (int ks = 0; ks < 8; ++ks){
    bf16x8 b = *(const bf16x8*)(brow + ks*32);
#pragma unroll
    for (int a = 0; a < 4; ++a){
      bf16x8 av = *(const bf16x8*)(arow + a*16*256 + ks*32);
      acc[a] = mfma16(av, b, acc[a]);
    }
  }
  int col = m0 + wv_*16 + lr;
#pragma unroll
  for (int a = 0; a < 4; ++a)
#pragma unroll
    for (int q_ = 0; q_ < 4; ++q_)
      Z[(long)(n0 + a*16 + lk*4 + q_)*513 + col] = acc[a][q_]*0.0625f;
}

__global__ __launch_bounds__(256) void fill_border(float* Z, const float* __restrict__ alpha)
{
  int i = blockIdx.x*256 + threadIdx.x;
  if (i < ZDIM){
    float a = alpha[0];
    Z[(long)i*ZDIM + (ZDIM-1)] = a;
    Z[(long)(ZDIM-1)*ZDIM + i] = a;
  }
}

__global__ __launch_bounds__(256) void transpose_k(const float* __restrict__ A,
                                                   float* __restrict__ B, int n)
{
  __shared__ float t[32][33];
  int bx = blockIdx.x*32, by = blockIdx.y*32;
  int lx = threadIdx.x & 31, ly0 = threadIdx.x >> 5;
  for (int dy = 0; dy < 32; dy += 8){
    int x = bx + lx, y = by + ly0 + dy;
    if (x < n && y < n) t[ly0+dy][lx] = A[(long)y*n + x];
  }
  __syncthreads();
  for (int dy = 0; dy < 32; dy += 8){
    int x = by + lx, y = bx + ly0 + dy;
    if (x < n && y < n) B[(long)y*n + x] = t[lx][ly0+dy];
  }
}

// ======================= mega kernel roles (512 threads) =======================
static constexpr int ARENA = 142336;

__device__ void transport_role(char* arena, int bid,
    const float* __restrict__ Z, const float* __restrict__ Zt,
    float* Rr, float* Cc, float* UU, float* VV,
    float* __restrict__ out, float outadd)
{
  float* A = (float*)arena;
  float* B = A + TPROWS*513;
  float* RrL = B + TPROWS*513;
  float* CcL = RrL + 513;
  float* M   = CcL + 513;
  float* rown = M + 513;
  float* cown = rown + TPROWS;
  float* uown = cown + TPROWS;
  int tid = threadIdx.x;
  int wv_ = tid >> 6, lane = tid & 63;
  int r0 = bid * TPROWS;
  int nr = 513 - r0; if (nr > TPROWS) nr = TPROWS;

  for (int i = wv_; i < nr; i += 8){
    const float* zr  = Z  + (long)(r0+i)*513;
    const float* ztr = Zt + (long)(r0+i)*513;
    for (int j = lane; j < 513; j += 64){ A[i*513+j] = zr[j]; B[i*513+j] = ztr[j]; }
  }
  __syncthreads();
  for (int i = wv_; i < nr; i += 8){
    float m = -INFINITY;
    for (int j = lane; j < 513; j += 64) m = fmaxf(m, A[i*513+j]);
    for (int o = 32; o; o >>= 1) m = fmaxf(m, __shfl_xor(m, o));
    if (lane == 0){ rown[i] = m; astore(&Rr[r0+i], m); }
  }
  if (tid == 0)      fpoll2(&Rr[0], &Rr[512], &RrL[0], &RrL[512]);
  else if (tid < 512) RrL[tid] = fpoll(&Rr[tid]);
  __syncthreads();
  for (int i = wv_; i < nr; i += 8){
    float m = -INFINITY;
    for (int j = lane; j < 513; j += 64) m = fmaxf(m, B[i*513+j] - RrL[j]);
    for (int o = 32; o; o >>= 1) m = fmaxf(m, __shfl_xor(m, o));
    if (lane == 0){ cown[i] = m; astore(&Cc[r0+i], m); }
  }
  if (tid == 0)      fpoll2(&Cc[0], &Cc[512], &CcL[0], &CcL[512]);
  else if (tid < 512) CcL[tid] = fpoll(&Cc[tid]);
  __syncthreads();
  for (int i = wv_; i < nr; i += 8){
    float ro = rown[i], co = cown[i];
    for (int j = lane; j < 513; j += 64){
      A[i*513+j] = __expf(A[i*513+j] - ro - CcL[j]);
      B[i*513+j] = __expf(B[i*513+j] - co - RrL[j]);
    }
  }
  __syncthreads();
  const float EBM = 1.0f/1024.0f, EBL = 0.5f;
  for (int i = wv_; i < nr; i += 8){
    float s = 0.f;
    for (int j = lane; j < 513; j += 64) s += A[i*513+j];
    for (int o = 32; o; o >>= 1) s += __shfl_xor(s, o);
    if (lane == 0){
      int r = r0+i; float u = ((r < 512) ? EBM : EBL) / s;
      uown[i] = u; astore(&UU[r], u);
    }
  }
  for (int it = 0; it < 50; ++it){
    const float* src = &UU[(long)it*640];
    if (tid == 0)      fpoll2(&src[0], &src[512], &M[0], &M[512]);
    else if (tid < 512) M[tid] = fpoll(&src[tid]);
    __syncthreads();
    for (int i = wv_; i < nr; i += 8){
      float s = 0.f;
      for (int j = lane; j < 513; j += 64) s = fmaf(B[i*513+j], M[j], s);
      for (int o = 32; o; o >>= 1) s += __shfl_xor(s, o);
      if (lane == 0){
        int r = r0+i;
        astore(&VV[(long)it*640 + r], ((r < 512) ? EBM : EBL) / s);
      }
    }
    __syncthreads();
    if (it == 49) break;
    const float* srcv = &VV[(long)it*640];
    if (tid == 0)      fpoll2(&srcv[0], &srcv[512], &M[0], &M[512]);
    else if (tid < 512) M[tid] = fpoll(&srcv[tid]);
    __syncthreads();
    for (int i = wv_; i < nr; i += 8){
      float s = 0.f;
      for (int j = lane; j < 513; j += 64) s = fmaf(A[i*513+j], M[j], s);
      for (int o = 32; o; o >>= 1) s += __shfl_xor(s, o);
      if (lane == 0){
        int r = r0+i; float u = ((r < 512) ? EBM : EBL) / s;
        uown[i] = u; astore(&UU[(long)(it+1)*640 + r], u);
      }
    }
    __syncthreads();
  }
  {
    const float* srcv = &VV[49L*640];
    if (tid == 0)      fpoll2(&srcv[0], &srcv[512], &M[0], &M[512]);
    else if (tid < 512) M[tid] = fpoll(&srcv[tid]);
  }
  __syncthreads();
  for (int j = tid; j < 513; j += 512) M[j] = __logf(M[j]) - CcL[j];
  __syncthreads();
  for (int i = wv_; i < nr; i += 8){
    int r = r0 + i;
    float uu = __logf(uown[i]) - rown[i];
    const float* zr = Z + (long)r*513;
    float* orow = out + (long)r*513;
    for (int j = lane; j < 513; j += 64) orow[j] = zr[j] + uu + M[j] + outadd;
  }
}

// ---- local layer application (512 threads, swizzled LDS) ----
// pool layout (u16 elems): qS 0..8191, kS 8192..16383, vT 16384..24831 (stride 66),
// msgS 24832..33023. P overlays qS/kS; m2 overlays qS; h1 overlays kS/vT.
__device__ void layerapp(
    u16* __restrict__ x, const u16* __restrict__ s, u16* __restrict__ pool,
    const u16* __restrict__ Wq, const u16* __restrict__ Wk,
    const u16* __restrict__ Wv, const u16* __restrict__ Wm,
    const u16* __restrict__ W1, const u16* __restrict__ W2,
    const float* __restrict__ bq, const float* __restrict__ bk,
    const float* __restrict__ bv, const float* __restrict__ bm,
    const float* __restrict__ b1, const float* __restrict__ b2)
{
  int tid = threadIdx.x;
  int wv8 = tid >> 6, L = tid & 63, lr = L & 15, lk = L >> 4;
  u16* qS = pool; u16* kS = pool + 8192; u16* vT = pool + 16384; u16* msgS = pool + 24832;
  int swr = (lr & 7) << 3;   // read-side swizzle (row = ...*16 + lr)

#pragma unroll
  for (int proj = 0; proj < 3; ++proj){
    const u16* in = proj ? s : x;
    const u16* W = proj==0?Wq:proj==1?Wk:Wv;
    const float* bi = proj==0?bq:proj==1?bk:bv;
    int o0 = wv8 << 4;
    f32x4 acc[4] = {};
    const u16* wrow = W + (long)(o0+lr)*128 + 8*lk;
    const u16* inr = in + (long)lr*128 + 8*lk;
#pragma unroll
    for (int ks = 0; ks < 4; ++ks){
      bf16x8 b = *(const bf16x8*)(wrow + ks*32);
#pragma unroll
      for (int a = 0; a < 4; ++a){
        bf16x8 av = *(const bf16x8*)(inr + a*16*128 + ks*32);
        acc[a] = mfma16(av, b, acc[a]);
      }
    }
    int col = o0 + lr; float bb = bi[col];
    if (proj < 2){
      u16* dst = (proj==0 ? qS : kS);
#pragma unroll
      for (int a = 0; a < 4; ++a)
#pragma unroll
        for (int q_ = 0; q_ < 4; ++q_){
          int row = a*16 + lk*4 + q_;
          dst[row*128 + (col ^ ((row&7)<<3))] = f2b(acc[a][q_] + bb);
        }
    } else {
#pragma unroll
      for (int a = 0; a < 4; ++a)
#pragma unroll
        for (int q_ = 0; q_ < 4; ++q_)
          vT[col*66 + a*16 + lk*4 + q_] = f2b(acc[a][q_] + bb);
    }
  }
  __syncthreads();
  // scores: head h = wv8>>1, half of a-tiles per wave
  int h = wv8 >> 1, half = wv8 & 1;
  bf16x8 qf[2], kf[4];
#pragma unroll
  for (int ai = 0; ai < 2; ++ai){
    int a = half*2 + ai;
    qf[ai] = *(const bf16x8*)(&qS[(a*16+lr)*128 + ((h*32 + 8*lk) ^ swr)]);
  }
#pragma unroll
  for (int b = 0; b < 4; ++b)
    kf[b] = *(const bf16x8*)(&kS[(b*16+lr)*128 + ((h*32 + 8*lk) ^ swr)]);
  f32x4 sc[2][4] = {};
#pragma unroll
  for (int b = 0; b < 4; ++b)
#pragma unroll
    for (int ai = 0; ai < 2; ++ai)
      sc[ai][b] = mfma16(qf[ai], kf[b], sc[ai][b]);
  const float SCs = 0.17677669529663687f;
  float invs[2][4];
#pragma unroll
  for (int ai = 0; ai < 2; ++ai)
#pragma unroll
    for (int q_ = 0; q_ < 4; ++q_){
      float m = sc[ai][0][q_];
#pragma unroll
      for (int b = 1; b < 4; ++b) m = fmaxf(m, sc[ai][b][q_]);
      m = fmaxf(m, __shfl_xor(m, 1)); m = fmaxf(m, __shfl_xor(m, 2));
      m = fmaxf(m, __shfl_xor(m, 4)); m = fmaxf(m, __shfl_xor(m, 8));
      float ss = 0.f;
#pragma unroll
      for (int b = 0; b < 4; ++b){
        float e = __expf((sc[ai][b][q_] - m)*SCs);
        sc[ai][b][q_] = e; ss += e;
      }
      ss += __shfl_xor(ss,1); ss += __shfl_xor(ss,2); ss += __shfl_xor(ss,4); ss += __shfl_xor(ss,8);
      invs[ai][q_] = 1.f/ss;
    }
  __syncthreads();   // all qS/kS reads done before P overwrites
  u16* P = pool + h*4096;
#pragma unroll
  for (int ai = 0; ai < 2; ++ai){
    int a = half*2 + ai;
#pragma unroll
    for (int q_ = 0; q_ < 4; ++q_){
      int row = a*16 + lk*4 + q_;
#pragma unroll
      for (int b = 0; b < 4; ++b)
        P[row*64 + ((b*16 + lr) ^ ((row&7)<<3))] = f2b(sc[ai][b][q_] * invs[ai][q_]);
    }
  }
  f32x4 mv[2][2] = {};
#pragma unroll
  for (int ks = 0; ks < 2; ++ks)
#pragma unroll
    for (int bt = 0; bt < 2; ++bt){
      bf16x8 bf = *(const bf16x8*)(&vT[(h*32 + bt*16 + lr)*66 + ks*32 + 8*lk]);
#pragma unroll
      for (int ai = 0; ai < 2; ++ai){
        int a = half*2 + ai;
        bf16x8 av = *(const bf16x8*)(&P[(a*16+lr)*64 + ((ks*32 + 8*lk) ^ swr)]);
        mv[ai][bt] = mfma16(av, bf, mv[ai][bt]);
      }
    }
#pragma unroll
  for (int ai = 0; ai < 2; ++ai){
    int a = half*2 + ai;
#pragma unroll
    for (int bt = 0; bt < 2; ++bt)
#pragma unroll
      for (int q_ = 0; q_ < 4; ++q_){
        int row = a*16 + lk*4 + q_;
        msgS[row*128 + ((h*32 + bt*16 + lr) ^ ((row&7)<<3))] = f2b(mv[ai][bt][q_]);
      }
  }
  __syncthreads();
  // wm
  u16* m2 = pool;
  {
    int o0 = wv8 << 4;
    f32x4 acc[4] = {};
    const u16* wrow = Wm + (long)(o0+lr)*128 + 8*lk;
#pragma unroll
    for (int ks = 0; ks < 4; ++ks){
      bf16x8 b = *(const bf16x8*)(wrow + ks*32);
#pragma unroll
      for (int a = 0; a < 4; ++a){
        bf16x8 av = *(const bf16x8*)(&msgS[(a*16+lr)*128 + ((ks*32 + 8*lk) ^ swr)]);
        acc[a] = mfma16(av, b, acc[a]);
      }
    }
    int col = o0+lr; float bb = bm[col];
#pragma unroll
    for (int a = 0; a < 4; ++a)
#pragma unroll
      for (int q_ = 0; q_ < 4; ++q_){
        int row = a*16+lk*4+q_;
        m2[row*128 + (col ^ ((row&7)<<3))] = f2b(acc[a][q_] + bb);
      }
  }
  __syncthreads();
  // w1 (concat [x | m2], relu)
  u16* h1 = pool + 8192;
#pragma unroll
  for (int oi = 0; oi < 2; ++oi){
    int o0 = (wv8*2 + oi) << 4;
    f32x4 acc[4] = {};
    const u16* wrow = W1 + (long)(o0+lr)*256 + 8*lk;
#pragma unroll
    for (int ks = 0; ks < 8; ++ks){
      int kk = ks*32;
      bf16x8 b = *(const bf16x8*)(wrow + kk);
#pragma unroll
      for (int a = 0; a < 4; ++a){
        bf16x8 av;
        if (kk < 128) av = *(const bf16x8*)(x + (long)(a*16+lr)*128 + kk + 8*lk);
        else          av = *(const bf16x8*)(&m2[(a*16+lr)*128 + ((kk - 128 + 8*lk) ^ swr)]);
        acc[a] = mfma16(av, b, acc[a]);
      }
    }
    int col = o0+lr; float bb = b1[col];
#pragma unroll
    for (int a = 0; a < 4; ++a)
#pragma unroll
      for (int q_ = 0; q_ < 4; ++q_){
        int row = a*16+lk*4+q_;
        h1[row*256 + (col ^ ((row&7)<<3))] = f2b(fmaxf(acc[a][q_] + bb, 0.f));
      }
  }
  __syncthreads();
  // w2 + residual
  {
    int o0 = wv8 << 4;
    f32x4 acc[4] = {};
    const u16* wrow = W2 + (long)(o0+lr)*256 + 8*lk;
#pragma unroll
    for (int ks = 0; ks < 8; ++ks){
      bf16x8 b = *(const bf16x8*)(wrow + ks*32);
#pragma unroll
      for (int a = 0; a < 4; ++a){
        bf16x8 av = *(const bf16x8*)(&h1[(a*16+lr)*256 + ((ks*32 + 8*lk) ^ swr)]);
        acc[a] = mfma16(av, b, acc[a]);
      }
    }
    int col = o0+lr; float bb = b2[col];
#pragma unroll
    for (int a = 0; a < 4; ++a)
#pragma unroll
      for (int q_ = 0; q_ < 4; ++q_){
        int ri = (a*16+lk*4+q_)*128 + col;
        x[ri] = f2b(acc[a][q_] + bb + b2f(x[ri]));
      }
  }
  __syncthreads();
}

// ---- local role: full per-patch pipeline (512 threads) ----
__device__ void local_role(char* arena, int c,
    const float* __restrict__ Fs, const float* __restrict__ Ft,
    const int* __restrict__ patch_s, const int* __restrict__ patch_t,
    const int* __restrict__ corr,
    const int* __restrict__ cnt_s, const int* __restrict__ cnt_t,
    const u16* WlQ, const u16* WlK, const u16* WlV, const u16* WlM,
    const u16* Wl1, const u16* Wl2, const u16* Wlfp,
    const float* lbq, const float* lbk, const float* lbv, const float* lbm,
    const float* lb1, const float* lb2, const float* lfpB,
    float* __restrict__ out_ls)
{
  u16* X    = (u16*)arena;                 // 32 KB
  u16* pool = (u16*)(arena + 32768);       // 66048 B
  float* LA = (float*)(arena + 98816);
  float* ET = (float*)(arena + 115976);
  float* uvec = (float*)(arena + 133136);
  float* vvec = (float*)(arena + 133456);
  float* u0s  = (float*)(arena + 133776);
  float* Ul   = (float*)(arena + 134096);
  float* Vl   = (float*)(arena + 134416);
  int* sel    = (int*)(arena + 134736);
  int tid = threadIdx.x;
  int wv8 = tid >> 6, L = tid & 63, lr = L & 15, lk = L >> 4;
  int swr = (lr & 7) << 3;

  if (tid < 128){
    int side = tid >> 6, n = tid & 63;
    int node = corr[c*2 + side];
    sel[tid] = (side ? patch_t : patch_s)[node*KP + n];
  }
  __syncthreads();
  for (int e = tid; e < 16384; e += 512){
    int side = e >> 13, r = e & 8191, n = r >> 7, d = r & 127;
    const float* F = side ? Ft : Fs;
    X[e] = f2b(F[(long)sel[side*64 + n]*128 + d]);
  }
  __syncthreads();

  for (int l = 0; l < 3; ++l){
    const u16* wq = WlQ + (size_t)l*16384; const u16* wk = WlK + (size_t)l*16384;
    const u16* wv = WlV + (size_t)l*16384; const u16* wm = WlM + (size_t)l*16384;
    const u16* w1 = Wl1 + (size_t)l*65536; const u16* w2 = Wl2 + (size_t)l*32768;
    const float* bq = lbq + (size_t)l*128; const float* bk = lbk + (size_t)l*128;
    const float* bv = lbv + (size_t)l*128; const float* bm = lbm + (size_t)l*128;
    const float* b1 = lb1 + (size_t)l*256; const float* b2 = lb2 + (size_t)l*128;
    int cross = (l == 1);
    layerapp(X,        X + (cross ? 8192 : 0), pool, wq,wk,wv,wm,w1,w2, bq,bk,bv,bm,b1,b2);
    layerapp(X + 8192, X + (cross ? 0 : 8192), pool, wq,wk,wv,wm,w1,w2, bq,bk,bv,bm,b1,b2);
  }

  // lfp projection -> sp/tp (swizzled, stride 128)
  u16* sp = pool; u16* tp = pool + 8192;
  for (int u_ = wv8; u_ < 16; u_ += 8){
    int sideSel = u_ >> 3, ot = u_ & 7;
    const u16* in = X + sideSel*8192;
    u16* dst = sideSel ? tp : sp;
    int o0 = ot << 4;
    f32x4 acc[4] = {};
    const u16* wrow = Wlfp + (long)(o0+lr)*128 + 8*lk;
    const u16* inr = in + (long)lr*128 + 8*lk;
#pragma unroll
    for (int ks = 0; ks < 4; ++ks){
      bf16x8 b = *(const bf16x8*)(wrow + ks*32);
#pragma unroll
      for (int a = 0; a < 4; ++a){
        bf16x8 av = *(const bf16x8*)(inr + a*16*128 + ks*32);
        acc[a] = mfma16(av, b, acc[a]);
      }
    }
    int col = o0 + lr; float bb = lfpB[col];
#pragma unroll
    for (int a = 0; a < 4; ++a)
#pragma unroll
      for (int q_ = 0; q_ < 4; ++q_){
        int row = a*16 + lk*4 + q_;
        dst[row*128 + (col ^ ((row&7)<<3))] = f2b(acc[a][q_] + bb);
      }
  }
  __syncthreads();

  int cs = cnt_s[corr[c*2]], ct = cnt_t[corr[c*2+1]];
  for (int t_ = wv8; t_ < 16; t_ += 8){
    int mt = t_ >> 2, nt = t_ & 3;
    f32x4 acc = {};
#pragma unroll
    for (int ks = 0; ks < 4; ++ks){
      bf16x8 a = *(const bf16x8*)(&sp[(mt*16 + lr)*128 + ((ks*32 + 8*lk) ^ swr)]);
      bf16x8 b = *(const bf16x8*)(&tp[(nt*16 + lr)*128 + ((ks*32 + 8*lk) ^ swr)]);
      acc = mfma16(a, b, acc);
    }
    const float SCS = 0.08838834764831845f;
#pragma unroll
    for (int q_ = 0; q_ < 4; ++q_){
      int row = mt*16 + lk*4 + q_;
      int col = nt*16 + lr;
      float v = acc[q_] * SCS;
      if (row >= cs || col >= ct) v = -1000000.0f;
      LA[row*66 + col] = v;
    }
  }
  if (tid < 65){ LA[64*66 + tid] = 0.f; LA[tid*66 + 64] = 0.f; uvec[tid] = 1.f; vvec[tid] = 1.f; }
  __syncthreads();

  float* E = (float*)pool;
  int g = tid >> 3, sub = tid & 7;
  {
    float mx = -INFINITY;
    for (int j = sub; j < 65; j += 8) mx = fmaxf(mx, LA[g*66 + j]);
    mx = fmaxf(mx, __shfl_xor(mx, 1)); mx = fmaxf(mx, __shfl_xor(mx, 2));
    mx = fmaxf(mx, __shfl_xor(mx, 4));
    float s = 0.f;
    for (int j = sub; j < 65; j += 8) s += __expf(LA[g*66 + j] - mx);
    s += __shfl_xor(s, 1); s += __shfl_xor(s, 2); s += __shfl_xor(s, 4);
    float u0 = mx + __logf(s);
    if (sub == 0) u0s[g] = u0;
    for (int j = sub; j < 65; j += 8){
      float e = __expf(LA[g*66 + j] - u0);
      E[g*66 + j] = e;
      ET[j*66 + g] = e;
    }
  }
  if (tid < 65){
    E[64*66 + tid] = 1.f;
    ET[tid*66 + 64] = 1.f;
    if (tid == 64) u0s[64] = 0.f;
  }
  __syncthreads();
  for (int it = 0; it < 50; ++it){
    {
      float s = 0.f;
      for (int r = sub; r < 65; r += 8) s = fmaf(ET[g*66 + r], uvec[r], s);
      s += __shfl_xor(s, 1); s += __shfl_xor(s, 2); s += __shfl_xor(s, 4);
      if (sub == 0) vvec[g] = 1.f / s;
    }
    __syncthreads();
    if (it == 49) break;
    {
      float s = 0.f;
      for (int j = sub; j < 65; j += 8) s = fmaf(E[g*66 + j], vvec[j], s);
      s += __shfl_xor(s, 1); s += __shfl_xor(s, 2); s += __shfl_xor(s, 4);
      if (sub == 0) uvec[g] = 1.f / s;
    }
    __syncthreads();
  }
  __syncthreads();
  if (tid < 65){ Ul[tid] = u0s[tid] - __logf(uvec[tid]); Vl[tid] = -__logf(vvec[tid]); }
  __syncthreads();
  for (int e = tid; e < 4225; e += 512){
    int r = e / 65, c2 = e % 65;
    out_ls[(long)c*4225 + e] = LA[r*66 + c2] - Ul[r] - Vl[c2];
  }
}

// ---- gt role (512 threads) ----
__device__ void gt_role(char* arena, int c,
    const float* __restrict__ sraw, const float* __restrict__ traw,
    const float* __restrict__ rot, const float* __restrict__ trans,
    const int* __restrict__ patch_s, const int* __restrict__ patch_t,
    const int* __restrict__ corr,
    const int* __restrict__ cnt_s, const int* __restrict__ cnt_t,
    float* __restrict__ out)
{
#pragma clang fp contract(off)
  float* sx = (float*)arena;         float* sy = sx + 64;
  float* sz = sy + 64;               float* spp = sz + 64;
  float* txa = spp + 64;             float* tya = txa + 64;
  float* tza = tya + 64;             float* tpp = tza + 64;
  float* g   = tpp + 64;
  float* rowsum = g + 64*65;
  float* colsum = rowsum + 64;
  int tid = threadIdx.x;
  int sn = corr[c*2], tn = corr[c*2+1];
  int cs = cnt_s[sn], ct = cnt_t[tn];
  if (tid < 64){
    int idx = patch_s[sn*KP + tid];
    float p0 = sraw[(long)idx*3], p1 = sraw[(long)idx*3+1], p2 = sraw[(long)idx*3+2];
    float a0 = fmaf(rot[2], p2, fmaf(rot[1], p1, rot[0]*p0)) + trans[0];
    float a1 = fmaf(rot[5], p2, fmaf(rot[4], p1, rot[3]*p0)) + trans[1];
    float a2 = fmaf(rot[8], p2, fmaf(rot[7], p1, rot[6]*p0)) + trans[2];
    sx[tid]=a0; sy[tid]=a1; sz[tid]=a2;
    spp[tid] = a0*a0 + a1*a1 + a2*a2;
  } else if (tid < 128){
    int l = tid - 64;
    int idx = patch_t[tn*KP + l];
    float p0 = traw[(long)idx*3], p1 = traw[(long)idx*3+1], p2 = traw[(long)idx*3+2];
    txa[l]=p0; tya[l]=p1; tza[l]=p2;
    tpp[l] = p0*p0 + p1*p1 + p2*p2;
  }
  __syncthreads();
  for (int e = tid; e < 4096; e += 512){
    int n = e >> 6, m = e & 63;
    float dot = fmaf(sz[n], tza[m], fmaf(sy[n], tya[m], sx[n]*txa[m]));
    float d2 = (spp[n] + tpp[m]) - 2.0f*dot;
    d2 = fmaxf(d2, 0.f);
    g[n*65 + m] = (sqrtf(d2) < 0.1f) ? 1.f : 0.f;
  }
  __syncthreads();
  if (tid < 64){
    float s = 0.f;
    for (int m = 0; m < 64; ++m) s += g[tid*65 + m];
    rowsum[tid] = fmaxf(1.f - s, 0.f);
  } else if (tid < 128){
    int m = tid - 64;
    float s = 0.f;
    for (int n = 0; n < 64; ++n) s += g[n*65 + m];
    colsum[m] = fmaxf(1.f - s, 0.f);
  }
  __syncthreads();
  float* o = out + (long)c*4225;
  for (int e = tid; e < 4225; e += 512){
    int r = e / 65, col = e % 65;
    float v;
    if (r < 64 && col < 64) v = g[r*65 + col];
    else if (r < 64)        v = rowsum[r];
    else if (col < 64)      v = colsum[col];
    else                    v = 0.f;
    if (r < 64 && r >= cs)    v = 0.f;
    if (col < 64 && col >= ct) v = 0.f;
    o[e] = v;
  }
}

// ---- mega kernel: transport (XCD-pinned) ∥ local ∥ gt ----
__global__ __launch_bounds__(512) void mega(
    const float* Z, const float* Zt, float* Rr, float* Cc, float* UU, float* VV,
    float* out0, float outadd,
    const float* Fs, const float* Ft,
    const int* patch_s, const int* patch_t, const int* corr,
    const int* cnt_s, const int* cnt_t,
    const u16* WlQ, const u16* WlK, const u16* WlV, const u16* WlM,
    const u16* Wl1, const u16* Wl2, const u16* Wlfp,
    const float* lbq, const float* lbk, const float* lbv, const float* lbm,
    const float* lb1, const float* lb2, const float* lfpB,
    float* out_ls,
    const float* sraw, const float* traw, const float* rot, const float* trans,
    float* out_gt)
{
  __shared__ __align__(16) char arena[ARENA];
  int b = blockIdx.x;
  if (b < 128){
    if ((b & 7) == 0)
      transport_role(arena, b >> 3, Z, Zt, Rr, Cc, UU, VV, out0, outadd);
    return;
  }
  b -= 128;
  if (b < CC)
    local_role(arena, b, Fs, Ft, patch_s, patch_t, corr, cnt_s, cnt_t,
               WlQ, WlK, WlV, WlM, Wl1, Wl2, Wlfp,
               lbq, lbk, lbv, lbm, lb1, lb2, lfpB, out_ls);
  else
    gt_role(arena, b - CC, sraw, traw, rot, trans,
            patch_s, patch_t, corr, cnt_s, cnt_t, out_gt);
}

// ======================= host =======================
extern "C" void kernel_launch(void* const* d_in, const int* in_sizes, int n_in,
                              void* d_out, int out_size, void* d_ws, size_t ws_size,
                              hipStream_t stream)
{
  const float* src_pcd_c  = (const float*)d_in[0];
  const float* tgt_pcd_c  = (const float*)d_in[1];
  const float* src_node_c = (const float*)d_in[2];
  const float* tgt_node_c = (const float*)d_in[3];
  const float* src_feats  = (const float*)d_in[4];
  const float* tgt_feats  = (const float*)d_in[5];
  const float* src_final  = (const float*)d_in[6];
  const float* tgt_final  = (const float*)d_in[7];
  const float* rot        = (const float*)d_in[8];
  const float* trans      = (const float*)d_in[9];
  const float* src_raw    = (const float*)d_in[10];
  const float* tgt_raw    = (const float*)d_in[11];
  const int*   node_corr  = (const int*)d_in[12];
  const float* c_wq = (const float*)d_in[13]; const float* c_bq = (const float*)d_in[14];
  const float* c_wk = (const float*)d_in[15]; const float* c_bk = (const float*)d_in[16];
  const float* c_wv = (const float*)d_in[17]; const float* c_bv = (const float*)d_in[18];
  const float* c_wm = (const float*)d_in[19]; const float* c_bm = (const float*)d_in[20];
  const float* c_w1 = (const float*)d_in[21]; const float* c_b1 = (const float*)d_in[22];
  const float* c_w2 = (const float*)d_in[23]; const float* c_b2 = (const float*)d_in[24];
  const float* l_wq = (const float*)d_in[25]; const float* l_bq = (const float*)d_in[26];
  const float* l_wk = (const float*)d_in[27]; const float* l_bk = (const float*)d_in[28];
  const float* l_wv = (const float*)d_in[29]; const float* l_bv = (const float*)d_in[30];
  const float* l_wm = (const float*)d_in[31]; const float* l_bm = (const float*)d_in[32];
  const float* l_w1 = (const float*)d_in[33]; const float* l_b1 = (const float*)d_in[34];
  const float* l_w2 = (const float*)d_in[35]; const float* l_b2 = (const float*)d_in[36];
  const float* fp_w = (const float*)d_in[37]; const float* fp_b = (const float*)d_in[38];
  const float* lfp_w = (const float*)d_in[39]; const float* lfp_b = (const float*)d_in[40];
  const float* bin_score = (const float*)d_in[41];

  const int NS = in_sizes[0] / 3;
  const int NT = in_sizes[1] / 3;

  float* FB = (float*)d_ws;
  size_t off = 0;
  auto falloc = [&](size_t n){ float* p = FB + off; off += (n + 63) & ~size_t(63); return p; };
  float* Zx  = falloc(263169);
  float* Zt  = falloc(263169);
  float* Rr  = falloc(640);
  float* Cc  = falloc(640);
  float* UU  = falloc(32000);
  float* VV  = falloc(32000);
  float* cff = falloc(262144);
  u16* cf   = (u16*)falloc(131072);
  u16* qb   = (u16*)falloc(131072);
  u16* kb   = (u16*)falloc(131072);
  u16* vtb  = (u16*)falloc(131072);
  u16* msgb = (u16*)falloc(131072);
  u16* sfpb = (u16*)falloc(131072);
  u16* wsb  = (u16*)falloc(1269760);

  int* IB = (int*)(FB + off);
  size_t ioff = 0;
  auto ialloc = [&](size_t n){ int* p = IB + ioff; ioff += (n + 63) & ~size_t(63); return p; };
  int* id_s = ialloc(NS);
  int* id_t = ialloc(NT);
  const int nbs = (NS + 255) / 256, nbt = (NT + 255) / 256;
  int* hist_s = ialloc((size_t)nbs * NODES);
  int* hist_t = ialloc((size_t)nbt * NODES);
  int* cnt_s = ialloc(NODES);
  int* cnt_t = ialloc(NODES);
  int* patch_s = ialloc(NODES*KP);
  int* patch_t = ialloc(NODES*KP);

  float* out0 = (float*)d_out;
  float* out_ls = out0 + ZDIM*ZDIM;
  float* out_gt = out_ls + (long)CC*65*65;

  u16* WcQ = wsb + 0;
  u16* WcK = wsb + 196608;
  u16* WcV = wsb + 393216;
  u16* WcM = wsb + 589824;
  u16* Wc1 = wsb + 786432;
  u16* Wc2 = wsb + 1572864;
  u16* Wfp = wsb + 1966080;
  u16* WlQ = wsb + 2031616;
  u16* WlK = wsb + 2080768;
  u16* WlV = wsb + 2129920;
  u16* WlM = wsb + 2179072;
  u16* Wl1 = wsb + 2228224;
  u16* Wl2 = wsb + 2424832;
  u16* Wlfp = wsb + 2523136;

  hipMemsetAsync(Rr, 0xFF, (640 + 640 + 32000 + 32000)*sizeof(float), stream);
  hipMemsetAsync(patch_s, 0, NODES*KP*sizeof(int), stream);
  hipMemsetAsync(patch_t, 0, NODES*KP*sizeof(int), stream);

  int nbnn = nbs + nbt;
  prep<<<NBW + nbnn + 1024, 256, 0, stream>>>(
      c_wq, c_wk, c_wv, c_wm, c_w1, c_w2, fp_w,
      l_wq, l_wk, l_wv, l_wm, l_w1, l_w2, lfp_w, wsb,
      src_pcd_c, NS, src_node_c, id_s, hist_s,
      tgt_pcd_c, NT, tgt_node_c, id_t, hist_t, nbs, nbnn,
      src_feats, tgt_feats, cf, cff);
  scan_kernel2<<<256, 256, 0, stream>>>(hist_s, nbs, cnt_s, hist_t, nbt, cnt_t);
  rank_kernel<<<nbs + nbt, 256, 0, stream>>>(
      id_s, NS, hist_s, patch_s, id_t, NT, hist_t, patch_t, nbs);

  // ---- coarse transformer (sequential-cross semantics) ----
  int crossL[3] = {0, 1, 0};
  for (int l = 0; l < 3; ++l){
    u16* wq = WcQ + (size_t)l*65536; u16* wk = WcK + (size_t)l*65536;
    u16* wv = WcV + (size_t)l*65536; u16* wm = WcM + (size_t)l*65536;
    u16* w1 = Wc1 + (size_t)l*262144; u16* w2 = Wc2 + (size_t)l*131072;
    const float* bq = c_bq + (size_t)l*256; const float* bk = c_bk + (size_t)l*256;
    const float* bv = c_bv + (size_t)l*256; const float* bm = c_bm + (size_t)l*256;
    const float* b1 = c_b1 + (size_t)l*512; const float* b2 = c_b2 + (size_t)l*256;
    if (!crossL[l]){
      coarse_qkv<<<96, 256, 0, stream>>>(cf, 0, 0, wq, wk, wv, bq, bk, bv, qb, kb, vtb);
      coarse_attn<<<128, 256, 0, stream>>>(qb, kb, vtb, msgb, 0);
      coarse_ffn<<<64, 256, 0, stream>>>(msgb, cf, cff, wm, bm, w1, b1, w2, b2, 0);
    } else {
      for (int sd = 0; sd < 2; ++sd){
        coarse_qkv<<<48, 256, 0, stream>>>(cf, 1, sd, wq, wk, wv, bq, bk, bv, qb, kb, vtb);
        coarse_attn<<<64, 256, 0, stream>>>(qb, kb, vtb, msgb, sd);
        coarse_ffn<<<32, 256, 0, stream>>>(msgb, cf, cff, wm, bm, w1, b1, w2, b2, sd);
      }
    }
  }
  coarse_proj<<<32, 256, 0, stream>>>(cf, Wfp, fp_b, sfpb);
  coarse_scores<<<dim3(8,8), 256, 0, stream>>>(sfpb, sfpb + 131072, Zx);
  fill_border<<<3, 256, 0, stream>>>(Zx, bin_score);
  transpose_k<<<dim3(17,17), 256, 0, stream>>>(Zx, Zt, ZDIM);

  // ---- mega: transport (pinned) ∥ local ∥ gt ----
  mega<<<128 + CC + CC, 512, 0, stream>>>(
      Zx, Zt, Rr, Cc, UU, VV, out0, logf(1024.0f),
      src_final, tgt_final, patch_s, patch_t, node_corr, cnt_s, cnt_t,
      WlQ, WlK, WlV, WlM, Wl1, Wl2, Wlfp,
      l_bq, l_bk, l_bv, l_bm, l_b1, l_b2, lfp_b,
      out_ls,
      src_raw, tgt_raw, rot, trans, out_gt);

  (void)n_in; (void)out_size; (void)ws_size;
}

// Round 10
// 842.649 us; speedup vs baseline: 1.6676x; 1.0018x over previous
//
#include <hip/hip_runtime.h>
#include <math.h>

static constexpr int NODES = 512;
static constexpr int CC    = 256;
static constexpr int KP    = 64;
static constexpr int ZDIM  = 513;
static constexpr int TPNB  = 16;
static constexpr int TPROWS = 33;

typedef unsigned short u16;
typedef short bf16x8 __attribute__((ext_vector_type(8)));
typedef float f32x4 __attribute__((ext_vector_type(4)));

__device__ __forceinline__ u16 f2b(float f){
  unsigned u = __float_as_uint(f);
  unsigned r = (u + 0x7FFF + ((u >> 16) & 1)) >> 16;
  return (u16)r;
}
__device__ __forceinline__ float b2f(u16 h){ return __uint_as_float(((unsigned)h) << 16); }
__device__ __forceinline__ f32x4 mfma16(bf16x8 a, bf16x8 b, f32x4 c){
  return __builtin_amdgcn_mfma_f32_16x16x32_bf16(a, b, c, 0, 0, 0);
}
__device__ __forceinline__ void astore(float* p, float v){
  __hip_atomic_store(p, v, __ATOMIC_RELAXED, __HIP_MEMORY_SCOPE_AGENT);
}
// sentinel poll with s_sleep backoff: first try hot, then low-rate retries
__device__ __forceinline__ float fpoll(const float* p){
  const unsigned* up = (const unsigned*)p;
  unsigned v = __hip_atomic_load(up, __ATOMIC_RELAXED, __HIP_MEMORY_SCOPE_AGENT);
  while (v == 0xFFFFFFFFu){
    __builtin_amdgcn_s_sleep(1);
    v = __hip_atomic_load(up, __ATOMIC_RELAXED, __HIP_MEMORY_SCOPE_AGENT);
  }
  return __uint_as_float(v);
}
__device__ __forceinline__ void fpoll2(const float* p0, const float* p1,
                                       float* a, float* b){
  const unsigned* u0 = (const unsigned*)p0;
  const unsigned* u1 = (const unsigned*)p1;
  unsigned x = __hip_atomic_load(u0, __ATOMIC_RELAXED, __HIP_MEMORY_SCOPE_AGENT);
  unsigned y = __hip_atomic_load(u1, __ATOMIC_RELAXED, __HIP_MEMORY_SCOPE_AGENT);
  while (x == 0xFFFFFFFFu || y == 0xFFFFFFFFu){
    __builtin_amdgcn_s_sleep(1);
    if (x == 0xFFFFFFFFu) x = __hip_atomic_load(u0, __ATOMIC_RELAXED, __HIP_MEMORY_SCOPE_AGENT);
    if (y == 0xFFFFFFFFu) y = __hip_atomic_load(u1, __ATOMIC_RELAXED, __HIP_MEMORY_SCOPE_AGENT);
  }
  *a = __uint_as_float(x); *b = __uint_as_float(y);
}

// ======================= prep: conv_weights ∥ nn_hist ∥ tr_in =======================
static constexpr int NBW = (2539520 + 255) / 256;   // 9920

__global__ __launch_bounds__(256) void prep(
  const float* cwq, const float* cwk, const float* cwv, const float* cwm,
  const float* cw1, const float* cw2, const float* fpw,
  const float* lwq, const float* lwk, const float* lwv, const float* lwm,
  const float* lw1, const float* lw2, const float* lfp, u16* __restrict__ dst,
  const float* __restrict__ pts_s, int ns, const float* __restrict__ nodes_s,
  int* __restrict__ id_s, int* __restrict__ hist_s,
  const float* __restrict__ pts_t, int ntt, const float* __restrict__ nodes_t,
  int* __restrict__ id_t, int* __restrict__ hist_t, int nbs, int nbnn,
  const float* __restrict__ fs, const float* __restrict__ ft,
  u16* __restrict__ cf, float* __restrict__ cff)
{
  int blk = blockIdx.x;
  int t = threadIdx.x;
  if (blk < NBW){
    int i = blk*256 + t;
    if (i >= 2539520) return;
    const float* s; int off;
    if      (i <  196608){ s=cwq; off=0; }
    else if (i <  393216){ s=cwk; off=196608; }
    else if (i <  589824){ s=cwv; off=393216; }
    else if (i <  786432){ s=cwm; off=589824; }
    else if (i < 1572864){ s=cw1; off=786432; }
    else if (i < 1966080){ s=cw2; off=1572864; }
    else if (i < 2031616){ s=fpw; off=1966080; }
    else if (i < 2080768){ s=lwq; off=2031616; }
    else if (i < 2129920){ s=lwk; off=2080768; }
    else if (i < 2179072){ s=lwv; off=2129920; }
    else if (i < 2228224){ s=lwm; off=2179072; }
    else if (i < 2424832){ s=lw1; off=2228224; }
    else if (i < 2523136){ s=lw2; off=2424832; }
    else                 { s=lfp; off=2523136; }
    dst[i] = f2b(s[i - off]);
    return;
  }
  if (blk < NBW + nbnn){
#pragma clang fp contract(off)
    __shared__ float nx[NODES], ny[NODES], nz[NODES], nn[NODES];
    __shared__ int h[NODES];
    int b2 = blk - NBW;
    const float* pts; const float* nodes; int* out; int* hist; int n; int bb;
    if (b2 < nbs){ pts=pts_s; nodes=nodes_s; out=id_s; hist=hist_s; n=ns; bb=b2; }
    else         { pts=pts_t; nodes=nodes_t; out=id_t; hist=hist_t; n=ntt; bb=b2-nbs; }
    for (int m = t; m < NODES; m += 256){
      float a = nodes[m*3+0], b = nodes[m*3+1], c = nodes[m*3+2];
      nx[m]=a; ny[m]=b; nz[m]=c;
      nn[m] = a*a + b*b + c*c;
      h[m] = 0;
    }
    __syncthreads();
    int i = bb*256 + t;
    if (i < n){
      float p0 = pts[i*3+0], p1 = pts[i*3+1], p2 = pts[i*3+2];
      float pp = p0*p0 + p1*p1 + p2*p2;
      float best = INFINITY; int bi = 0;
      for (int m = 0; m < NODES; ++m){
        float dot = fmaf(p2, nz[m], fmaf(p1, ny[m], p0*nx[m]));
        float d = (pp - 2.0f*dot) + nn[m];
        if (d < best){ best = d; bi = m; }
      }
      out[i] = bi;
      atomicAdd(&h[bi], 1);
    }
    __syncthreads();
    hist[(long)bb*NODES + t]       = h[t];
    hist[(long)bb*NODES + t + 256] = h[t+256];
    return;
  }
  {
    int i = (blk - NBW - nbnn)*256 + t;
    if (i >= 262144) return;
    int side = i >> 17; int r = i & 131071; int d = r >> 9; int n = r & 511;
    float v = (side ? ft : fs)[r];
    long o = ((long)side*512 + n)*256 + d;
    cf[o] = f2b(v);
    cff[o] = v;
  }
}

__global__ __launch_bounds__(256) void scan_kernel2(
    int* __restrict__ hist_s, int nbs, int* __restrict__ cnt_s,
    int* __restrict__ hist_t, int nbt, int* __restrict__ cnt_t)
{
  int task = blockIdx.x*4 + (threadIdx.x >> 6);
  int lane = threadIdx.x & 63;
  int which = task >> 9;
  int m = task & 511;
  int* hist = which ? hist_t : hist_s;
  int nb = which ? nbt : nbs;
  int* counts = which ? cnt_t : cnt_s;
  int chunk = (nb + 63) >> 6;
  int vals[7];
  int b0 = lane * chunk;
  int localsum = 0;
#pragma unroll
  for (int k = 0; k < 7; ++k){
    int b = b0 + k;
    int v = (k < chunk && b < nb) ? hist[(long)b*NODES + m] : 0;
    vals[k] = v; localsum += v;
  }
  int pre = localsum;
  for (int o = 1; o < 64; o <<= 1){
    int y = __shfl_up(pre, o);
    if (lane >= o) pre += y;
  }
  int total = __shfl(pre, 63);
  int run = pre - localsum;
#pragma unroll
  for (int k = 0; k < 7; ++k){
    int b = b0 + k;
    if (k < chunk && b < nb){ hist[(long)b*NODES + m] = run; run += vals[k]; }
  }
  if (lane == 0) counts[m] = total;
}

__global__ __launch_bounds__(256) void rank_kernel(
    const int* __restrict__ id_s, int ns, const int* __restrict__ hist_s, int* __restrict__ patch_s,
    const int* __restrict__ id_t, int ntt, const int* __restrict__ hist_t, int* __restrict__ patch_t,
    int nbs)
{
  __shared__ int lid[256];
  int blk = blockIdx.x;
  const int* id; const int* hist; int* patch; int n; int bb;
  if (blk < nbs){ id=id_s; hist=hist_s; patch=patch_s; n=ns; bb=blk; }
  else          { id=id_t; hist=hist_t; patch=patch_t; n=ntt; bb=blk-nbs; }
  int t = threadIdx.x;
  int i = bb*256 + t;
  lid[t] = (i < n) ? id[i] : -1;
  __syncthreads();
  if (i >= n) return;
  int m = lid[t];
  int r = hist[(long)bb*NODES + m];
  for (int q = 0; q < t; ++q) r += (lid[q] == m) ? 1 : 0;
  if (r < KP) patch[m*KP + r] = i;
}

// ======================= coarse transformer (bf16 MFMA, [n][d]) =======================
__global__ __launch_bounds__(256) void coarse_qkv(
    const u16* __restrict__ cf, int cross, int side0,
    const u16* __restrict__ Wq, const u16* __restrict__ Wk, const u16* __restrict__ Wv,
    const float* __restrict__ bq, const float* __restrict__ bk, const float* __restrict__ bv,
    u16* __restrict__ qb, u16* __restrict__ kb, u16* __restrict__ vtb)
{
  int z = blockIdx.x;
  int side = side0 + z/48, rem = z%48, proj = rem >> 4, slice = rem & 15;
  const u16* x = cf + (long)side*131072;
  const u16* s = cross ? cf + (long)(1-side)*131072 : x;
  const u16* in = (proj == 0) ? x : s;
  const u16* W  = (proj==0)?Wq:(proj==1)?Wk:Wv;
  const float* bi = (proj==0)?bq:(proj==1)?bk:bv;
  int n0 = slice << 5;
  int wv_ = threadIdx.x >> 6, L = threadIdx.x & 63, lr = L & 15, lk = L >> 4;
  const u16* inb = in + (long)(n0 + lr)*256 + 8*lk;
  for (int oi = 0; oi < 4; ++oi){
    int o0 = (wv_*4 + oi) << 4;
    const u16* wrow = W + (long)(o0 + lr)*256 + 8*lk;
    f32x4 acc[2] = {};
#pragma unroll
    for (int ks = 0; ks < 8; ++ks){
      bf16x8 b = *(const bf16x8*)(wrow + ks*32);
#pragma unroll
      for (int a = 0; a < 2; ++a){
        bf16x8 av = *(const bf16x8*)(inb + a*16*256 + ks*32);
        acc[a] = mfma16(av, b, acc[a]);
      }
    }
    int col = o0 + lr;
    float bvv = bi[col];
    if (proj < 2){
      u16* o = (proj==0 ? qb : kb) + ((long)side*512 + n0)*256 + col;
#pragma unroll
      for (int a = 0; a < 2; ++a)
#pragma unroll
        for (int q_ = 0; q_ < 4; ++q_)
          o[(long)(a*16 + lk*4 + q_)*256] = f2b(acc[a][q_] + bvv);
    } else {
      u16* o = vtb + ((long)side*256 + col)*512 + n0;
#pragma unroll
      for (int a = 0; a < 2; ++a)
#pragma unroll
        for (int q_ = 0; q_ < 4; ++q_)
          o[a*16 + lk*4 + q_] = f2b(acc[a][q_] + bvv);
    }
  }
}

__global__ __launch_bounds__(256) void coarse_attn(
    const u16* __restrict__ qb, const u16* __restrict__ kb,
    const u16* __restrict__ vtb, u16* __restrict__ msgb, int side0)
{
  __shared__ u16 P[32*512];
  __shared__ float rmx[32][4], rsm[32][4];
  int z = blockIdx.x;
  int side = side0 + (z >> 6); int rem = z & 63;
  int head = rem >> 4, qs = rem & 15;
  int wv_ = threadIdx.x >> 6, L = threadIdx.x & 63, lr = L & 15, lk = L >> 4;
  const u16* q = qb + ((long)side*512 + qs*32)*256 + head*64;
  const u16* k = kb + (long)side*512*256 + head*64;
  const u16* vt = vtb + ((long)side*256 + head*64)*512;

  bf16x8 af[2][2];
#pragma unroll
  for (int a = 0; a < 2; ++a)
#pragma unroll
    for (int ks = 0; ks < 2; ++ks)
      af[a][ks] = *(const bf16x8*)(q + (long)(a*16 + lr)*256 + ks*32 + 8*lk);

  f32x4 sc[2][8] = {};
  for (int b = 0; b < 8; ++b){
    const u16* krow = k + (long)(wv_*128 + b*16 + lr)*256 + 8*lk;
#pragma unroll
    for (int ks = 0; ks < 2; ++ks){
      bf16x8 bf = *(const bf16x8*)(krow + ks*32);
#pragma unroll
      for (int a = 0; a < 2; ++a)
        sc[a][b] = mfma16(af[a][ks], bf, sc[a][b]);
    }
  }
  const float SC = 0.125f;
#pragma unroll
  for (int a = 0; a < 2; ++a)
#pragma unroll
    for (int q_ = 0; q_ < 4; ++q_){
      float m = sc[a][0][q_];
#pragma unroll
      for (int b = 1; b < 8; ++b) m = fmaxf(m, sc[a][b][q_]);
      m = fmaxf(m, __shfl_xor(m, 1)); m = fmaxf(m, __shfl_xor(m, 2));
      m = fmaxf(m, __shfl_xor(m, 4)); m = fmaxf(m, __shfl_xor(m, 8));
      if (lr == 0) rmx[a*16 + lk*4 + q_][wv_] = m;
    }
  __syncthreads();
#pragma unroll
  for (int a = 0; a < 2; ++a)
#pragma unroll
    for (int q_ = 0; q_ < 4; ++q_){
      int row = a*16 + lk*4 + q_;
      float m = fmaxf(fmaxf(rmx[row][0], rmx[row][1]), fmaxf(rmx[row][2], rmx[row][3]));
      float s = 0.f;
#pragma unroll
      for (int b = 0; b < 8; ++b){
        float e = __expf((sc[a][b][q_] - m)*SC);
        sc[a][b][q_] = e; s += e;
      }
      s += __shfl_xor(s,1); s += __shfl_xor(s,2); s += __shfl_xor(s,4); s += __shfl_xor(s,8);
      if (lr == 0) rsm[row][wv_] = s;
    }
  __syncthreads();
#pragma unroll
  for (int a = 0; a < 2; ++a)
#pragma unroll
    for (int q_ = 0; q_ < 4; ++q_){
      int row = a*16 + lk*4 + q_;
      float inv = 1.f / (rsm[row][0]+rsm[row][1]+rsm[row][2]+rsm[row][3]);
#pragma unroll
      for (int b = 0; b < 8; ++b)
        P[row*512 + ((wv_*128 + b*16 + lr) ^ ((row&7)<<3))] = f2b(sc[a][b][q_] * inv);
    }
  __syncthreads();
  f32x4 mv[2] = {};
  for (int ks = 0; ks < 16; ++ks){
    bf16x8 bf = *(const bf16x8*)(vt + (long)(wv_*16 + lr)*512 + ks*32 + 8*lk);
#pragma unroll
    for (int a = 0; a < 2; ++a){
      bf16x8 av = *(const bf16x8*)(&P[(a*16 + lr)*512 + ((ks*32 + 8*lk) ^ ((lr&7)<<3))]);
      mv[a] = mfma16(av, bf, mv[a]);
    }
  }
  u16* o = msgb + ((long)side*512 + qs*32)*256 + head*64 + wv_*16 + lr;
#pragma unroll
  for (int a = 0; a < 2; ++a)
#pragma unroll
    for (int q_ = 0; q_ < 4; ++q_)
      o[(long)(a*16 + lk*4 + q_)*256] = f2b(mv[a][q_]);
}

__global__ __launch_bounds__(256) void coarse_ffn(
    const u16* __restrict__ msgb, u16* __restrict__ cf, float* __restrict__ cff,
    const u16* __restrict__ Wm, const float* __restrict__ bm,
    const u16* __restrict__ W1, const float* __restrict__ b1,
    const u16* __restrict__ W2, const float* __restrict__ b2, int side0)
{
  __shared__ u16 m2[16*256];
  __shared__ u16 h1[16*512];
  int z = blockIdx.x;
  int side = side0 + (z >> 5), slice = z & 31;
  int wv_ = threadIdx.x >> 6, L = threadIdx.x & 63, lr = L & 15, lk = L >> 4;
  const u16* msg = msgb + ((long)side*512 + slice*16)*256;
  u16* x = cf + ((long)side*512 + slice*16)*256;
  float* xf = cff + ((long)side*512 + slice*16)*256;
  for (int oi = 0; oi < 4; ++oi){
    int o0 = (wv_*4 + oi) << 4;
    f32x4 acc = {};
    const u16* wrow = Wm + (long)(o0+lr)*256 + 8*lk;
#pragma unroll
    for (int ks = 0; ks < 8; ++ks){
      bf16x8 b = *(const bf16x8*)(wrow + ks*32);
      bf16x8 av = *(const bf16x8*)(msg + (long)lr*256 + ks*32 + 8*lk);
      acc = mfma16(av, b, acc);
    }
    int col = o0 + lr; float bb = bm[col];
#pragma unroll
    for (int q_ = 0; q_ < 4; ++q_){
      int row = lk*4 + q_;
      m2[row*256 + (col ^ ((row&7)<<3))] = f2b(acc[q_] + bb);
    }
  }
  __syncthreads();
  for (int oi = 0; oi < 8; ++oi){
    int o0 = (wv_*8 + oi) << 4;
    f32x4 acc = {};
    const u16* wrow = W1 + (long)(o0+lr)*512 + 8*lk;
#pragma unroll
    for (int ks = 0; ks < 16; ++ks){
      int kk = ks*32;
      bf16x8 b = *(const bf16x8*)(wrow + kk);
      bf16x8 av;
      if (kk < 256) av = *(const bf16x8*)(x + (long)lr*256 + kk + 8*lk);
      else          av = *(const bf16x8*)(&m2[lr*256 + ((kk - 256 + 8*lk) ^ ((lr&7)<<3))]);
      acc = mfma16(av, b, acc);
    }
    int col = o0 + lr; float bb = b1[col];
#pragma unroll
    for (int q_ = 0; q_ < 4; ++q_){
      int row = lk*4 + q_;
      h1[row*512 + (col ^ ((row&7)<<3))] = f2b(fmaxf(acc[q_] + bb, 0.f));
    }
  }
  __syncthreads();
  for (int oi = 0; oi < 4; ++oi){
    int o0 = (wv_*4 + oi) << 4;
    f32x4 acc = {};
    const u16* wrow = W2 + (long)(o0+lr)*512 + 8*lk;
#pragma unroll
    for (int ks = 0; ks < 16; ++ks){
      bf16x8 b = *(const bf16x8*)(wrow + ks*32);
      bf16x8 av = *(const bf16x8*)(&h1[lr*512 + ((ks*32 + 8*lk) ^ ((lr&7)<<3))]);
      acc = mfma16(av, b, acc);
    }
    int col = o0 + lr; float bb = b2[col];
#pragma unroll
    for (int q_ = 0; q_ < 4; ++q_){
      long idx = (long)(lk*4+q_)*256 + col;
      float v = acc[q_] + bb + xf[idx];
      xf[idx] = v;
      x[idx] = f2b(v);
    }
  }
}

__global__ __launch_bounds__(256) void coarse_proj(
    const u16* __restrict__ cf, const u16* __restrict__ W,
    const float* __restrict__ bias, u16* __restrict__ out)
{
  int z = blockIdx.x;
  int side = z >> 4, slice = z & 15;
  const u16* in = cf + (long)side*131072;
  u16* o = out + (long)side*131072;
  int n0 = slice << 5;
  int wv_ = threadIdx.x >> 6, L = threadIdx.x & 63, lr = L & 15, lk = L >> 4;
  const u16* inb = in + (long)(n0 + lr)*256 + 8*lk;
  for (int oi = 0; oi < 4; ++oi){
    int o0 = (wv_*4 + oi) << 4;
    const u16* wrow = W + (long)(o0 + lr)*256 + 8*lk;
    f32x4 acc[2] = {};
#pragma unroll
    for (int ks = 0; ks < 8; ++ks){
      bf16x8 b = *(const bf16x8*)(wrow + ks*32);
#pragma unroll
      for (int a = 0; a < 2; ++a){
        bf16x8 av = *(const bf16x8*)(inb + a*16*256 + ks*32);
        acc[a] = mfma16(av, b, acc[a]);
      }
    }
    int col = o0 + lr; float bb = bias[col];
#pragma unroll
    for (int a = 0; a < 2; ++a)
#pragma unroll
      for (int q_ = 0; q_ < 4; ++q_)
        o[(long)(n0 + a*16 + lk*4 + q_)*256 + col] = f2b(acc[a][q_] + bb);
  }
}

// writes BOTH Z[n][m] and Zt[m][n] (same value) — kills the transpose pass
__global__ __launch_bounds__(256) void coarse_scores(
    const u16* __restrict__ sfp, const u16* __restrict__ tfp,
    float* __restrict__ Z, float* __restrict__ Zt)
{
  int n0 = blockIdx.y << 6, m0 = blockIdx.x << 6;
  int wv_ = threadIdx.x >> 6, L = threadIdx.x & 63, lr = L & 15, lk = L >> 4;
  f32x4 acc[4] = {};
  const u16* arow = sfp + (long)(n0 + lr)*256 + 8*lk;
  const u16* brow = tfp + (long)(m0 + wv_*16 + lr)*256 + 8*lk;
#pragma unroll
  for (int ks = 0; ks < 8; ++ks){
    bf16x8 b = *(const bf16x8*)(brow + ks*32);
#pragma unroll
    for (int a = 0; a < 4; ++a){
      bf16x8 av = *(const bf16x8*)(arow + a*16*256 + ks*32);
      acc[a] = mfma16(av, b, acc[a]);
    }
  }
  int col = m0 + wv_*16 + lr;
#pragma unroll
  for (int a = 0; a < 4; ++a)
#pragma unroll
    for (int q_ = 0; q_ < 4; ++q_){
      int row = n0 + a*16 + lk*4 + q_;
      float v = acc[a][q_]*0.0625f;
      Z[(long)row*513 + col] = v;
      Zt[(long)col*513 + row] = v;
    }
}

__global__ __launch_bounds__(256) void fill_border(float* Z, float* Zt,
                                                   const float* __restrict__ alpha)
{
  int i = blockIdx.x*256 + threadIdx.x;
  if (i < ZDIM){
    float a = alpha[0];
    Z[(long)i*ZDIM + (ZDIM-1)] = a;
    Z[(long)(ZDIM-1)*ZDIM + i] = a;
    Zt[(long)i*ZDIM + (ZDIM-1)] = a;
    Zt[(long)(ZDIM-1)*ZDIM + i] = a;
  }
}

// ======================= mega kernel roles (512 threads) =======================
static constexpr int ARENA = 142336;

__device__ void transport_role(char* arena, int bid,
    const float* __restrict__ Z, const float* __restrict__ Zt,
    float* Rr, float* Cc, float* UU, float* VV,
    float* __restrict__ out, float outadd)
{
  float* A = (float*)arena;
  float* B = A + TPROWS*513;
  float* RrL = B + TPROWS*513;
  float* CcL = RrL + 513;
  float* M   = CcL + 513;
  float* rown = M + 513;
  float* cown = rown + TPROWS;
  float* uown = cown + TPROWS;
  int tid = threadIdx.x;
  int wv_ = tid >> 6, lane = tid & 63;
  int r0 = bid * TPROWS;
  int nr = 513 - r0; if (nr > TPROWS) nr = TPROWS;

  for (int i = wv_; i < nr; i += 8){
    const float* zr  = Z  + (long)(r0+i)*513;
    const float* ztr = Zt + (long)(r0+i)*513;
    for (int j = lane; j < 513; j += 64){ A[i*513+j] = zr[j]; B[i*513+j] = ztr[j]; }
  }
  __syncthreads();
  for (int i = wv_; i < nr; i += 8){
    float m = -INFINITY;
    for (int j = lane; j < 513; j += 64) m = fmaxf(m, A[i*513+j]);
    for (int o = 32; o; o >>= 1) m = fmaxf(m, __shfl_xor(m, o));
    if (lane == 0){ rown[i] = m; astore(&Rr[r0+i], m); }
  }
  if (tid == 0)      fpoll2(&Rr[0], &Rr[512], &RrL[0], &RrL[512]);
  else if (tid < 512) RrL[tid] = fpoll(&Rr[tid]);
  __syncthreads();
  for (int i = wv_; i < nr; i += 8){
    float m = -INFINITY;
    for (int j = lane; j < 513; j += 64) m = fmaxf(m, B[i*513+j] - RrL[j]);
    for (int o = 32; o; o >>= 1) m = fmaxf(m, __shfl_xor(m, o));
    if (lane == 0){ cown[i] = m; astore(&Cc[r0+i], m); }
  }
  if (tid == 0)      fpoll2(&Cc[0], &Cc[512], &CcL[0], &CcL[512]);
  else if (tid < 512) CcL[tid] = fpoll(&Cc[tid]);
  __syncthreads();
  for (int i = wv_; i < nr; i += 8){
    float ro = rown[i], co = cown[i];
    for (int j = lane; j < 513; j += 64){
      A[i*513+j] = __expf(A[i*513+j] - ro - CcL[j]);
      B[i*513+j] = __expf(B[i*513+j] - co - RrL[j]);
    }
  }
  __syncthreads();
  const float EBM = 1.0f/1024.0f, EBL = 0.5f;
  for (int i = wv_; i < nr; i += 8){
    float s = 0.f;
    for (int j = lane; j < 513; j += 64) s += A[i*513+j];
    for (int o = 32; o; o >>= 1) s += __shfl_xor(s, o);
    if (lane == 0){
      int r = r0+i; float u = ((r < 512) ? EBM : EBL) / s;
      uown[i] = u; astore(&UU[r], u);
    }
  }
  for (int it = 0; it < 50; ++it){
    const float* src = &UU[(long)it*640];
    if (tid == 0)      fpoll2(&src[0], &src[512], &M[0], &M[512]);
    else if (tid < 512) M[tid] = fpoll(&src[tid]);
    __syncthreads();
    for (int i = wv_; i < nr; i += 8){
      float s = 0.f;
      for (int j = lane; j < 513; j += 64) s = fmaf(B[i*513+j], M[j], s);
      for (int o = 32; o; o >>= 1) s += __shfl_xor(s, o);
      if (lane == 0){
        int r = r0+i;
        astore(&VV[(long)it*640 + r], ((r < 512) ? EBM : EBL) / s);
      }
    }
    __syncthreads();
    if (it == 49) break;
    const float* srcv = &VV[(long)it*640];
    if (tid == 0)      fpoll2(&srcv[0], &srcv[512], &M[0], &M[512]);
    else if (tid < 512) M[tid] = fpoll(&srcv[tid]);
    __syncthreads();
    for (int i = wv_; i < nr; i += 8){
      float s = 0.f;
      for (int j = lane; j < 513; j += 64) s = fmaf(A[i*513+j], M[j], s);
      for (int o = 32; o; o >>= 1) s += __shfl_xor(s, o);
      if (lane == 0){
        int r = r0+i; float u = ((r < 512) ? EBM : EBL) / s;
        uown[i] = u; astore(&UU[(long)(it+1)*640 + r], u);
      }
    }
    __syncthreads();
  }
  {
    const float* srcv = &VV[49L*640];
    if (tid == 0)      fpoll2(&srcv[0], &srcv[512], &M[0], &M[512]);
    else if (tid < 512) M[tid] = fpoll(&srcv[tid]);
  }
  __syncthreads();
  for (int j = tid; j < 513; j += 512) M[j] = __logf(M[j]) - CcL[j];
  __syncthreads();
  for (int i = wv_; i < nr; i += 8){
    int r = r0 + i;
    float uu = __logf(uown[i]) - rown[i];
    const float* zr = Z + (long)r*513;
    float* orow = out + (long)r*513;
    for (int j = lane; j < 513; j += 64) orow[j] = zr[j] + uu + M[j] + outadd;
  }
}

// ---- local layer application (512 threads, swizzled LDS) ----
__device__ void layerapp(
    u16* __restrict__ x, const u16* __restrict__ s, u16* __restrict__ pool,
    const u16* __restrict__ Wq, const u16* __restrict__ Wk,
    const u16* __restrict__ Wv, const u16* __restrict__ Wm,
    const u16* __restrict__ W1, const u16* __restrict__ W2,
    const float* __restrict__ bq, const float* __restrict__ bk,
    const float* __restrict__ bv, const float* __restrict__ bm,
    const float* __restrict__ b1, const float* __restrict__ b2)
{
  int tid = threadIdx.x;
  int wv8 = tid >> 6, L = tid & 63, lr = L & 15, lk = L >> 4;
  u16* qS = pool; u16* kS = pool + 8192; u16* vT = pool + 16384; u16* msgS = pool + 24832;
  int swr = (lr & 7) << 3;

#pragma unroll
  for (int proj = 0; proj < 3; ++proj){
    const u16* in = proj ? s : x;
    const u16* W = proj==0?Wq:proj==1?Wk:Wv;
    const float* bi = proj==0?bq:proj==1?bk:bv;
    int o0 = wv8 << 4;
    f32x4 acc[4] = {};
    const u16* wrow = W + (long)(o0+lr)*128 + 8*lk;
    const u16* inr = in + (long)lr*128 + 8*lk;
#pragma unroll
    for (int ks = 0; ks < 4; ++ks){
      bf16x8 b = *(const bf16x8*)(wrow + ks*32);
#pragma unroll
      for (int a = 0; a < 4; ++a){
        bf16x8 av = *(const bf16x8*)(inr + a*16*128 + ks*32);
        acc[a] = mfma16(av, b, acc[a]);
      }
    }
    int col = o0 + lr; float bb = bi[col];
    if (proj < 2){
      u16* dst = (proj==0 ? qS : kS);
#pragma unroll
      for (int a = 0; a < 4; ++a)
#pragma unroll
        for (int q_ = 0; q_ < 4; ++q_){
          int row = a*16 + lk*4 + q_;
          dst[row*128 + (col ^ ((row&7)<<3))] = f2b(acc[a][q_] + bb);
        }
    } else {
#pragma unroll
      for (int a = 0; a < 4; ++a)
#pragma unroll
        for (int q_ = 0; q_ < 4; ++q_)
          vT[col*66 + a*16 + lk*4 + q_] = f2b(acc[a][q_] + bb);
    }
  }
  __syncthreads();
  int h = wv8 >> 1, half = wv8 & 1;
  bf16x8 qf[2], kf[4];
#pragma unroll
  for (int ai = 0; ai < 2; ++ai){
    int a = half*2 + ai;
    qf[ai] = *(const bf16x8*)(&qS[(a*16+lr)*128 + ((h*32 + 8*lk) ^ swr)]);
  }
#pragma unroll
  for (int b = 0; b < 4; ++b)
    kf[b] = *(const bf16x8*)(&kS[(b*16+lr)*128 + ((h*32 + 8*lk) ^ swr)]);
  f32x4 sc[2][4] = {};
#pragma unroll
  for (int b = 0; b < 4; ++b)
#pragma unroll
    for (int ai = 0; ai < 2; ++ai)
      sc[ai][b] = mfma16(qf[ai], kf[b], sc[ai][b]);
  const float SCs = 0.17677669529663687f;
  float invs[2][4];
#pragma unroll
  for (int ai = 0; ai < 2; ++ai)
#pragma unroll
    for (int q_ = 0; q_ < 4; ++q_){
      float m = sc[ai][0][q_];
#pragma unroll
      for (int b = 1; b < 4; ++b) m = fmaxf(m, sc[ai][b][q_]);
      m = fmaxf(m, __shfl_xor(m, 1)); m = fmaxf(m, __shfl_xor(m, 2));
      m = fmaxf(m, __shfl_xor(m, 4)); m = fmaxf(m, __shfl_xor(m, 8));
      float ss = 0.f;
#pragma unroll
      for (int b = 0; b < 4; ++b){
        float e = __expf((sc[ai][b][q_] - m)*SCs);
        sc[ai][b][q_] = e; ss += e;
      }
      ss += __shfl_xor(ss,1); ss += __shfl_xor(ss,2); ss += __shfl_xor(ss,4); ss += __shfl_xor(ss,8);
      invs[ai][q_] = 1.f/ss;
    }
  __syncthreads();
  u16* P = pool + h*4096;
#pragma unroll
  for (int ai = 0; ai < 2; ++ai){
    int a = half*2 + ai;
#pragma unroll
    for (int q_ = 0; q_ < 4; ++q_){
      int row = a*16 + lk*4 + q_;
#pragma unroll
      for (int b = 0; b < 4; ++b)
        P[row*64 + ((b*16 + lr) ^ ((row&7)<<3))] = f2b(sc[ai][b][q_] * invs[ai][q_]);
    }
  }
  f32x4 mv[2][2] = {};
#pragma unroll
  for (int ks = 0; ks < 2; ++ks)
#pragma unroll
    for (int bt = 0; bt < 2; ++bt){
      bf16x8 bf = *(const bf16x8*)(&vT[(h*32 + bt*16 + lr)*66 + ks*32 + 8*lk]);
#pragma unroll
      for (int ai = 0; ai < 2; ++ai){
        int a = half*2 + ai;
        bf16x8 av = *(const bf16x8*)(&P[(a*16+lr)*64 + ((ks*32 + 8*lk) ^ swr)]);
        mv[ai][bt] = mfma16(av, bf, mv[ai][bt]);
      }
    }
#pragma unroll
  for (int ai = 0; ai < 2; ++ai){
    int a = half*2 + ai;
#pragma unroll
    for (int bt = 0; bt < 2; ++bt)
#pragma unroll
      for (int q_ = 0; q_ < 4; ++q_){
        int row = a*16 + lk*4 + q_;
        msgS[row*128 + ((h*32 + bt*16 + lr) ^ ((row&7)<<3))] = f2b(mv[ai][bt][q_]);
      }
  }
  __syncthreads();
  u16* m2 = pool;
  {
    int o0 = wv8 << 4;
    f32x4 acc[4] = {};
    const u16* wrow = Wm + (long)(o0+lr)*128 + 8*lk;
#pragma unroll
    for (int ks = 0; ks < 4; ++ks){
      bf16x8 b = *(const bf16x8*)(wrow + ks*32);
#pragma unroll
      for (int a = 0; a < 4; ++a){
        bf16x8 av = *(const bf16x8*)(&msgS[(a*16+lr)*128 + ((ks*32 + 8*lk) ^ swr)]);
        acc[a] = mfma16(av, b, acc[a]);
      }
    }
    int col = o0+lr; float bb = bm[col];
#pragma unroll
    for (int a = 0; a < 4; ++a)
#pragma unroll
      for (int q_ = 0; q_ < 4; ++q_){
        int row = a*16+lk*4+q_;
        m2[row*128 + (col ^ ((row&7)<<3))] = f2b(acc[a][q_] + bb);
      }
  }
  __syncthreads();
  u16* h1 = pool + 8192;
#pragma unroll
  for (int oi = 0; oi < 2; ++oi){
    int o0 = (wv8*2 + oi) << 4;
    f32x4 acc[4] = {};
    const u16* wrow = W1 + (long)(o0+lr)*256 + 8*lk;
#pragma unroll
    for (int ks = 0; ks < 8; ++ks){
      int kk = ks*32;
      bf16x8 b = *(const bf16x8*)(wrow + kk);
#pragma unroll
      for (int a = 0; a < 4; ++a){
        bf16x8 av;
        if (kk < 128) av = *(const bf16x8*)(x + (long)(a*16+lr)*128 + kk + 8*lk);
        else          av = *(const bf16x8*)(&m2[(a*16+lr)*128 + ((kk - 128 + 8*lk) ^ swr)]);
        acc[a] = mfma16(av, b, acc[a]);
      }
    }
    int col = o0+lr; float bb = b1[col];
#pragma unroll
    for (int a = 0; a < 4; ++a)
#pragma unroll
      for (int q_ = 0; q_ < 4; ++q_){
        int row = a*16+lk*4+q_;
        h1[row*256 + (col ^ ((row&7)<<3))] = f2b(fmaxf(acc[a][q_] + bb, 0.f));
      }
  }
  __syncthreads();
  {
    int o0 = wv8 << 4;
    f32x4 acc[4] = {};
    const u16* wrow = W2 + (long)(o0+lr)*256 + 8*lk;
#pragma unroll
    for (int ks = 0; ks < 8; ++ks){
      bf16x8 b = *(const bf16x8*)(wrow + ks*32);
#pragma unroll
      for (int a = 0; a < 4; ++a){
        bf16x8 av = *(const bf16x8*)(&h1[(a*16+lr)*256 + ((ks*32 + 8*lk) ^ swr)]);
        acc[a] = mfma16(av, b, acc[a]);
      }
    }
    int col = o0+lr; float bb = b2[col];
#pragma unroll
    for (int a = 0; a < 4; ++a)
#pragma unroll
      for (int q_ = 0; q_ < 4; ++q_){
        int ri = (a*16+lk*4+q_)*128 + col;
        x[ri] = f2b(acc[a][q_] + bb + b2f(x[ri]));
      }
  }
  __syncthreads();
}

// ---- gt tail (512 threads, disjoint arena region [0, ~20KB)) ----
__device__ void gt_role(char* arena, int c,
    const float* __restrict__ sraw, const float* __restrict__ traw,
    const float* __restrict__ rot, const float* __restrict__ trans,
    const int* __restrict__ patch_s, const int* __restrict__ patch_t,
    const int* __restrict__ corr,
    const int* __restrict__ cnt_s, const int* __restrict__ cnt_t,
    float* __restrict__ out)
{
#pragma clang fp contract(off)
  float* sx = (float*)arena;         float* sy = sx + 64;
  float* sz = sy + 64;               float* spp = sz + 64;
  float* txa = spp + 64;             float* tya = txa + 64;
  float* tza = tya + 64;             float* tpp = tza + 64;
  float* g   = tpp + 64;
  float* rowsum = g + 64*65;
  float* colsum = rowsum + 64;
  int tid = threadIdx.x;
  int sn = corr[c*2], tn = corr[c*2+1];
  int cs = cnt_s[sn], ct = cnt_t[tn];
  if (tid < 64){
    int idx = patch_s[sn*KP + tid];
    float p0 = sraw[(long)idx*3], p1 = sraw[(long)idx*3+1], p2 = sraw[(long)idx*3+2];
    float a0 = fmaf(rot[2], p2, fmaf(rot[1], p1, rot[0]*p0)) + trans[0];
    float a1 = fmaf(rot[5], p2, fmaf(rot[4], p1, rot[3]*p0)) + trans[1];
    float a2 = fmaf(rot[8], p2, fmaf(rot[7], p1, rot[6]*p0)) + trans[2];
    sx[tid]=a0; sy[tid]=a1; sz[tid]=a2;
    spp[tid] = a0*a0 + a1*a1 + a2*a2;
  } else if (tid < 128){
    int l = tid - 64;
    int idx = patch_t[tn*KP + l];
    float p0 = traw[(long)idx*3], p1 = traw[(long)idx*3+1], p2 = traw[(long)idx*3+2];
    txa[l]=p0; tya[l]=p1; tza[l]=p2;
    tpp[l] = p0*p0 + p1*p1 + p2*p2;
  }
  __syncthreads();
  for (int e = tid; e < 4096; e += 512){
    int n = e >> 6, m = e & 63;
    float dot = fmaf(sz[n], tza[m], fmaf(sy[n], tya[m], sx[n]*txa[m]));
    float d2 = (spp[n] + tpp[m]) - 2.0f*dot;
    d2 = fmaxf(d2, 0.f);
    g[n*65 + m] = (sqrtf(d2) < 0.1f) ? 1.f : 0.f;
  }
  __syncthreads();
  if (tid < 64){
    float s = 0.f;
    for (int m = 0; m < 64; ++m) s += g[tid*65 + m];
    rowsum[tid] = fmaxf(1.f - s, 0.f);
  } else if (tid < 128){
    int m = tid - 64;
    float s = 0.f;
    for (int n = 0; n < 64; ++n) s += g[n*65 + m];
    colsum[m] = fmaxf(1.f - s, 0.f);
  }
  __syncthreads();
  float* o = out + (long)c*4225;
  for (int e = tid; e < 4225; e += 512){
    int r = e / 65, col = e % 65;
    float v;
    if (r < 64 && col < 64) v = g[r*65 + col];
    else if (r < 64)        v = rowsum[r];
    else if (col < 64)      v = colsum[col];
    else                    v = 0.f;
    if (r < 64 && r >= cs)    v = 0.f;
    if (col < 64 && col >= ct) v = 0.f;
    o[e] = v;
  }
}

// ---- local role: per-patch pipeline + gt tail (512 threads) ----
__device__ void local_role(char* arena, int c,
    const float* __restrict__ Fs, const float* __restrict__ Ft,
    const int* __restrict__ patch_s, const int* __restrict__ patch_t,
    const int* __restrict__ corr,
    const int* __restrict__ cnt_s, const int* __restrict__ cnt_t,
    const u16* WlQ, const u16* WlK, const u16* WlV, const u16* WlM,
    const u16* Wl1, const u16* Wl2, const u16* Wlfp,
    const float* lbq, const float* lbk, const float* lbv, const float* lbm,
    const float* lb1, const float* lb2, const float* lfpB,
    float* __restrict__ out_ls)
{
  u16* X    = (u16*)arena;
  u16* pool = (u16*)(arena + 32768);
  float* LA = (float*)(arena + 98816);
  float* ET = (float*)(arena + 115976);
  float* uvec = (float*)(arena + 133136);
  float* vvec = (float*)(arena + 133456);
  float* u0s  = (float*)(arena + 133776);
  float* Ul   = (float*)(arena + 134096);
  float* Vl   = (float*)(arena + 134416);
  int* sel    = (int*)(arena + 134736);
  int tid = threadIdx.x;
  int wv8 = tid >> 6, L = tid & 63, lr = L & 15, lk = L >> 4;
  int swr = (lr & 7) << 3;

  if (tid < 128){
    int side = tid >> 6, n = tid & 63;
    int node = corr[c*2 + side];
    sel[tid] = (side ? patch_t : patch_s)[node*KP + n];
  }
  __syncthreads();
  for (int e = tid; e < 16384; e += 512){
    int side = e >> 13, r = e & 8191, n = r >> 7, d = r & 127;
    const float* F = side ? Ft : Fs;
    X[e] = f2b(F[(long)sel[side*64 + n]*128 + d]);
  }
  __syncthreads();

  for (int l = 0; l < 3; ++l){
    const u16* wq = WlQ + (size_t)l*16384; const u16* wk = WlK + (size_t)l*16384;
    const u16* wv = WlV + (size_t)l*16384; const u16* wm = WlM + (size_t)l*16384;
    const u16* w1 = Wl1 + (size_t)l*65536; const u16* w2 = Wl2 + (size_t)l*32768;
    const float* bq = lbq + (size_t)l*128; const float* bk = lbk + (size_t)l*128;
    const float* bv = lbv + (size_t)l*128; const float* bm = lbm + (size_t)l*128;
    const float* b1 = lb1 + (size_t)l*256; const float* b2 = lb2 + (size_t)l*128;
    int cross = (l == 1);
    layerapp(X,        X + (cross ? 8192 : 0), pool, wq,wk,wv,wm,w1,w2, bq,bk,bv,bm,b1,b2);
    layerapp(X + 8192, X + (cross ? 0 : 8192), pool, wq,wk,wv,wm,w1,w2, bq,bk,bv,bm,b1,b2);
  }

  u16* sp = pool; u16* tp = pool + 8192;
  for (int u_ = wv8; u_ < 16; u_ += 8){
    int sideSel = u_ >> 3, ot = u_ & 7;
    const u16* in = X + sideSel*8192;
    u16* dst = sideSel ? tp : sp;
    int o0 = ot << 4;
    f32x4 acc[4] = {};
    const u16* wrow = Wlfp + (long)(o0+lr)*128 + 8*lk;
    const u16* inr = in + (long)lr*128 + 8*lk;
#pragma unroll
    for (int ks = 0; ks < 4; ++ks){
      bf16x8 b = *(const bf16x8*)(wrow + ks*32);
#pragma unroll
      for (int a = 0; a < 4; ++a){
        bf16x8 av = *(const bf16x8*)(inr + a*16*128 + ks*32);
        acc[a] = mfma16(av, b, acc[a]);
      }
    }
    int col = o0 + lr; float bb = lfpB[col];
#pragma unroll
    for (int a = 0; a < 4; ++a)
#pragma unroll
      for (int q_ = 0; q_ < 4; ++q_){
        int row = a*16 + lk*4 + q_;
        dst[row*128 + (col ^ ((row&7)<<3))] = f2b(acc[a][q_] + bb);
      }
  }
  __syncthreads();

  int cs = cnt_s[corr[c*2]], ct = cnt_t[corr[c*2+1]];
  for (int t_ = wv8; t_ < 16; t_ += 8){
    int mt = t_ >> 2, nt = t_ & 3;
    f32x4 acc = {};
#pragma unroll
    for (int ks = 0; ks < 4; ++ks){
      bf16x8 a = *(const bf16x8*)(&sp[(mt*16 + lr)*128 + ((ks*32 + 8*lk) ^ swr)]);
      bf16x8 b = *(const bf16x8*)(&tp[(nt*16 + lr)*128 + ((ks*32 + 8*lk) ^ swr)]);
      acc = mfma16(a, b, acc);
    }
    const float SCS = 0.08838834764831845f;
#pragma unroll
    for (int q_ = 0; q_ < 4; ++q_){
      int row = mt*16 + lk*4 + q_;
      int col = nt*16 + lr;
      float v = acc[q_] * SCS;
      if (row >= cs || col >= ct) v = -1000000.0f;
      LA[row*66 + col] = v;
    }
  }
  if (tid < 65){ LA[64*66 + tid] = 0.f; LA[tid*66 + 64] = 0.f; uvec[tid] = 1.f; vvec[tid] = 1.f; }
  __syncthreads();

  float* E = (float*)pool;
  int g = tid >> 3, sub = tid & 7;
  {
    float mx = -INFINITY;
    for (int j = sub; j < 65; j += 8) mx = fmaxf(mx, LA[g*66 + j]);
    mx = fmaxf(mx, __shfl_xor(mx, 1)); mx = fmaxf(mx, __shfl_xor(mx, 2));
    mx = fmaxf(mx, __shfl_xor(mx, 4));
    float s = 0.f;
    for (int j = sub; j < 65; j += 8) s += __expf(LA[g*66 + j] - mx);
    s += __shfl_xor(s, 1); s += __shfl_xor(s, 2); s += __shfl_xor(s, 4);
    float u0 = mx + __logf(s);
    if (sub == 0) u0s[g] = u0;
    for (int j = sub; j < 65; j += 8){
      float e = __expf(LA[g*66 + j] - u0);
      E[g*66 + j] = e;
      ET[j*66 + g] = e;
    }
  }
  if (tid < 65){
    E[64*66 + tid] = 1.f;
    ET[tid*66 + 64] = 1.f;
    if (tid == 64) u0s[64] = 0.f;
  }
  __syncthreads();
  for (int it = 0; it < 50; ++it){
    {
      float s = 0.f;
      for (int r = sub; r < 65; r += 8) s = fmaf(ET[g*66 + r], uvec[r], s);
      s += __shfl_xor(s, 1); s += __shfl_xor(s, 2); s += __shfl_xor(s, 4);
      if (sub == 0) vvec[g] = 1.f / s;
    }
    __syncthreads();
    if (it == 49) break;
    {
      float s = 0.f;
      for (int j = sub; j < 65; j += 8) s = fmaf(E[g*66 + j], vvec[j], s);
      s += __shfl_xor(s, 1); s += __shfl_xor(s, 2); s += __shfl_xor(s, 4);
      if (sub == 0) uvec[g] = 1.f / s;
    }
    __syncthreads();
  }
  __syncthreads();
  if (tid < 65){ Ul[tid] = u0s[tid] - __logf(uvec[tid]); Vl[tid] = -__logf(vvec[tid]); }
  __syncthreads();
  for (int e = tid; e < 4225; e += 512){
    int r = e / 65, c2 = e % 65;
    out_ls[(long)c*4225 + e] = LA[r*66 + c2] - Ul[r] - Vl[c2];
  }
}

// ---- mega kernel: transport (XCD-pinned) ∥ local(+gt tail) ----
__global__ __launch_bounds__(512) void mega(
    const float* Z, const float* Zt, float* Rr, float* Cc, float* UU, float* VV,
    float* out0, float outadd,
    const float* Fs, const float* Ft,
    const int* patch_s, const int* patch_t, const int* corr,
    const int* cnt_s, const int* cnt_t,
    const u16* WlQ, const u16* WlK, const u16* WlV, const u16* WlM,
    const u16* Wl1, const u16* Wl2, const u16* Wlfp,
    const float* lbq, const float* lbk, const float* lbv, const float* lbm,
    const float* lb1, const float* lb2, const float* lfpB,
    float* out_ls,
    const float* sraw, const float* traw, const float* rot, const float* trans,
    float* out_gt)
{
  __shared__ __align__(16) char arena[ARENA];
  int b = blockIdx.x;
  if (b < 128){
    if ((b & 7) == 0)
      transport_role(arena, b >> 3, Z, Zt, Rr, Cc, UU, VV, out0, outadd);
    return;
  }
  b -= 128;
  local_role(arena, b, Fs, Ft, patch_s, patch_t, corr, cnt_s, cnt_t,
             WlQ, WlK, WlV, WlM, Wl1, Wl2, Wlfp,
             lbq, lbk, lbv, lbm, lb1, lb2, lfpB, out_ls);
  gt_role(arena, b, sraw, traw, rot, trans,
          patch_s, patch_t, corr, cnt_s, cnt_t, out_gt);
}

// ======================= host =======================
extern "C" void kernel_launch(void* const* d_in, const int* in_sizes, int n_in,
                              void* d_out, int out_size, void* d_ws, size_t ws_size,
                              hipStream_t stream)
{
  const float* src_pcd_c  = (const float*)d_in[0];
  const float* tgt_pcd_c  = (const float*)d_in[1];
  const float* src_node_c = (const float*)d_in[2];
  const float* tgt_node_c = (const float*)d_in[3];
  const float* src_feats  = (const float*)d_in[4];
  const float* tgt_feats  = (const float*)d_in[5];
  const float* src_final  = (const float*)d_in[6];
  const float* tgt_final  = (const float*)d_in[7];
  const float* rot        = (const float*)d_in[8];
  const float* trans      = (const float*)d_in[9];
  const float* src_raw    = (const float*)d_in[10];
  const float* tgt_raw    = (const float*)d_in[11];
  const int*   node_corr  = (const int*)d_in[12];
  const float* c_wq = (const float*)d_in[13]; const float* c_bq = (const float*)d_in[14];
  const float* c_wk = (const float*)d_in[15]; const float* c_bk = (const float*)d_in[16];
  const float* c_wv = (const float*)d_in[17]; const float* c_bv = (const float*)d_in[18];
  const float* c_wm = (const float*)d_in[19]; const float* c_bm = (const float*)d_in[20];
  const float* c_w1 = (const float*)d_in[21]; const float* c_b1 = (const float*)d_in[22];
  const float* c_w2 = (const float*)d_in[23]; const float* c_b2 = (const float*)d_in[24];
  const float* l_wq = (const float*)d_in[25]; const float* l_bq = (const float*)d_in[26];
  const float* l_wk = (const float*)d_in[27]; const float* l_bk = (const float*)d_in[28];
  const float* l_wv = (const float*)d_in[29]; const float* l_bv = (const float*)d_in[30];
  const float* l_wm = (const float*)d_in[31]; const float* l_bm = (const float*)d_in[32];
  const float* l_w1 = (const float*)d_in[33]; const float* l_b1 = (const float*)d_in[34];
  const float* l_w2 = (const float*)d_in[35]; const float* l_b2 = (const float*)d_in[36];
  const float* fp_w = (const float*)d_in[37]; const float* fp_b = (const float*)d_in[38];
  const float* lfp_w = (const float*)d_in[39]; const float* lfp_b = (const float*)d_in[40];
  const float* bin_score = (const float*)d_in[41];

  const int NS = in_sizes[0] / 3;
  const int NT = in_sizes[1] / 3;

  float* FB = (float*)d_ws;
  size_t off = 0;
  auto falloc = [&](size_t n){ float* p = FB + off; off += (n + 63) & ~size_t(63); return p; };
  float* Zx  = falloc(263169);
  float* Zt  = falloc(263169);
  float* Rr  = falloc(640);
  float* Cc  = falloc(640);
  float* UU  = falloc(32000);
  float* VV  = falloc(32000);
  float* cff = falloc(262144);
  u16* cf   = (u16*)falloc(131072);
  u16* qb   = (u16*)falloc(131072);
  u16* kb   = (u16*)falloc(131072);
  u16* vtb  = (u16*)falloc(131072);
  u16* msgb = (u16*)falloc(131072);
  u16* sfpb = (u16*)falloc(131072);
  u16* wsb  = (u16*)falloc(1269760);

  int* IB = (int*)(FB + off);
  size_t ioff = 0;
  auto ialloc = [&](size_t n){ int* p = IB + ioff; ioff += (n + 63) & ~size_t(63); return p; };
  int* id_s = ialloc(NS);
  int* id_t = ialloc(NT);
  const int nbs = (NS + 255) / 256, nbt = (NT + 255) / 256;
  int* hist_s = ialloc((size_t)nbs * NODES);
  int* hist_t = ialloc((size_t)nbt * NODES);
  int* cnt_s = ialloc(NODES);
  int* cnt_t = ialloc(NODES);
  int* patch_s = ialloc(NODES*KP);
  int* patch_t = ialloc(NODES*KP);

  float* out0 = (float*)d_out;
  float* out_ls = out0 + ZDIM*ZDIM;
  float* out_gt = out_ls + (long)CC*65*65;

  u16* WcQ = wsb + 0;
  u16* WcK = wsb + 196608;
  u16* WcV = wsb + 393216;
  u16* WcM = wsb + 589824;
  u16* Wc1 = wsb + 786432;
  u16* Wc2 = wsb + 1572864;
  u16* Wfp = wsb + 1966080;
  u16* WlQ = wsb + 2031616;
  u16* WlK = wsb + 2080768;
  u16* WlV = wsb + 2129920;
  u16* WlM = wsb + 2179072;
  u16* Wl1 = wsb + 2228224;
  u16* Wl2 = wsb + 2424832;
  u16* Wlfp = wsb + 2523136;

  hipMemsetAsync(Rr, 0xFF, (640 + 640 + 32000 + 32000)*sizeof(float), stream);
  hipMemsetAsync(patch_s, 0, NODES*KP*sizeof(int), stream);
  hipMemsetAsync(patch_t, 0, NODES*KP*sizeof(int), stream);

  int nbnn = nbs + nbt;
  prep<<<NBW + nbnn + 1024, 256, 0, stream>>>(
      c_wq, c_wk, c_wv, c_wm, c_w1, c_w2, fp_w,
      l_wq, l_wk, l_wv, l_wm, l_w1, l_w2, lfp_w, wsb,
      src_pcd_c, NS, src_node_c, id_s, hist_s,
      tgt_pcd_c, NT, tgt_node_c, id_t, hist_t, nbs, nbnn,
      src_feats, tgt_feats, cf, cff);
  scan_kernel2<<<256, 256, 0, stream>>>(hist_s, nbs, cnt_s, hist_t, nbt, cnt_t);
  rank_kernel<<<nbs + nbt, 256, 0, stream>>>(
      id_s, NS, hist_s, patch_s, id_t, NT, hist_t, patch_t, nbs);

  // ---- coarse transformer (sequential-cross semantics) ----
  int crossL[3] = {0, 1, 0};
  for (int l = 0; l < 3; ++l){
    u16* wq = WcQ + (size_t)l*65536; u16* wk = WcK + (size_t)l*65536;
    u16* wv = WcV + (size_t)l*65536; u16* wm = WcM + (size_t)l*65536;
    u16* w1 = Wc1 + (size_t)l*262144; u16* w2 = Wc2 + (size_t)l*131072;
    const float* bq = c_bq + (size_t)l*256; const float* bk = c_bk + (size_t)l*256;
    const float* bv = c_bv + (size_t)l*256; const float* bm = c_bm + (size_t)l*256;
    const float* b1 = c_b1 + (size_t)l*512; const float* b2 = c_b2 + (size_t)l*256;
    if (!crossL[l]){
      coarse_qkv<<<96, 256, 0, stream>>>(cf, 0, 0, wq, wk, wv, bq, bk, bv, qb, kb, vtb);
      coarse_attn<<<128, 256, 0, stream>>>(qb, kb, vtb, msgb, 0);
      coarse_ffn<<<64, 256, 0, stream>>>(msgb, cf, cff, wm, bm, w1, b1, w2, b2, 0);
    } else {
      for (int sd = 0; sd < 2; ++sd){
        coarse_qkv<<<48, 256, 0, stream>>>(cf, 1, sd, wq, wk, wv, bq, bk, bv, qb, kb, vtb);
        coarse_attn<<<64, 256, 0, stream>>>(qb, kb, vtb, msgb, sd);
        coarse_ffn<<<32, 256, 0, stream>>>(msgb, cf, cff, wm, bm, w1, b1, w2, b2, sd);
      }
    }
  }
  coarse_proj<<<32, 256, 0, stream>>>(cf, Wfp, fp_b, sfpb);
  coarse_scores<<<dim3(8,8), 256, 0, stream>>>(sfpb, sfpb + 131072, Zx, Zt);
  fill_border<<<3, 256, 0, stream>>>(Zx, Zt, bin_score);

  // ---- mega: transport (pinned) ∥ local pipeline + gt tail ----
  mega<<<128 + CC, 512, 0, stream>>>(
      Zx, Zt, Rr, Cc, UU, VV, out0, logf(1024.0f),
      src_final, tgt_final, patch_s, patch_t, node_corr, cnt_s, cnt_t,
      WlQ, WlK, WlV, WlM, Wl1, Wl2, Wlfp,
      l_bq, l_bk, l_bv, l_bm, l_b1, l_b2, lfp_b,
      out_ls,
      src_raw, tgt_raw, rot, trans, out_gt);

  (void)n_in; (void)out_size; (void)ws_size;
}